// Round 2
// baseline (503.307 us; speedup 1.0000x reference)
//
#include <hip/hip_runtime.h>
#include <math.h>

// MLA + ALiBi causal attention. fp32 in/out, bf16 MFMA internal compute.
// R9: revert R8's 32-key tiles (FETCH doubled: 64B V-rows wasted half of
// every L2 line; occupancy was a red herring -- MfmaUtil unchanged). Back to
// 64-key/80KB. New: REVERSED tile order (diagonal first -> running max
// established on tile 0) + vote-gated fast-path softmax: per tile a lane-
// local 3-fmax max and one wave-uniform __any(growth>20) vote; fast path
// (taken ~always) has NO shfl reduce, NO rescale, NO m-update -- softmax is
// shift-invariant, any reference within exp2 range is exact. Slow path
// (tile 0 / rare excursions) = old full reduce+rescale. Scores in exp2
// domain (log2e folded into scale/slope). s_setprio(1) around MFMA (T5).
typedef __bf16 bf16;
typedef __bf16 bf16x8 __attribute__((ext_vector_type(8)));
typedef __bf16 bf16x4 __attribute__((ext_vector_type(4)));
typedef float f32x4 __attribute__((ext_vector_type(4)));

#define AS1 __attribute__((address_space(1)))
#define AS3 __attribute__((address_space(3)))

// Exact static decomposition (L=2048, 128-row q tiles, 64-key kv tiles,
// chunk = 8 kv tiles, ALiBi window WH[h]): per b: 172 direct + 224 chunks,
// 84 groups. Totals: 344 direct + 448 partial = 792 blocks; 168 groups.
#define ATTN_BLOCKS 792
#define COMB_BLOCKS 168

struct ATables {
  int tbl[ATTN_BLOCKS * 2];   // {meta, partIdx(-1=direct)}
  int grp[COMB_BLOCKS * 4];   // {meta, firstPart, nChunks, pad}
};

// meta = b | h<<1 | qt<<5 | cstart<<9 | clen<<16
constexpr ATables make_tables() {
  ATables T{};
  int WH[16] = {22,32,45,64,90,128,181,256,362,512,724,1024,1448,2048,2896,4096};
  int nc = 0, np = 0, ng = 0;
  for (int qt = 15; qt >= 0; --qt)
    for (int h = 15; h >= 0; --h)
      for (int b = 0; b < 2; ++b) {
        int q0 = qt * 128, nkv = 2 * qt + 2;
        int dlo = q0 - WH[h];
        int kv_lo = dlo > 0 ? (dlo >> 6) : 0;
        int span = nkv - kv_lo;
        int nch = (span + 7) >> 3;
        int base = b | (h << 1) | (qt << 5);
        if (nch == 1) {
          T.tbl[2 * nc] = base | (kv_lo << 9) | (span << 16);
          T.tbl[2 * nc + 1] = -1;
          ++nc;
        } else {
          T.grp[4 * ng] = base; T.grp[4 * ng + 1] = np; T.grp[4 * ng + 2] = nch;
          ++ng;
          for (int c = 0; c < nch; ++c) {
            int cs = kv_lo + c * 8;
            int cl = nkv - cs; if (cl > 8) cl = 8;
            T.tbl[2 * nc] = base | (cs << 9) | (cl << 16);
            T.tbl[2 * nc + 1] = np;
            ++nc; ++np;
          }
        }
      }
  return T;
}

__device__ const ATables g_tab = make_tables();

__device__ __forceinline__ void g2l16(const void* g, void* l) {
  // async global->LDS, 16B per lane; LDS dest is wave-uniform base + lane*16
  __builtin_amdgcn_global_load_lds((const AS1 void*)g, (AS3 void*)l, 16, 0, 0);
}

// ---------------------------------------------------------------------------
// fp32 -> bf16 elementwise convert (n4 = element count / 4)
// ---------------------------------------------------------------------------
__device__ __forceinline__ void cvt_seg(const float* __restrict__ in,
                                        bf16* __restrict__ out, int n4) {
  int i = blockIdx.x * 256 + threadIdx.x;
  const int stride = gridDim.x * 256;
  for (; i < n4; i += stride) {
    float4 v = ((const float4*)in)[i];
    bf16x4 o;
    o[0] = (bf16)v.x; o[1] = (bf16)v.y; o[2] = (bf16)v.z; o[3] = (bf16)v.w;
    ((bf16x4*)out)[i] = o;
  }
}

__global__ __launch_bounds__(256) void cvt_f32_bf16(
    const float* __restrict__ in, bf16* __restrict__ out, int n4) {
  cvt_seg(in, out, n4);
}

__global__ __launch_bounds__(256) void cvt3_f32_bf16(
    const float* __restrict__ s0, bf16* __restrict__ d0, int n0,
    const float* __restrict__ s1, bf16* __restrict__ d1, int n1,
    const float* __restrict__ s2, bf16* __restrict__ d2, int n2) {
  cvt_seg(s0, d0, n0);
  cvt_seg(s1, d1, n1);
  cvt_seg(s2, d2, n2);
}

// ---------------------------------------------------------------------------
// fused convert+transpose: fp32 [Z][R][D] -> bf16 [Z][D][R]. R%64==0, D%64==0.
// ---------------------------------------------------------------------------
__global__ __launch_bounds__(256) void transpose_cvt(
    const float* __restrict__ in, bf16* __restrict__ out, int R, int D)
{
  __shared__ bf16 tile[64][72];
  const long long base = (long long)blockIdx.z * R * D;
  const int r0 = blockIdx.y * 64, c0 = blockIdx.x * 64;
  const int t = threadIdx.x;
#pragma unroll
  for (int i = 0; i < 4; ++i) {
    int c = i * 256 + t;
    int rr = c >> 4, cc = (c & 15) << 2;
    float4 v = *(const float4*)&in[base + (long long)(r0 + rr) * D + c0 + cc];
    tile[rr][cc + 0] = (bf16)v.x;
    tile[rr][cc + 1] = (bf16)v.y;
    tile[rr][cc + 2] = (bf16)v.z;
    tile[rr][cc + 3] = (bf16)v.w;
  }
  __syncthreads();
#pragma unroll
  for (int i = 0; i < 2; ++i) {
    int c = i * 256 + t;
    int rr = c >> 3, cc = (c & 7) << 3;
    bf16x8 v;
#pragma unroll
    for (int j = 0; j < 8; ++j) v[j] = tile[cc + j][rr];
    *(bf16x8*)&out[base + (long long)(c0 + rr) * R + r0 + cc] = v;
  }
}

// ---------------------------------------------------------------------------
// NT GEMM: C[m,n] = sum_k A[m,k]*B[n,k]. 128x128 tile, BK=32, 4 waves.
// ---------------------------------------------------------------------------
template <typename CT>
__global__ __launch_bounds__(256) void gemm_nt(
    const bf16* __restrict__ A, const bf16* __restrict__ B, CT* __restrict__ C,
    int lda, int ldb, int ldc, int K, long long sA, long long sB, long long sC)
{
  A += (long long)blockIdx.z * sA;
  B += (long long)blockIdx.z * sB;
  C += (long long)blockIdx.z * sC;

  __shared__ bf16 As[128][32];
  __shared__ bf16 Bs[128][32];

  const int t = threadIdx.x;
  const int lane = t & 63, wave = t >> 6;
  const int wm = (wave >> 1) * 64, wn = (wave & 1) * 64;
  const int m0 = blockIdx.y * 128, n0 = blockIdx.x * 128;
  const int r16 = lane & 15, q8 = (lane >> 4) * 8;

  f32x4 acc[4][4] = {};

  for (int k0 = 0; k0 < K; k0 += 32) {
    __syncthreads();
#pragma unroll
    for (int r = 0; r < 2; ++r) {
      int c = r * 256 + t;
      int row = c >> 2, col = (c & 3) << 3;
      g2l16(A + (long long)(m0 + row) * lda + (k0 + col), &As[row][col]);
      g2l16(B + (long long)(n0 + row) * ldb + (k0 + col), &Bs[row][col]);
    }
    __syncthreads();

    bf16x8 af[4], bfr[4];
#pragma unroll
    for (int i = 0; i < 4; ++i) af[i]  = *(const bf16x8*)&As[wm + i * 16 + r16][q8];
#pragma unroll
    for (int i = 0; i < 4; ++i) bfr[i] = *(const bf16x8*)&Bs[wn + i * 16 + r16][q8];
#pragma unroll
    for (int mi = 0; mi < 4; ++mi)
#pragma unroll
      for (int ni = 0; ni < 4; ++ni)
        acc[mi][ni] = __builtin_amdgcn_mfma_f32_16x16x32_bf16(af[mi], bfr[ni], acc[mi][ni], 0, 0, 0);
  }

  const int quad = lane >> 4;
#pragma unroll
  for (int mi = 0; mi < 4; ++mi)
#pragma unroll
    for (int ni = 0; ni < 4; ++ni)
#pragma unroll
      for (int r = 0; r < 4; ++r) {
        int mm = m0 + wm + mi * 16 + quad * 4 + r;
        int nn = n0 + wn + ni * 16 + r16;
        C[(long long)mm * ldc + nn] = (CT)acc[mi][ni][r];
      }
}

// ---------------------------------------------------------------------------
// Flash attention, chunked + double-buffered, 64-key tiles, REVERSED order.
// Block = table entry: 128 q rows of (b,h,qt) over KV tiles [cs,cs+cl),
// iterated cend-1 .. cs (diagonal first). K/V double-buffered in LDS (80KB);
// ONE barrier per tile (Psf is wave-private). Prefetch issued right after
// the barrier. Softmax: scores in exp2 domain; per-tile lane-local max +
// wave vote; fast path = no shuffles/no rescale (shift-invariance: any
// reference m within exp2 range is exact); slow path (tile 0 / rare) = full
// 16-lane reduce + rescale. Causal mask on tiles >= nkv-2. LDS XOR-swizzled.
// ---------------------------------------------------------------------------
__global__ __launch_bounds__(256, 2) void attn_kernel(
    const bf16* __restrict__ Q, const bf16* __restrict__ Kh,
    const bf16* __restrict__ VT, bf16* __restrict__ O,
    float* __restrict__ ml, bf16* __restrict__ parts)
{
  const int L = 2048, HD = 128, D = 2048;
  const int meta = g_tab.tbl[2 * blockIdx.x];
  const int part = g_tab.tbl[2 * blockIdx.x + 1];
  const int b = meta & 1, h = (meta >> 1) & 15, qt = (meta >> 5) & 15;
  const int cs = (meta >> 9) & 127, cl = (meta >> 16) & 15;
  const int q0 = qt * 128, nkv = 2 * qt + 2;
  const int cend = cs + cl;
  // mask any diagonal tile (>= nkv-2) present in this chunk:
  const int mraw = nkv - 2 > cs ? nkv - 2 : cs;
  const int mstart = mraw < cend ? mraw : cend;

  const int t = threadIdx.x, wave = t >> 6, lane = t & 63;
  const int col = lane & 15, quad = lane >> 4;
  const float LOG2E = 1.44269504f;
  const float slope2 = exp2f(-0.5f * (float)(h + 1)) * LOG2E;  // exp2-domain
  const float slope16 = slope2 * 16.0f;
  const float scale2 = 0.08838834764831845f * LOG2E;   // (1/sqrt(128))*log2e

  __shared__ bf16 Ksf[2][64 * 128];   // [key][d],  16 chunks/row, swz mask 15
  __shared__ bf16 Vsf[2][128 * 64];   // [d][key],   8 chunks/row, swz mask 7
  __shared__ bf16 Psf[128 * 64];      // [q][key],  wave-private 32-row bands

  const long long qrow0 = (long long)(b * L + q0 + wave * 32);
  const long long kbase = (long long)(h * 4096 + b * L) * HD;
  const long long vbase = (long long)(h * HD) * 4096 + b * L;

  auto stage = [&](int buf, int itile) {
    const int kv0 = itile << 6;
#pragma unroll
    for (int i = 0; i < 4; ++i) {
      int P = i * 256 + t;   // physical 16B chunk index (contiguous per wave)
      {  // K: row = P>>4, phys chunk p = P&15, logical chunk = p ^ (row&15)
        int rr = P >> 4, cc = ((P & 15) ^ (rr & 15)) << 3;
        g2l16(Kh + kbase + (long long)(kv0 + rr) * HD + cc, &Ksf[buf][P * 8]);
      }
      {  // V: row = P>>3, phys chunk p = P&7, logical chunk = p ^ (row&7)
        int rr = P >> 3, cc = ((P & 7) ^ (rr & 7)) << 3;
        g2l16(VT + vbase + (long long)rr * 4096 + kv0 + cc, &Vsf[buf][P * 8]);
      }
    }
  };

  bf16x8 qf[2][4];
#pragma unroll
  for (int mi = 0; mi < 2; ++mi)
#pragma unroll
    for (int ks = 0; ks < 4; ++ks)
      qf[mi][ks] = *(const bf16x8*)&Q[(qrow0 + mi * 16 + col) * D + h * HD + ks * 32 + quad * 8];

  f32x4 o_acc[2][8] = {};
  float m_i[2][4], l_i[2][4];   // l lane-partial (this lane's 4 cols)
#pragma unroll
  for (int mi = 0; mi < 2; ++mi)
#pragma unroll
    for (int r = 0; r < 4; ++r) { m_i[mi][r] = -1e30f; l_i[mi][r] = 0.f; }

  stage(0, cend - 1);

  for (int it = cend - 1; it >= cs; --it) {
    const int cur = (cend - 1 - it) & 1;
    const int kv0 = it << 6;
    const bool masked = (it >= mstart);   // wave-uniform

    __syncthreads();                      // drains vmcnt: Ks/Vs[cur] ready
    if (it > cs) stage(cur ^ 1, it - 1);  // prefetch next (older) tile

    // S = Q K^T  (per wave: 2 m-tiles x 4 n-tiles, 4 k-steps over d=128)
    f32x4 s_acc[2][4] = {};
    __builtin_amdgcn_s_setprio(1);
#pragma unroll
    for (int ks = 0; ks < 4; ++ks) {
      bf16x8 kf[4];
#pragma unroll
      for (int ni = 0; ni < 4; ++ni)
        kf[ni] = *(const bf16x8*)&Ksf[cur][(ni * 16 + col) * 128 +
                                          (((ks * 4 + quad) ^ col) << 3)];
#pragma unroll
      for (int mi = 0; mi < 2; ++mi)
#pragma unroll
        for (int ni = 0; ni < 4; ++ni)
          s_acc[mi][ni] = __builtin_amdgcn_mfma_f32_16x16x32_bf16(
              qf[mi][ks], kf[ni], s_acc[mi][ni], 0, 0, 0);
    }
    __builtin_amdgcn_s_setprio(0);

    // pass 1: scores (exp2 domain) + lane-local row max; no cross-lane ops.
    // S row = quad*4+r (+16*mi), col = ni*16 + (lane&15)
    float sv[2][4][4];
    float grow = -1e30f;   // max over this lane's rows of (rowmax - m_ref)
#pragma unroll
    for (int mi = 0; mi < 2; ++mi)
#pragma unroll
      for (int r = 0; r < 4; ++r) {
        const int rowq = wave * 32 + mi * 16 + quad * 4 + r;
        const int qg = q0 + rowq;
        const float sb = slope2 * (float)(qg - kv0 - col);   // dist at ni=0
#pragma unroll
        for (int ni = 0; ni < 4; ++ni)
          sv[mi][r][ni] = fmaf(s_acc[mi][ni][r], scale2, (float)ni * slope16 - sb);
        if (masked) {
#pragma unroll
          for (int ni = 0; ni < 4; ++ni)
            if (kv0 + ni * 16 + col > qg) sv[mi][r][ni] = -1e30f;
        }
        float rm = fmaxf(fmaxf(sv[mi][r][0], sv[mi][r][1]),
                         fmaxf(sv[mi][r][2], sv[mi][r][3]));
        grow = fmaxf(grow, rm - m_i[mi][r]);
      }

    if (!__any(grow > 20.0f)) {
      // fast path: reference m is safe (P <= 2^20); no reduce, no rescale.
#pragma unroll
      for (int mi = 0; mi < 2; ++mi)
#pragma unroll
        for (int r = 0; r < 4; ++r) {
          const int rowq = wave * 32 + mi * 16 + quad * 4 + r;
          const float mref = m_i[mi][r];
          float ps = 0.f;
#pragma unroll
          for (int ni = 0; ni < 4; ++ni) {
            float pv = exp2f(sv[mi][r][ni] - mref);
            ps += pv;
            Psf[rowq * 64 + ((((ni * 2) + (col >> 3)) ^ (rowq & 7)) << 3) +
                (col & 7)] = (bf16)pv;
          }
          l_i[mi][r] += ps;
        }
    } else {
      // slow path (tile 0 / rare excursion): full reduce + rescale.
#pragma unroll
      for (int mi = 0; mi < 2; ++mi)
#pragma unroll
        for (int r = 0; r < 4; ++r) {
          const int rowq = wave * 32 + mi * 16 + quad * 4 + r;
          float rm = fmaxf(fmaxf(sv[mi][r][0], sv[mi][r][1]),
                           fmaxf(sv[mi][r][2], sv[mi][r][3]));
#pragma unroll
          for (int off = 1; off < 16; off <<= 1)
            rm = fmaxf(rm, __shfl_xor(rm, off, 64));
          const float mold = m_i[mi][r];
          float mnew = fmaxf(mold, rm);
          if (masked) mnew = fmaxf(mnew, -1e20f);   // all-masked-row floor
          const float alpha = exp2f(mold - mnew);
          float ps = 0.f;
#pragma unroll
          for (int ni = 0; ni < 4; ++ni) {
            float pv = exp2f(sv[mi][r][ni] - mnew);
            ps += pv;
            Psf[rowq * 64 + ((((ni * 2) + (col >> 3)) ^ (rowq & 7)) << 3) +
                (col & 7)] = (bf16)pv;
          }
          l_i[mi][r] = fmaf(alpha, l_i[mi][r], ps);
          m_i[mi][r] = mnew;
#pragma unroll
          for (int di = 0; di < 8; ++di) o_acc[mi][di][r] *= alpha;
        }
    }

    // O += P V (no barrier needed: Psf band is wave-private; Vs double-buffered)
    __builtin_amdgcn_s_setprio(1);
#pragma unroll
    for (int kstep = 0; kstep < 2; ++kstep) {
      bf16x8 pf[2];
#pragma unroll
      for (int mi = 0; mi < 2; ++mi)
        pf[mi] = *(const bf16x8*)&Psf[(wave * 32 + mi * 16 + col) * 64 +
                                      (((kstep * 4 + quad) ^ (col & 7)) << 3)];
#pragma unroll
      for (int di = 0; di < 8; ++di) {
        bf16x8 vf = *(const bf16x8*)&Vsf[cur][(di * 16 + col) * 64 +
                                             (((kstep * 4 + quad) ^ (col & 7)) << 3)];
#pragma unroll
        for (int mi = 0; mi < 2; ++mi)
          o_acc[mi][di] = __builtin_amdgcn_mfma_f32_16x16x32_bf16(
              pf[mi], vf, o_acc[mi][di], 0, 0, 0);
      }
    }
    __builtin_amdgcn_s_setprio(0);
  }

  if (part < 0) {
    // direct: normalize (reduce lane-partial l over the 16-lane row group)
#pragma unroll
    for (int mi = 0; mi < 2; ++mi)
#pragma unroll
      for (int r = 0; r < 4; ++r) {
        float lt = l_i[mi][r];
#pragma unroll
        for (int off = 1; off < 16; off <<= 1)
          lt += __shfl_xor(lt, off, 64);
        float rl = 1.0f / lt;
        long long qg = qrow0 + mi * 16 + quad * 4 + r;
#pragma unroll
        for (int di = 0; di < 8; ++di)
          O[qg * D + h * HD + di * 16 + col] = (bf16)(o_acc[mi][di][r] * rl);
      }
  } else {
    // partial: store unnormalized O~ (bf16) + m,l (fp32 per row)
    bf16* pb = parts + (long long)part * 16384;
    float* mlp = ml + (long long)part * 256;
#pragma unroll
    for (int mi = 0; mi < 2; ++mi)
#pragma unroll
      for (int r = 0; r < 4; ++r) {
        float lt = l_i[mi][r];
#pragma unroll
        for (int off = 1; off < 16; off <<= 1)
          lt += __shfl_xor(lt, off, 64);
        int rowq = wave * 32 + mi * 16 + quad * 4 + r;
        if (col == 0) { mlp[rowq] = m_i[mi][r]; mlp[128 + rowq] = lt; }
#pragma unroll
        for (int di = 0; di < 8; ++di)
          pb[rowq * 128 + di * 16 + col] = (bf16)o_acc[mi][di][r];
      }
  }
}

// ---------------------------------------------------------------------------
// Combine partial chunks: O = sum_c e2^(m_c-M) O~_c / sum_c e2^(m_c-M) l_c.
// (m are exp2-domain references; weights use exp2f.) One block per group;
// thread t: row = t>>1, cols (t&1)*64..+63.
// ---------------------------------------------------------------------------
__global__ __launch_bounds__(256) void attn_combine(
    const float* __restrict__ ml, const bf16* __restrict__ parts,
    bf16* __restrict__ O)
{
  const int meta = g_tab.grp[4 * blockIdx.x];
  const int first = g_tab.grp[4 * blockIdx.x + 1];
  const int n = g_tab.grp[4 * blockIdx.x + 2];
  const int b = meta & 1, h = (meta >> 1) & 15, qt = (meta >> 5) & 15;
  const int t = threadIdx.x;
  const int row = t >> 1, cg = t & 1;

  float M = -1e30f;
  for (int c = 0; c < n; ++c) M = fmaxf(M, ml[(long long)(first + c) * 256 + row]);

  float acc[64];
#pragma unroll
  for (int j = 0; j < 64; ++j) acc[j] = 0.f;
  float den = 0.f;
  for (int c = 0; c < n; ++c) {
    const float* mlc = ml + (long long)(first + c) * 256;
    float w = exp2f(mlc[row] - M);
    den = fmaf(w, mlc[128 + row], den);
    const bf16* p = parts + (long long)(first + c) * 16384 + row * 128 + cg * 64;
#pragma unroll
    for (int j8 = 0; j8 < 8; ++j8) {
      bf16x8 v = ((const bf16x8*)p)[j8];
#pragma unroll
      for (int k = 0; k < 8; ++k) acc[j8 * 8 + k] = fmaf(w, (float)v[k], acc[j8 * 8 + k]);
    }
  }
  float rd = 1.0f / den;
  long long qg = (long long)b * 2048 + qt * 128 + row;
  bf16* o = O + qg * 2048 + h * 128 + cg * 64;
#pragma unroll
  for (int j8 = 0; j8 < 8; ++j8) {
    bf16x8 v;
#pragma unroll
    for (int k = 0; k < 8; ++k) v[k] = (bf16)(acc[j8 * 8 + k] * rd);
    ((bf16x8*)o)[j8] = v;
  }
}

// ---------------------------------------------------------------------------
extern "C" void kernel_launch(void* const* d_in, const int* in_sizes, int n_in,
                              void* d_out, int out_size, void* d_ws, size_t ws_size,
                              hipStream_t stream) {
  (void)in_sizes; (void)n_in; (void)out_size; (void)ws_size;
  const float* hs  = (const float*)d_in[0];  // [2,2048,2048]
  const float* Wqd = (const float*)d_in[1];  // [1536,2048]
  const float* Wqu = (const float*)d_in[2];  // [2048,1536]
  const float* Wkv = (const float*)d_in[3];  // [512,2048]
  const float* kup = (const float*)d_in[4];  // [16,512,128]
  const float* vup = (const float*)d_in[5];  // [16,512,128]
  const float* Wo  = (const float*)d_in[6];  // [2048,2048]
  float* out = (float*)d_out;                // [2,2048,2048] fp32

  char* ws = (char*)d_ws;
  bf16* hsb  = (bf16*)ws; ws += (size_t)4096 * 2048 * 2;   // [also Ob]
  bf16* Wdcb = (bf16*)ws; ws += (size_t)2048 * 2048 * 2;   // concat(Wqd,Wkv)
  bf16* Wqub = (bf16*)ws; ws += (size_t)2048 * 1536 * 2;
  bf16* kupT = (bf16*)ws; ws += (size_t)16 * 128 * 512 * 2;
  bf16* vupT = (bf16*)ws; ws += (size_t)16 * 128 * 512 * 2;
  bf16* XC   = (bf16*)ws; ws += (size_t)4096 * 2048 * 2;   // [Xq | Cl] [also Wob]
  bf16* Qb   = (bf16*)ws; ws += (size_t)4096 * 2048 * 2;
  bf16* Kb   = (bf16*)ws; ws += (size_t)16 * 4096 * 128 * 2;
  bf16* VTb  = (bf16*)ws; ws += (size_t)16 * 128 * 4096 * 2;
  bf16* Cl   = XC + 1536;   // latent = cols [1536,2048) of XC, ld 2048
  bf16* Ob   = hsb;         // attn out aliases hsb
  bf16* Wob  = XC;          // Wo bf16 aliases XC

  // attention split scratch aliases Wdcb.. (dead by attention time):
  // [ml 448*256 f32][parts 448*128*128 bf16] = 15.1 MB
  float* mld   = (float*)Wdcb;
  bf16*  parts = (bf16*)(mld + 448 * 256);

  // fp32 -> bf16 converts
  cvt_f32_bf16<<<1024, 256, 0, stream>>>(hs, hsb, 4096 * 2048 / 4);
  cvt3_f32_bf16<<<1024, 256, 0, stream>>>(
      Wqd, Wdcb, 1536 * 2048 / 4,
      Wkv, Wdcb + (size_t)1536 * 2048, 512 * 2048 / 4,
      Wqu, Wqub, 2048 * 1536 / 4);
  transpose_cvt<<<dim3(2, 8, 16), 256, 0, stream>>>(kup, kupT, 512, 128);
  transpose_cvt<<<dim3(2, 8, 16), 256, 0, stream>>>(vup, vupT, 512, 128);

  // XC = hs * [Wq_down|Wkv_down]^T   [4096 x 2048 x 2048]
  gemm_nt<bf16><<<dim3(16, 32, 1), 256, 0, stream>>>(hsb, Wdcb, XC,
                                                     2048, 2048, 2048, 2048, 0, 0, 0);
  // Q = Xq * Wq_up^T                 [4096 x 2048 x 1536]
  gemm_nt<bf16><<<dim3(16, 32, 1), 256, 0, stream>>>(XC, Wqub, Qb,
                                                     2048, 1536, 2048, 1536, 0, 0, 0);
  // K[h] = C * k_upT[h]^T            [4096 x 128 x 512] x16
  gemm_nt<bf16><<<dim3(1, 32, 16), 256, 0, stream>>>(Cl, kupT, Kb,
                                                     2048, 512, 128, 512,
                                                     0, 128 * 512, (long long)4096 * 128);
  // VT[h] = v_upT[h] * C^T           [128 x 4096 x 512] x16
  gemm_nt<bf16><<<dim3(32, 1, 16), 256, 0, stream>>>(vupT, Cl, VTb,
                                                     512, 2048, 4096, 512,
                                                     128 * 512, 0, (long long)128 * 4096);
  // Wo convert (into XC region, now dead)
  cvt_f32_bf16<<<512, 256, 0, stream>>>(Wo, Wob, 2048 * 2048 / 4);
  // chunked attention + combine (tables are compile-time constants)
  attn_kernel<<<dim3(ATTN_BLOCKS, 1, 1), 256, 0, stream>>>(Qb, Kb, VTb, Ob, mld, parts);
  attn_combine<<<dim3(COMB_BLOCKS, 1, 1), 256, 0, stream>>>(mld, parts, Ob);
  // out = O * Wo^T                   [4096 x 2048 x 2048], fp32 output
  gemm_nt<float><<<dim3(16, 32, 1), 256, 0, stream>>>(Ob, Wob, out,
                                                      2048, 2048, 2048, 2048, 0, 0, 0);
}

// Round 3
// 434.062 us; speedup vs baseline: 1.1595x; 1.1595x over previous
//
#include <hip/hip_runtime.h>
#include <math.h>

// MLA + ALiBi causal attention. fp32 in/out, bf16 MFMA internal compute.
// R10: fix R9's register spill (WRITE_SIZE 25->127MB = scratch traffic;
// VGPR capped 128 + sv[2][4][4] live across vote). Same verified algorithm
// (reversed tiles, vote-gated fast-path softmax, exp2 domain) restructured
// spill-free: pass A computes ONLY a growth scalar (rm via a different
// expression tree, mask-free overestimate -> safe), pass B recomputes
// scores from s_acc (live anyway) with reference folded into the fma.
// Plain __launch_bounds__(256) (LDS caps occupancy anyway; don't cap VGPR).
typedef __bf16 bf16;
typedef __bf16 bf16x8 __attribute__((ext_vector_type(8)));
typedef __bf16 bf16x4 __attribute__((ext_vector_type(4)));
typedef float f32x4 __attribute__((ext_vector_type(4)));

#define AS1 __attribute__((address_space(1)))
#define AS3 __attribute__((address_space(3)))

// Exact static decomposition (L=2048, 128-row q tiles, 64-key kv tiles,
// chunk = 8 kv tiles, ALiBi window WH[h]): per b: 172 direct + 224 chunks,
// 84 groups. Totals: 344 direct + 448 partial = 792 blocks; 168 groups.
#define ATTN_BLOCKS 792
#define COMB_BLOCKS 168

struct ATables {
  int tbl[ATTN_BLOCKS * 2];   // {meta, partIdx(-1=direct)}
  int grp[COMB_BLOCKS * 4];   // {meta, firstPart, nChunks, pad}
};

// meta = b | h<<1 | qt<<5 | cstart<<9 | clen<<16
constexpr ATables make_tables() {
  ATables T{};
  int WH[16] = {22,32,45,64,90,128,181,256,362,512,724,1024,1448,2048,2896,4096};
  int nc = 0, np = 0, ng = 0;
  for (int qt = 15; qt >= 0; --qt)
    for (int h = 15; h >= 0; --h)
      for (int b = 0; b < 2; ++b) {
        int q0 = qt * 128, nkv = 2 * qt + 2;
        int dlo = q0 - WH[h];
        int kv_lo = dlo > 0 ? (dlo >> 6) : 0;
        int span = nkv - kv_lo;
        int nch = (span + 7) >> 3;
        int base = b | (h << 1) | (qt << 5);
        if (nch == 1) {
          T.tbl[2 * nc] = base | (kv_lo << 9) | (span << 16);
          T.tbl[2 * nc + 1] = -1;
          ++nc;
        } else {
          T.grp[4 * ng] = base; T.grp[4 * ng + 1] = np; T.grp[4 * ng + 2] = nch;
          ++ng;
          for (int c = 0; c < nch; ++c) {
            int cs = kv_lo + c * 8;
            int cl = nkv - cs; if (cl > 8) cl = 8;
            T.tbl[2 * nc] = base | (cs << 9) | (cl << 16);
            T.tbl[2 * nc + 1] = np;
            ++nc; ++np;
          }
        }
      }
  return T;
}

__device__ const ATables g_tab = make_tables();

__device__ __forceinline__ void g2l16(const void* g, void* l) {
  // async global->LDS, 16B per lane; LDS dest is wave-uniform base + lane*16
  __builtin_amdgcn_global_load_lds((const AS1 void*)g, (AS3 void*)l, 16, 0, 0);
}

// ---------------------------------------------------------------------------
// fp32 -> bf16 elementwise convert (n4 = element count / 4)
// ---------------------------------------------------------------------------
__device__ __forceinline__ void cvt_seg(const float* __restrict__ in,
                                        bf16* __restrict__ out, int n4) {
  int i = blockIdx.x * 256 + threadIdx.x;
  const int stride = gridDim.x * 256;
  for (; i < n4; i += stride) {
    float4 v = ((const float4*)in)[i];
    bf16x4 o;
    o[0] = (bf16)v.x; o[1] = (bf16)v.y; o[2] = (bf16)v.z; o[3] = (bf16)v.w;
    ((bf16x4*)out)[i] = o;
  }
}

__global__ __launch_bounds__(256) void cvt_f32_bf16(
    const float* __restrict__ in, bf16* __restrict__ out, int n4) {
  cvt_seg(in, out, n4);
}

__global__ __launch_bounds__(256) void cvt3_f32_bf16(
    const float* __restrict__ s0, bf16* __restrict__ d0, int n0,
    const float* __restrict__ s1, bf16* __restrict__ d1, int n1,
    const float* __restrict__ s2, bf16* __restrict__ d2, int n2) {
  cvt_seg(s0, d0, n0);
  cvt_seg(s1, d1, n1);
  cvt_seg(s2, d2, n2);
}

// ---------------------------------------------------------------------------
// fused convert+transpose: fp32 [Z][R][D] -> bf16 [Z][D][R]. R%64==0, D%64==0.
// ---------------------------------------------------------------------------
__global__ __launch_bounds__(256) void transpose_cvt(
    const float* __restrict__ in, bf16* __restrict__ out, int R, int D)
{
  __shared__ bf16 tile[64][72];
  const long long base = (long long)blockIdx.z * R * D;
  const int r0 = blockIdx.y * 64, c0 = blockIdx.x * 64;
  const int t = threadIdx.x;
#pragma unroll
  for (int i = 0; i < 4; ++i) {
    int c = i * 256 + t;
    int rr = c >> 4, cc = (c & 15) << 2;
    float4 v = *(const float4*)&in[base + (long long)(r0 + rr) * D + c0 + cc];
    tile[rr][cc + 0] = (bf16)v.x;
    tile[rr][cc + 1] = (bf16)v.y;
    tile[rr][cc + 2] = (bf16)v.z;
    tile[rr][cc + 3] = (bf16)v.w;
  }
  __syncthreads();
#pragma unroll
  for (int i = 0; i < 2; ++i) {
    int c = i * 256 + t;
    int rr = c >> 3, cc = (c & 7) << 3;
    bf16x8 v;
#pragma unroll
    for (int j = 0; j < 8; ++j) v[j] = tile[cc + j][rr];
    *(bf16x8*)&out[base + (long long)(c0 + rr) * R + r0 + cc] = v;
  }
}

// ---------------------------------------------------------------------------
// NT GEMM: C[m,n] = sum_k A[m,k]*B[n,k]. 128x128 tile, BK=32, 4 waves.
// ---------------------------------------------------------------------------
template <typename CT>
__global__ __launch_bounds__(256) void gemm_nt(
    const bf16* __restrict__ A, const bf16* __restrict__ B, CT* __restrict__ C,
    int lda, int ldb, int ldc, int K, long long sA, long long sB, long long sC)
{
  A += (long long)blockIdx.z * sA;
  B += (long long)blockIdx.z * sB;
  C += (long long)blockIdx.z * sC;

  __shared__ bf16 As[128][32];
  __shared__ bf16 Bs[128][32];

  const int t = threadIdx.x;
  const int lane = t & 63, wave = t >> 6;
  const int wm = (wave >> 1) * 64, wn = (wave & 1) * 64;
  const int m0 = blockIdx.y * 128, n0 = blockIdx.x * 128;
  const int r16 = lane & 15, q8 = (lane >> 4) * 8;

  f32x4 acc[4][4] = {};

  for (int k0 = 0; k0 < K; k0 += 32) {
    __syncthreads();
#pragma unroll
    for (int r = 0; r < 2; ++r) {
      int c = r * 256 + t;
      int row = c >> 2, col = (c & 3) << 3;
      g2l16(A + (long long)(m0 + row) * lda + (k0 + col), &As[row][col]);
      g2l16(B + (long long)(n0 + row) * ldb + (k0 + col), &Bs[row][col]);
    }
    __syncthreads();

    bf16x8 af[4], bfr[4];
#pragma unroll
    for (int i = 0; i < 4; ++i) af[i]  = *(const bf16x8*)&As[wm + i * 16 + r16][q8];
#pragma unroll
    for (int i = 0; i < 4; ++i) bfr[i] = *(const bf16x8*)&Bs[wn + i * 16 + r16][q8];
#pragma unroll
    for (int mi = 0; mi < 4; ++mi)
#pragma unroll
      for (int ni = 0; ni < 4; ++ni)
        acc[mi][ni] = __builtin_amdgcn_mfma_f32_16x16x32_bf16(af[mi], bfr[ni], acc[mi][ni], 0, 0, 0);
  }

  const int quad = lane >> 4;
#pragma unroll
  for (int mi = 0; mi < 4; ++mi)
#pragma unroll
    for (int ni = 0; ni < 4; ++ni)
#pragma unroll
      for (int r = 0; r < 4; ++r) {
        int mm = m0 + wm + mi * 16 + quad * 4 + r;
        int nn = n0 + wn + ni * 16 + r16;
        C[(long long)mm * ldc + nn] = (CT)acc[mi][ni][r];
      }
}

// ---------------------------------------------------------------------------
// Flash attention, chunked + double-buffered, 64-key tiles, REVERSED order.
// Block = table entry: 128 q rows of (b,h,qt) over KV tiles [cs,cs+cl),
// iterated cend-1 .. cs (diagonal first). K/V double-buffered in LDS (80KB);
// ONE barrier per tile (Psf is wave-private). Prefetch issued right after
// the barrier. Softmax: scores in exp2 domain; pass A computes a single
// growth scalar per lane (row-max via a separate expression tree, no mask
// -> safe overestimate); wave vote; fast path (common) recomputes P from
// s_acc with reference folded into the fma -- no shuffles, no rescale, no
// m-update (shift-invariance). Slow path (tile 0 / rare) = full 16-lane
// reduce + rescale. Causal mask on tiles >= nkv-2. LDS XOR-swizzled.
// ---------------------------------------------------------------------------
__global__ __launch_bounds__(256) void attn_kernel(
    const bf16* __restrict__ Q, const bf16* __restrict__ Kh,
    const bf16* __restrict__ VT, bf16* __restrict__ O,
    float* __restrict__ ml, bf16* __restrict__ parts)
{
  const int L = 2048, HD = 128, D = 2048;
  const int meta = g_tab.tbl[2 * blockIdx.x];
  const int part = g_tab.tbl[2 * blockIdx.x + 1];
  const int b = meta & 1, h = (meta >> 1) & 15, qt = (meta >> 5) & 15;
  const int cs = (meta >> 9) & 127, cl = (meta >> 16) & 15;
  const int q0 = qt * 128, nkv = 2 * qt + 2;
  const int cend = cs + cl;
  // mask any diagonal tile (>= nkv-2) present in this chunk:
  const int mraw = nkv - 2 > cs ? nkv - 2 : cs;
  const int mstart = mraw < cend ? mraw : cend;

  const int t = threadIdx.x, wave = t >> 6, lane = t & 63;
  const int col = lane & 15, quad = lane >> 4;
  const float LOG2E = 1.44269504f;
  const float slope2 = exp2f(-0.5f * (float)(h + 1)) * LOG2E;  // exp2-domain
  const float slope16 = slope2 * 16.0f;
  const float scale2 = 0.08838834764831845f * LOG2E;   // (1/sqrt(128))*log2e

  __shared__ bf16 Ksf[2][64 * 128];   // [key][d],  16 chunks/row, swz mask 15
  __shared__ bf16 Vsf[2][128 * 64];   // [d][key],   8 chunks/row, swz mask 7
  __shared__ bf16 Psf[128 * 64];      // [q][key],  wave-private 32-row bands

  const long long qrow0 = (long long)(b * L + q0 + wave * 32);
  const long long kbase = (long long)(h * 4096 + b * L) * HD;
  const long long vbase = (long long)(h * HD) * 4096 + b * L;

  auto stage = [&](int buf, int itile) {
    const int kv0 = itile << 6;
#pragma unroll
    for (int i = 0; i < 4; ++i) {
      int P = i * 256 + t;   // physical 16B chunk index (contiguous per wave)
      {  // K: row = P>>4, phys chunk p = P&15, logical chunk = p ^ (row&15)
        int rr = P >> 4, cc = ((P & 15) ^ (rr & 15)) << 3;
        g2l16(Kh + kbase + (long long)(kv0 + rr) * HD + cc, &Ksf[buf][P * 8]);
      }
      {  // V: row = P>>3, phys chunk p = P&7, logical chunk = p ^ (row&7)
        int rr = P >> 3, cc = ((P & 7) ^ (rr & 7)) << 3;
        g2l16(VT + vbase + (long long)rr * 4096 + kv0 + cc, &Vsf[buf][P * 8]);
      }
    }
  };

  bf16x8 qf[2][4];
#pragma unroll
  for (int mi = 0; mi < 2; ++mi)
#pragma unroll
    for (int ks = 0; ks < 4; ++ks)
      qf[mi][ks] = *(const bf16x8*)&Q[(qrow0 + mi * 16 + col) * D + h * HD + ks * 32 + quad * 8];

  f32x4 o_acc[2][8] = {};
  float m_i[2][4], l_i[2][4];   // l lane-partial (this lane's 4 cols)
#pragma unroll
  for (int mi = 0; mi < 2; ++mi)
#pragma unroll
    for (int r = 0; r < 4; ++r) { m_i[mi][r] = -1e30f; l_i[mi][r] = 0.f; }

  stage(0, cend - 1);

  for (int it = cend - 1; it >= cs; --it) {
    const int cur = (cend - 1 - it) & 1;
    const int kv0 = it << 6;
    const bool masked = (it >= mstart);   // wave-uniform

    __syncthreads();                      // drains vmcnt: Ks/Vs[cur] ready
    if (it > cs) stage(cur ^ 1, it - 1);  // prefetch next (older) tile

    // S = Q K^T  (per wave: 2 m-tiles x 4 n-tiles, 4 k-steps over d=128)
    f32x4 s_acc[2][4] = {};
    __builtin_amdgcn_s_setprio(1);
#pragma unroll
    for (int ks = 0; ks < 4; ++ks) {
      bf16x8 kf[4];
#pragma unroll
      for (int ni = 0; ni < 4; ++ni)
        kf[ni] = *(const bf16x8*)&Ksf[cur][(ni * 16 + col) * 128 +
                                          (((ks * 4 + quad) ^ col) << 3)];
#pragma unroll
      for (int mi = 0; mi < 2; ++mi)
#pragma unroll
        for (int ni = 0; ni < 4; ++ni)
          s_acc[mi][ni] = __builtin_amdgcn_mfma_f32_16x16x32_bf16(
              qf[mi][ks], kf[ni], s_acc[mi][ni], 0, 0, 0);
    }
    __builtin_amdgcn_s_setprio(0);

    // pass A: single growth scalar per lane. Row max via max over ni of
    // fmaf(s, scale2, ni*slope16) minus sb -- a DIFFERENT expression tree
    // than pass B (no CSE -> nothing but `grow` stays live). Mask ignored:
    // overestimated rm only ever forces the always-correct slow path.
    float grow = -1e30f;
#pragma unroll
    for (int mi = 0; mi < 2; ++mi)
#pragma unroll
      for (int r = 0; r < 4; ++r) {
        const int rowq = wave * 32 + mi * 16 + quad * 4 + r;
        const int qg = q0 + rowq;
        const float sb = slope2 * (float)(qg - kv0 - col);   // dist at ni=0
        float t0 = fmaxf(
            fmaxf(fmaf(s_acc[mi][0][r], scale2, 0.0f * slope16),
                  fmaf(s_acc[mi][1][r], scale2, 1.0f * slope16)),
            fmaxf(fmaf(s_acc[mi][2][r], scale2, 2.0f * slope16),
                  fmaf(s_acc[mi][3][r], scale2, 3.0f * slope16)));
        grow = fmaxf(grow, (t0 - sb) - m_i[mi][r]);
      }

    if (!__any(grow > 20.0f)) {
      // fast path: reference m is safe (P <= 2^20); no reduce, no rescale,
      // no m-update. pv = exp2(fma(s, scale2, ni*slope16 - sb - mref)).
#pragma unroll
      for (int mi = 0; mi < 2; ++mi)
#pragma unroll
        for (int r = 0; r < 4; ++r) {
          const int rowq = wave * 32 + mi * 16 + quad * 4 + r;
          const int qg = q0 + rowq;
          const float c0 = -slope2 * (float)(qg - kv0 - col) - m_i[mi][r];
          float ps = 0.f;
#pragma unroll
          for (int ni = 0; ni < 4; ++ni) {
            float pv = exp2f(fmaf(s_acc[mi][ni][r], scale2,
                                  (float)ni * slope16 + c0));
            if (masked && (kv0 + ni * 16 + col > qg)) pv = 0.f;
            ps += pv;
            Psf[rowq * 64 + ((((ni * 2) + (col >> 3)) ^ (rowq & 7)) << 3) +
                (col & 7)] = (bf16)pv;
          }
          l_i[mi][r] += ps;
        }
    } else {
      // slow path (tile 0 / rare excursion): full reduce + rescale.
#pragma unroll
      for (int mi = 0; mi < 2; ++mi)
#pragma unroll
        for (int r = 0; r < 4; ++r) {
          const int rowq = wave * 32 + mi * 16 + quad * 4 + r;
          const int qg = q0 + rowq;
          const float sb = slope2 * (float)(qg - kv0 - col);
          float svv[4];
#pragma unroll
          for (int ni = 0; ni < 4; ++ni) {
            svv[ni] = fmaf(s_acc[mi][ni][r], scale2, (float)ni * slope16 - sb);
            if (masked && (kv0 + ni * 16 + col > qg)) svv[ni] = -1e30f;
          }
          float rm = fmaxf(fmaxf(svv[0], svv[1]), fmaxf(svv[2], svv[3]));
#pragma unroll
          for (int off = 1; off < 16; off <<= 1)
            rm = fmaxf(rm, __shfl_xor(rm, off, 64));
          const float mold = m_i[mi][r];
          float mnew = fmaxf(mold, rm);
          if (masked) mnew = fmaxf(mnew, -1e20f);   // all-masked-row floor
          const float alpha = exp2f(mold - mnew);
          float ps = 0.f;
#pragma unroll
          for (int ni = 0; ni < 4; ++ni) {
            float pv = exp2f(svv[ni] - mnew);
            ps += pv;
            Psf[rowq * 64 + ((((ni * 2) + (col >> 3)) ^ (rowq & 7)) << 3) +
                (col & 7)] = (bf16)pv;
          }
          l_i[mi][r] = fmaf(alpha, l_i[mi][r], ps);
          m_i[mi][r] = mnew;
#pragma unroll
          for (int di = 0; di < 8; ++di) o_acc[mi][di][r] *= alpha;
        }
    }

    // O += P V (no barrier needed: Psf band is wave-private; Vs double-buffered)
    __builtin_amdgcn_s_setprio(1);
#pragma unroll
    for (int kstep = 0; kstep < 2; ++kstep) {
      bf16x8 pf[2];
#pragma unroll
      for (int mi = 0; mi < 2; ++mi)
        pf[mi] = *(const bf16x8*)&Psf[(wave * 32 + mi * 16 + col) * 64 +
                                      (((kstep * 4 + quad) ^ (col & 7)) << 3)];
#pragma unroll
      for (int di = 0; di < 8; ++di) {
        bf16x8 vf = *(const bf16x8*)&Vsf[cur][(di * 16 + col) * 64 +
                                             (((kstep * 4 + quad) ^ (col & 7)) << 3)];
#pragma unroll
        for (int mi = 0; mi < 2; ++mi)
          o_acc[mi][di] = __builtin_amdgcn_mfma_f32_16x16x32_bf16(
              pf[mi], vf, o_acc[mi][di], 0, 0, 0);
      }
    }
    __builtin_amdgcn_s_setprio(0);
  }

  if (part < 0) {
    // direct: normalize (reduce lane-partial l over the 16-lane row group)
#pragma unroll
    for (int mi = 0; mi < 2; ++mi)
#pragma unroll
      for (int r = 0; r < 4; ++r) {
        float lt = l_i[mi][r];
#pragma unroll
        for (int off = 1; off < 16; off <<= 1)
          lt += __shfl_xor(lt, off, 64);
        float rl = 1.0f / lt;
        long long qg = qrow0 + mi * 16 + quad * 4 + r;
#pragma unroll
        for (int di = 0; di < 8; ++di)
          O[qg * D + h * HD + di * 16 + col] = (bf16)(o_acc[mi][di][r] * rl);
      }
  } else {
    // partial: store unnormalized O~ (bf16) + m,l (fp32 per row)
    bf16* pb = parts + (long long)part * 16384;
    float* mlp = ml + (long long)part * 256;
#pragma unroll
    for (int mi = 0; mi < 2; ++mi)
#pragma unroll
      for (int r = 0; r < 4; ++r) {
        float lt = l_i[mi][r];
#pragma unroll
        for (int off = 1; off < 16; off <<= 1)
          lt += __shfl_xor(lt, off, 64);
        int rowq = wave * 32 + mi * 16 + quad * 4 + r;
        if (col == 0) { mlp[rowq] = m_i[mi][r]; mlp[128 + rowq] = lt; }
#pragma unroll
        for (int di = 0; di < 8; ++di)
          pb[rowq * 128 + di * 16 + col] = (bf16)o_acc[mi][di][r];
      }
  }
}

// ---------------------------------------------------------------------------
// Combine partial chunks: O = sum_c e2^(m_c-M) O~_c / sum_c e2^(m_c-M) l_c.
// (m are exp2-domain references; weights use exp2f.) One block per group;
// thread t: row = t>>1, cols (t&1)*64..+63.
// ---------------------------------------------------------------------------
__global__ __launch_bounds__(256) void attn_combine(
    const float* __restrict__ ml, const bf16* __restrict__ parts,
    bf16* __restrict__ O)
{
  const int meta = g_tab.grp[4 * blockIdx.x];
  const int first = g_tab.grp[4 * blockIdx.x + 1];
  const int n = g_tab.grp[4 * blockIdx.x + 2];
  const int b = meta & 1, h = (meta >> 1) & 15, qt = (meta >> 5) & 15;
  const int t = threadIdx.x;
  const int row = t >> 1, cg = t & 1;

  float M = -1e30f;
  for (int c = 0; c < n; ++c) M = fmaxf(M, ml[(long long)(first + c) * 256 + row]);

  float acc[64];
#pragma unroll
  for (int j = 0; j < 64; ++j) acc[j] = 0.f;
  float den = 0.f;
  for (int c = 0; c < n; ++c) {
    const float* mlc = ml + (long long)(first + c) * 256;
    float w = exp2f(mlc[row] - M);
    den = fmaf(w, mlc[128 + row], den);
    const bf16* p = parts + (long long)(first + c) * 16384 + row * 128 + cg * 64;
#pragma unroll
    for (int j8 = 0; j8 < 8; ++j8) {
      bf16x8 v = ((const bf16x8*)p)[j8];
#pragma unroll
      for (int k = 0; k < 8; ++k) acc[j8 * 8 + k] = fmaf(w, (float)v[k], acc[j8 * 8 + k]);
    }
  }
  float rd = 1.0f / den;
  long long qg = (long long)b * 2048 + qt * 128 + row;
  bf16* o = O + qg * 2048 + h * 128 + cg * 64;
#pragma unroll
  for (int j8 = 0; j8 < 8; ++j8) {
    bf16x8 v;
#pragma unroll
    for (int k = 0; k < 8; ++k) v[k] = (bf16)(acc[j8 * 8 + k] * rd);
    ((bf16x8*)o)[j8] = v;
  }
}

// ---------------------------------------------------------------------------
extern "C" void kernel_launch(void* const* d_in, const int* in_sizes, int n_in,
                              void* d_out, int out_size, void* d_ws, size_t ws_size,
                              hipStream_t stream) {
  (void)in_sizes; (void)n_in; (void)out_size; (void)ws_size;
  const float* hs  = (const float*)d_in[0];  // [2,2048,2048]
  const float* Wqd = (const float*)d_in[1];  // [1536,2048]
  const float* Wqu = (const float*)d_in[2];  // [2048,1536]
  const float* Wkv = (const float*)d_in[3];  // [512,2048]
  const float* kup = (const float*)d_in[4];  // [16,512,128]
  const float* vup = (const float*)d_in[5];  // [16,512,128]
  const float* Wo  = (const float*)d_in[6];  // [2048,2048]
  float* out = (float*)d_out;                // [2,2048,2048] fp32

  char* ws = (char*)d_ws;
  bf16* hsb  = (bf16*)ws; ws += (size_t)4096 * 2048 * 2;   // [also Ob]
  bf16* Wdcb = (bf16*)ws; ws += (size_t)2048 * 2048 * 2;   // concat(Wqd,Wkv)
  bf16* Wqub = (bf16*)ws; ws += (size_t)2048 * 1536 * 2;
  bf16* kupT = (bf16*)ws; ws += (size_t)16 * 128 * 512 * 2;
  bf16* vupT = (bf16*)ws; ws += (size_t)16 * 128 * 512 * 2;
  bf16* XC   = (bf16*)ws; ws += (size_t)4096 * 2048 * 2;   // [Xq | Cl] [also Wob]
  bf16* Qb   = (bf16*)ws; ws += (size_t)4096 * 2048 * 2;
  bf16* Kb   = (bf16*)ws; ws += (size_t)16 * 4096 * 128 * 2;
  bf16* VTb  = (bf16*)ws; ws += (size_t)16 * 128 * 4096 * 2;
  bf16* Cl   = XC + 1536;   // latent = cols [1536,2048) of XC, ld 2048
  bf16* Ob   = hsb;         // attn out aliases hsb
  bf16* Wob  = XC;          // Wo bf16 aliases XC

  // attention split scratch aliases Wdcb.. (dead by attention time):
  // [ml 448*256 f32][parts 448*128*128 bf16] = 15.1 MB
  float* mld   = (float*)Wdcb;
  bf16*  parts = (bf16*)(mld + 448 * 256);

  // fp32 -> bf16 converts
  cvt_f32_bf16<<<1024, 256, 0, stream>>>(hs, hsb, 4096 * 2048 / 4);
  cvt3_f32_bf16<<<1024, 256, 0, stream>>>(
      Wqd, Wdcb, 1536 * 2048 / 4,
      Wkv, Wdcb + (size_t)1536 * 2048, 512 * 2048 / 4,
      Wqu, Wqub, 2048 * 1536 / 4);
  transpose_cvt<<<dim3(2, 8, 16), 256, 0, stream>>>(kup, kupT, 512, 128);
  transpose_cvt<<<dim3(2, 8, 16), 256, 0, stream>>>(vup, vupT, 512, 128);

  // XC = hs * [Wq_down|Wkv_down]^T   [4096 x 2048 x 2048]
  gemm_nt<bf16><<<dim3(16, 32, 1), 256, 0, stream>>>(hsb, Wdcb, XC,
                                                     2048, 2048, 2048, 2048, 0, 0, 0);
  // Q = Xq * Wq_up^T                 [4096 x 2048 x 1536]
  gemm_nt<bf16><<<dim3(16, 32, 1), 256, 0, stream>>>(XC, Wqub, Qb,
                                                     2048, 1536, 2048, 1536, 0, 0, 0);
  // K[h] = C * k_upT[h]^T            [4096 x 128 x 512] x16
  gemm_nt<bf16><<<dim3(1, 32, 16), 256, 0, stream>>>(Cl, kupT, Kb,
                                                     2048, 512, 128, 512,
                                                     0, 128 * 512, (long long)4096 * 128);
  // VT[h] = v_upT[h] * C^T           [128 x 4096 x 512] x16
  gemm_nt<bf16><<<dim3(32, 1, 16), 256, 0, stream>>>(vupT, Cl, VTb,
                                                     512, 2048, 4096, 512,
                                                     128 * 512, 0, (long long)128 * 4096);
  // Wo convert (into XC region, now dead)
  cvt_f32_bf16<<<512, 256, 0, stream>>>(Wo, Wob, 2048 * 2048 / 4);
  // chunked attention + combine (tables are compile-time constants)
  attn_kernel<<<dim3(ATTN_BLOCKS, 1, 1), 256, 0, stream>>>(Qb, Kb, VTb, Ob, mld, parts);
  attn_combine<<<dim3(COMB_BLOCKS, 1, 1), 256, 0, stream>>>(mld, parts, Ob);
  // out = O * Wo^T                   [4096 x 2048 x 2048], fp32 output
  gemm_nt<float><<<dim3(16, 32, 1), 256, 0, stream>>>(Ob, Wob, out,
                                                      2048, 2048, 2048, 2048, 0, 0, 0);
}

// Round 5
// 424.220 us; speedup vs baseline: 1.1864x; 1.0232x over previous
//
#include <hip/hip_runtime.h>
#include <math.h>

// MLA + ALiBi causal attention. fp32 in/out, bf16 MFMA internal compute.
// R11 (resubmit; prior bench failed on container acquisition, no data).
// attn occupancy via LDS 80->64KB. Evidence: at 80KB occupancy ~8%
// (1 block/CU; 2x80KB does not co-schedule), at 40KB it was 23.8%. Fix:
// single-buffer K (V stays dbuf, Psf unchanged) = 16+32+16 = 64KB -> 2
// blocks/CU. Cost: +1 barrier per tile (after QK's K-reads, before staging
// next K over the single buffer). Stage moves after that barrier; its drain
// is the NEXT tile's first barrier, so prefetch window = softmax+PV.
// Access patterns byte-identical to R10 (FETCH must stay ~48MB).
typedef __bf16 bf16;
typedef __bf16 bf16x8 __attribute__((ext_vector_type(8)));
typedef __bf16 bf16x4 __attribute__((ext_vector_type(4)));
typedef float f32x4 __attribute__((ext_vector_type(4)));

#define AS1 __attribute__((address_space(1)))
#define AS3 __attribute__((address_space(3)))

// Exact static decomposition (L=2048, 128-row q tiles, 64-key kv tiles,
// chunk = 8 kv tiles, ALiBi window WH[h]): per b: 172 direct + 224 chunks,
// 84 groups. Totals: 344 direct + 448 partial = 792 blocks; 168 groups.
#define ATTN_BLOCKS 792
#define COMB_BLOCKS 168

struct ATables {
  int tbl[ATTN_BLOCKS * 2];   // {meta, partIdx(-1=direct)}
  int grp[COMB_BLOCKS * 4];   // {meta, firstPart, nChunks, pad}
};

// meta = b | h<<1 | qt<<5 | cstart<<9 | clen<<16
constexpr ATables make_tables() {
  ATables T{};
  int WH[16] = {22,32,45,64,90,128,181,256,362,512,724,1024,1448,2048,2896,4096};
  int nc = 0, np = 0, ng = 0;
  for (int qt = 15; qt >= 0; --qt)
    for (int h = 15; h >= 0; --h)
      for (int b = 0; b < 2; ++b) {
        int q0 = qt * 128, nkv = 2 * qt + 2;
        int dlo = q0 - WH[h];
        int kv_lo = dlo > 0 ? (dlo >> 6) : 0;
        int span = nkv - kv_lo;
        int nch = (span + 7) >> 3;
        int base = b | (h << 1) | (qt << 5);
        if (nch == 1) {
          T.tbl[2 * nc] = base | (kv_lo << 9) | (span << 16);
          T.tbl[2 * nc + 1] = -1;
          ++nc;
        } else {
          T.grp[4 * ng] = base; T.grp[4 * ng + 1] = np; T.grp[4 * ng + 2] = nch;
          ++ng;
          for (int c = 0; c < nch; ++c) {
            int cs = kv_lo + c * 8;
            int cl = nkv - cs; if (cl > 8) cl = 8;
            T.tbl[2 * nc] = base | (cs << 9) | (cl << 16);
            T.tbl[2 * nc + 1] = np;
            ++nc; ++np;
          }
        }
      }
  return T;
}

__device__ const ATables g_tab = make_tables();

__device__ __forceinline__ void g2l16(const void* g, void* l) {
  // async global->LDS, 16B per lane; LDS dest is wave-uniform base + lane*16
  __builtin_amdgcn_global_load_lds((const AS1 void*)g, (AS3 void*)l, 16, 0, 0);
}

// ---------------------------------------------------------------------------
// fp32 -> bf16 elementwise convert (n4 = element count / 4)
// ---------------------------------------------------------------------------
__device__ __forceinline__ void cvt_seg(const float* __restrict__ in,
                                        bf16* __restrict__ out, int n4) {
  int i = blockIdx.x * 256 + threadIdx.x;
  const int stride = gridDim.x * 256;
  for (; i < n4; i += stride) {
    float4 v = ((const float4*)in)[i];
    bf16x4 o;
    o[0] = (bf16)v.x; o[1] = (bf16)v.y; o[2] = (bf16)v.z; o[3] = (bf16)v.w;
    ((bf16x4*)out)[i] = o;
  }
}

__global__ __launch_bounds__(256) void cvt_f32_bf16(
    const float* __restrict__ in, bf16* __restrict__ out, int n4) {
  cvt_seg(in, out, n4);
}

__global__ __launch_bounds__(256) void cvt3_f32_bf16(
    const float* __restrict__ s0, bf16* __restrict__ d0, int n0,
    const float* __restrict__ s1, bf16* __restrict__ d1, int n1,
    const float* __restrict__ s2, bf16* __restrict__ d2, int n2) {
  cvt_seg(s0, d0, n0);
  cvt_seg(s1, d1, n1);
  cvt_seg(s2, d2, n2);
}

// ---------------------------------------------------------------------------
// fused convert+transpose: fp32 [Z][R][D] -> bf16 [Z][D][R]. R%64==0, D%64==0.
// ---------------------------------------------------------------------------
__global__ __launch_bounds__(256) void transpose_cvt(
    const float* __restrict__ in, bf16* __restrict__ out, int R, int D)
{
  __shared__ bf16 tile[64][72];
  const long long base = (long long)blockIdx.z * R * D;
  const int r0 = blockIdx.y * 64, c0 = blockIdx.x * 64;
  const int t = threadIdx.x;
#pragma unroll
  for (int i = 0; i < 4; ++i) {
    int c = i * 256 + t;
    int rr = c >> 4, cc = (c & 15) << 2;
    float4 v = *(const float4*)&in[base + (long long)(r0 + rr) * D + c0 + cc];
    tile[rr][cc + 0] = (bf16)v.x;
    tile[rr][cc + 1] = (bf16)v.y;
    tile[rr][cc + 2] = (bf16)v.z;
    tile[rr][cc + 3] = (bf16)v.w;
  }
  __syncthreads();
#pragma unroll
  for (int i = 0; i < 2; ++i) {
    int c = i * 256 + t;
    int rr = c >> 3, cc = (c & 7) << 3;
    bf16x8 v;
#pragma unroll
    for (int j = 0; j < 8; ++j) v[j] = tile[cc + j][rr];
    *(bf16x8*)&out[base + (long long)(c0 + rr) * R + r0 + cc] = v;
  }
}

// ---------------------------------------------------------------------------
// NT GEMM: C[m,n] = sum_k A[m,k]*B[n,k]. 128x128 tile, BK=32, 4 waves.
// ---------------------------------------------------------------------------
template <typename CT>
__global__ __launch_bounds__(256) void gemm_nt(
    const bf16* __restrict__ A, const bf16* __restrict__ B, CT* __restrict__ C,
    int lda, int ldb, int ldc, int K, long long sA, long long sB, long long sC)
{
  A += (long long)blockIdx.z * sA;
  B += (long long)blockIdx.z * sB;
  C += (long long)blockIdx.z * sC;

  __shared__ bf16 As[128][32];
  __shared__ bf16 Bs[128][32];

  const int t = threadIdx.x;
  const int lane = t & 63, wave = t >> 6;
  const int wm = (wave >> 1) * 64, wn = (wave & 1) * 64;
  const int m0 = blockIdx.y * 128, n0 = blockIdx.x * 128;
  const int r16 = lane & 15, q8 = (lane >> 4) * 8;

  f32x4 acc[4][4] = {};

  for (int k0 = 0; k0 < K; k0 += 32) {
    __syncthreads();
#pragma unroll
    for (int r = 0; r < 2; ++r) {
      int c = r * 256 + t;
      int row = c >> 2, col = (c & 3) << 3;
      g2l16(A + (long long)(m0 + row) * lda + (k0 + col), &As[row][col]);
      g2l16(B + (long long)(n0 + row) * ldb + (k0 + col), &Bs[row][col]);
    }
    __syncthreads();

    bf16x8 af[4], bfr[4];
#pragma unroll
    for (int i = 0; i < 4; ++i) af[i]  = *(const bf16x8*)&As[wm + i * 16 + r16][q8];
#pragma unroll
    for (int i = 0; i < 4; ++i) bfr[i] = *(const bf16x8*)&Bs[wn + i * 16 + r16][q8];
#pragma unroll
    for (int mi = 0; mi < 4; ++mi)
#pragma unroll
      for (int ni = 0; ni < 4; ++ni)
        acc[mi][ni] = __builtin_amdgcn_mfma_f32_16x16x32_bf16(af[mi], bfr[ni], acc[mi][ni], 0, 0, 0);
  }

  const int quad = lane >> 4;
#pragma unroll
  for (int mi = 0; mi < 4; ++mi)
#pragma unroll
    for (int ni = 0; ni < 4; ++ni)
#pragma unroll
      for (int r = 0; r < 4; ++r) {
        int mm = m0 + wm + mi * 16 + quad * 4 + r;
        int nn = n0 + wn + ni * 16 + r16;
        C[(long long)mm * ldc + nn] = (CT)acc[mi][ni][r];
      }
}

// ---------------------------------------------------------------------------
// Flash attention, chunked, 64-key tiles, REVERSED order (diagonal first).
// Block = table entry: 128 q rows of (b,h,qt) over KV tiles [cs,cs+cl),
// iterated cend-1 .. cs. K SINGLE-buffered, V double-buffered, Psf wave-
// private => LDS 64KB => 2 blocks/CU. Two barriers per tile:
//   A: drains vmcnt (K + V[cur] staged) / all waves left prev K section
//   QK^T (K consumed into regs)
//   B: all waves done reading Ksf -> safe to overwrite
//   stage K(next) + V(next) ; softmax ; PV (Vsf[cur], Psf)
// Softmax: exp2 domain, vote-gated fast path (no reduce/rescale; pass A
// growth scalar via separate expression tree). Slow path = full reduce.
// Causal mask on tiles >= nkv-2. LDS XOR-swizzled (conflict-free).
// ---------------------------------------------------------------------------
__global__ __launch_bounds__(256) void attn_kernel(
    const bf16* __restrict__ Q, const bf16* __restrict__ Kh,
    const bf16* __restrict__ VT, bf16* __restrict__ O,
    float* __restrict__ ml, bf16* __restrict__ parts)
{
  const int L = 2048, HD = 128, D = 2048;
  const int meta = g_tab.tbl[2 * blockIdx.x];
  const int part = g_tab.tbl[2 * blockIdx.x + 1];
  const int b = meta & 1, h = (meta >> 1) & 15, qt = (meta >> 5) & 15;
  const int cs = (meta >> 9) & 127, cl = (meta >> 16) & 15;
  const int q0 = qt * 128, nkv = 2 * qt + 2;
  const int cend = cs + cl;
  // mask any diagonal tile (>= nkv-2) present in this chunk:
  const int mraw = nkv - 2 > cs ? nkv - 2 : cs;
  const int mstart = mraw < cend ? mraw : cend;

  const int t = threadIdx.x, wave = t >> 6, lane = t & 63;
  const int col = lane & 15, quad = lane >> 4;
  const float LOG2E = 1.44269504f;
  const float slope2 = exp2f(-0.5f * (float)(h + 1)) * LOG2E;  // exp2-domain
  const float slope16 = slope2 * 16.0f;
  const float scale2 = 0.08838834764831845f * LOG2E;   // (1/sqrt(128))*log2e

  __shared__ bf16 Ksf[64 * 128];      // [key][d], 16 chunks/row, swz mask 15
  __shared__ bf16 Vsf[2][128 * 64];   // [d][key],  8 chunks/row, swz mask 7
  __shared__ bf16 Psf[128 * 64];      // [q][key], wave-private 32-row bands

  const long long qrow0 = (long long)(b * L + q0 + wave * 32);
  const long long kbase = (long long)(h * 4096 + b * L) * HD;
  const long long vbase = (long long)(h * HD) * 4096 + b * L;

  auto stage = [&](int vbuf, int itile) {
    const int kv0 = itile << 6;
#pragma unroll
    for (int i = 0; i < 4; ++i) {
      int P = i * 256 + t;   // physical 16B chunk index (contiguous per wave)
      {  // K: row = P>>4, phys chunk p = P&15, logical chunk = p ^ (row&15)
        int rr = P >> 4, cc = ((P & 15) ^ (rr & 15)) << 3;
        g2l16(Kh + kbase + (long long)(kv0 + rr) * HD + cc, &Ksf[P * 8]);
      }
      {  // V: row = P>>3, phys chunk p = P&7, logical chunk = p ^ (row&7)
        int rr = P >> 3, cc = ((P & 7) ^ (rr & 7)) << 3;
        g2l16(VT + vbase + (long long)rr * 4096 + kv0 + cc, &Vsf[vbuf][P * 8]);
      }
    }
  };

  bf16x8 qf[2][4];
#pragma unroll
  for (int mi = 0; mi < 2; ++mi)
#pragma unroll
    for (int ks = 0; ks < 4; ++ks)
      qf[mi][ks] = *(const bf16x8*)&Q[(qrow0 + mi * 16 + col) * D + h * HD + ks * 32 + quad * 8];

  f32x4 o_acc[2][8] = {};
  float m_i[2][4], l_i[2][4];   // l lane-partial (this lane's 4 cols)
#pragma unroll
  for (int mi = 0; mi < 2; ++mi)
#pragma unroll
    for (int r = 0; r < 4; ++r) { m_i[mi][r] = -1e30f; l_i[mi][r] = 0.f; }

  stage(0, cend - 1);

  for (int it = cend - 1; it >= cs; --it) {
    const int cur = (cend - 1 - it) & 1;
    const int kv0 = it << 6;
    const bool masked = (it >= mstart);   // wave-uniform

    __syncthreads();   // A: drains vmcnt -> Ksf + Vsf[cur] ready

    // S = Q K^T  (per wave: 2 m-tiles x 4 n-tiles, 4 k-steps over d=128)
    f32x4 s_acc[2][4] = {};
    __builtin_amdgcn_s_setprio(1);
#pragma unroll
    for (int ks = 0; ks < 4; ++ks) {
      bf16x8 kf[4];
#pragma unroll
      for (int ni = 0; ni < 4; ++ni)
        kf[ni] = *(const bf16x8*)&Ksf[(ni * 16 + col) * 128 +
                                      (((ks * 4 + quad) ^ col) << 3)];
#pragma unroll
      for (int mi = 0; mi < 2; ++mi)
#pragma unroll
        for (int ni = 0; ni < 4; ++ni)
          s_acc[mi][ni] = __builtin_amdgcn_mfma_f32_16x16x32_bf16(
              qf[mi][ks], kf[ni], s_acc[mi][ni], 0, 0, 0);
    }
    __builtin_amdgcn_s_setprio(0);

    __syncthreads();   // B: all waves done reading Ksf -> safe to restage
    if (it > cs) stage(cur ^ 1, it - 1);  // prefetch next (older) tile

    // pass A: single growth scalar per lane. Row max via max over ni of
    // fmaf(s, scale2, ni*slope16) minus sb -- a DIFFERENT expression tree
    // than pass B (no CSE -> nothing but `grow` stays live). Mask ignored:
    // overestimated rm only ever forces the always-correct slow path.
    float grow = -1e30f;
#pragma unroll
    for (int mi = 0; mi < 2; ++mi)
#pragma unroll
      for (int r = 0; r < 4; ++r) {
        const int rowq = wave * 32 + mi * 16 + quad * 4 + r;
        const int qg = q0 + rowq;
        const float sb = slope2 * (float)(qg - kv0 - col);   // dist at ni=0
        float t0 = fmaxf(
            fmaxf(fmaf(s_acc[mi][0][r], scale2, 0.0f * slope16),
                  fmaf(s_acc[mi][1][r], scale2, 1.0f * slope16)),
            fmaxf(fmaf(s_acc[mi][2][r], scale2, 2.0f * slope16),
                  fmaf(s_acc[mi][3][r], scale2, 3.0f * slope16)));
        grow = fmaxf(grow, (t0 - sb) - m_i[mi][r]);
      }

    if (!__any(grow > 20.0f)) {
      // fast path: reference m is safe (P <= 2^20); no reduce, no rescale,
      // no m-update. pv = exp2(fma(s, scale2, ni*slope16 - sb - mref)).
#pragma unroll
      for (int mi = 0; mi < 2; ++mi)
#pragma unroll
        for (int r = 0; r < 4; ++r) {
          const int rowq = wave * 32 + mi * 16 + quad * 4 + r;
          const int qg = q0 + rowq;
          const float c0 = -slope2 * (float)(qg - kv0 - col) - m_i[mi][r];
          float ps = 0.f;
#pragma unroll
          for (int ni = 0; ni < 4; ++ni) {
            float pv = exp2f(fmaf(s_acc[mi][ni][r], scale2,
                                  (float)ni * slope16 + c0));
            if (masked && (kv0 + ni * 16 + col > qg)) pv = 0.f;
            ps += pv;
            Psf[rowq * 64 + ((((ni * 2) + (col >> 3)) ^ (rowq & 7)) << 3) +
                (col & 7)] = (bf16)pv;
          }
          l_i[mi][r] += ps;
        }
    } else {
      // slow path (tile 0 / rare excursion): full reduce + rescale.
#pragma unroll
      for (int mi = 0; mi < 2; ++mi)
#pragma unroll
        for (int r = 0; r < 4; ++r) {
          const int rowq = wave * 32 + mi * 16 + quad * 4 + r;
          const int qg = q0 + rowq;
          const float sb = slope2 * (float)(qg - kv0 - col);
          float svv[4];
#pragma unroll
          for (int ni = 0; ni < 4; ++ni) {
            svv[ni] = fmaf(s_acc[mi][ni][r], scale2, (float)ni * slope16 - sb);
            if (masked && (kv0 + ni * 16 + col > qg)) svv[ni] = -1e30f;
          }
          float rm = fmaxf(fmaxf(svv[0], svv[1]), fmaxf(svv[2], svv[3]));
#pragma unroll
          for (int off = 1; off < 16; off <<= 1)
            rm = fmaxf(rm, __shfl_xor(rm, off, 64));
          const float mold = m_i[mi][r];
          float mnew = fmaxf(mold, rm);
          if (masked) mnew = fmaxf(mnew, -1e20f);   // all-masked-row floor
          const float alpha = exp2f(mold - mnew);
          float ps = 0.f;
#pragma unroll
          for (int ni = 0; ni < 4; ++ni) {
            float pv = exp2f(svv[ni] - mnew);
            ps += pv;
            Psf[rowq * 64 + ((((ni * 2) + (col >> 3)) ^ (rowq & 7)) << 3) +
                (col & 7)] = (bf16)pv;
          }
          l_i[mi][r] = fmaf(alpha, l_i[mi][r], ps);
          m_i[mi][r] = mnew;
#pragma unroll
          for (int di = 0; di < 8; ++di) o_acc[mi][di][r] *= alpha;
        }
    }

    // O += P V (no barrier needed: Psf band is wave-private; Vs double-buffered)
    __builtin_amdgcn_s_setprio(1);
#pragma unroll
    for (int kstep = 0; kstep < 2; ++kstep) {
      bf16x8 pf[2];
#pragma unroll
      for (int mi = 0; mi < 2; ++mi)
        pf[mi] = *(const bf16x8*)&Psf[(wave * 32 + mi * 16 + col) * 64 +
                                      (((kstep * 4 + quad) ^ (col & 7)) << 3)];
#pragma unroll
      for (int di = 0; di < 8; ++di) {
        bf16x8 vf = *(const bf16x8*)&Vsf[cur][(di * 16 + col) * 64 +
                                             (((kstep * 4 + quad) ^ (col & 7)) << 3)];
#pragma unroll
        for (int mi = 0; mi < 2; ++mi)
          o_acc[mi][di] = __builtin_amdgcn_mfma_f32_16x16x32_bf16(
              pf[mi], vf, o_acc[mi][di], 0, 0, 0);
      }
    }
    __builtin_amdgcn_s_setprio(0);
  }

  if (part < 0) {
    // direct: normalize (reduce lane-partial l over the 16-lane row group)
#pragma unroll
    for (int mi = 0; mi < 2; ++mi)
#pragma unroll
      for (int r = 0; r < 4; ++r) {
        float lt = l_i[mi][r];
#pragma unroll
        for (int off = 1; off < 16; off <<= 1)
          lt += __shfl_xor(lt, off, 64);
        float rl = 1.0f / lt;
        long long qg = qrow0 + mi * 16 + quad * 4 + r;
#pragma unroll
        for (int di = 0; di < 8; ++di)
          O[qg * D + h * HD + di * 16 + col] = (bf16)(o_acc[mi][di][r] * rl);
      }
  } else {
    // partial: store unnormalized O~ (bf16) + m,l (fp32 per row)
    bf16* pb = parts + (long long)part * 16384;
    float* mlp = ml + (long long)part * 256;
#pragma unroll
    for (int mi = 0; mi < 2; ++mi)
#pragma unroll
      for (int r = 0; r < 4; ++r) {
        float lt = l_i[mi][r];
#pragma unroll
        for (int off = 1; off < 16; off <<= 1)
          lt += __shfl_xor(lt, off, 64);
        int rowq = wave * 32 + mi * 16 + quad * 4 + r;
        if (col == 0) { mlp[rowq] = m_i[mi][r]; mlp[128 + rowq] = lt; }
#pragma unroll
        for (int di = 0; di < 8; ++di)
          pb[rowq * 128 + di * 16 + col] = (bf16)o_acc[mi][di][r];
      }
  }
}

// ---------------------------------------------------------------------------
// Combine partial chunks: O = sum_c e2^(m_c-M) O~_c / sum_c e2^(m_c-M) l_c.
// (m are exp2-domain references; weights use exp2f.) One block per group;
// thread t: row = t>>1, cols (t&1)*64..+63.
// ---------------------------------------------------------------------------
__global__ __launch_bounds__(256) void attn_combine(
    const float* __restrict__ ml, const bf16* __restrict__ parts,
    bf16* __restrict__ O)
{
  const int meta = g_tab.grp[4 * blockIdx.x];
  const int first = g_tab.grp[4 * blockIdx.x + 1];
  const int n = g_tab.grp[4 * blockIdx.x + 2];
  const int b = meta & 1, h = (meta >> 1) & 15, qt = (meta >> 5) & 15;
  const int t = threadIdx.x;
  const int row = t >> 1, cg = t & 1;

  float M = -1e30f;
  for (int c = 0; c < n; ++c) M = fmaxf(M, ml[(long long)(first + c) * 256 + row]);

  float acc[64];
#pragma unroll
  for (int j = 0; j < 64; ++j) acc[j] = 0.f;
  float den = 0.f;
  for (int c = 0; c < n; ++c) {
    const float* mlc = ml + (long long)(first + c) * 256;
    float w = exp2f(mlc[row] - M);
    den = fmaf(w, mlc[128 + row], den);
    const bf16* p = parts + (long long)(first + c) * 16384 + row * 128 + cg * 64;
#pragma unroll
    for (int j8 = 0; j8 < 8; ++j8) {
      bf16x8 v = ((const bf16x8*)p)[j8];
#pragma unroll
      for (int k = 0; k < 8; ++k) acc[j8 * 8 + k] = fmaf(w, (float)v[k], acc[j8 * 8 + k]);
    }
  }
  float rd = 1.0f / den;
  long long qg = (long long)b * 2048 + qt * 128 + row;
  bf16* o = O + qg * 2048 + h * 128 + cg * 64;
#pragma unroll
  for (int j8 = 0; j8 < 8; ++j8) {
    bf16x8 v;
#pragma unroll
    for (int k = 0; k < 8; ++k) v[k] = (bf16)(acc[j8 * 8 + k] * rd);
    ((bf16x8*)o)[j8] = v;
  }
}

// ---------------------------------------------------------------------------
extern "C" void kernel_launch(void* const* d_in, const int* in_sizes, int n_in,
                              void* d_out, int out_size, void* d_ws, size_t ws_size,
                              hipStream_t stream) {
  (void)in_sizes; (void)n_in; (void)out_size; (void)ws_size;
  const float* hs  = (const float*)d_in[0];  // [2,2048,2048]
  const float* Wqd = (const float*)d_in[1];  // [1536,2048]
  const float* Wqu = (const float*)d_in[2];  // [2048,1536]
  const float* Wkv = (const float*)d_in[3];  // [512,2048]
  const float* kup = (const float*)d_in[4];  // [16,512,128]
  const float* vup = (const float*)d_in[5];  // [16,512,128]
  const float* Wo  = (const float*)d_in[6];  // [2048,2048]
  float* out = (float*)d_out;                // [2,2048,2048] fp32

  char* ws = (char*)d_ws;
  bf16* hsb  = (bf16*)ws; ws += (size_t)4096 * 2048 * 2;   // [also Ob]
  bf16* Wdcb = (bf16*)ws; ws += (size_t)2048 * 2048 * 2;   // concat(Wqd,Wkv)
  bf16* Wqub = (bf16*)ws; ws += (size_t)2048 * 1536 * 2;
  bf16* kupT = (bf16*)ws; ws += (size_t)16 * 128 * 512 * 2;
  bf16* vupT = (bf16*)ws; ws += (size_t)16 * 128 * 512 * 2;
  bf16* XC   = (bf16*)ws; ws += (size_t)4096 * 2048 * 2;   // [Xq | Cl] [also Wob]
  bf16* Qb   = (bf16*)ws; ws += (size_t)4096 * 2048 * 2;
  bf16* Kb   = (bf16*)ws; ws += (size_t)16 * 4096 * 128 * 2;
  bf16* VTb  = (bf16*)ws; ws += (size_t)16 * 128 * 4096 * 2;
  bf16* Cl   = XC + 1536;   // latent = cols [1536,2048) of XC, ld 2048
  bf16* Ob   = hsb;         // attn out aliases hsb
  bf16* Wob  = XC;          // Wo bf16 aliases XC

  // attention split scratch aliases Wdcb.. (dead by attention time):
  // [ml 448*256 f32][parts 448*128*128 bf16] = 15.1 MB
  float* mld   = (float*)Wdcb;
  bf16*  parts = (bf16*)(mld + 448 * 256);

  // fp32 -> bf16 converts
  cvt_f32_bf16<<<1024, 256, 0, stream>>>(hs, hsb, 4096 * 2048 / 4);
  cvt3_f32_bf16<<<1024, 256, 0, stream>>>(
      Wqd, Wdcb, 1536 * 2048 / 4,
      Wkv, Wdcb + (size_t)1536 * 2048, 512 * 2048 / 4,
      Wqu, Wqub, 2048 * 1536 / 4);
  transpose_cvt<<<dim3(2, 8, 16), 256, 0, stream>>>(kup, kupT, 512, 128);
  transpose_cvt<<<dim3(2, 8, 16), 256, 0, stream>>>(vup, vupT, 512, 128);

  // XC = hs * [Wq_down|Wkv_down]^T   [4096 x 2048 x 2048]
  gemm_nt<bf16><<<dim3(16, 32, 1), 256, 0, stream>>>(hsb, Wdcb, XC,
                                                     2048, 2048, 2048, 2048, 0, 0, 0);
  // Q = Xq * Wq_up^T                 [4096 x 2048 x 1536]
  gemm_nt<bf16><<<dim3(16, 32, 1), 256, 0, stream>>>(XC, Wqub, Qb,
                                                     2048, 1536, 2048, 1536, 0, 0, 0);
  // K[h] = C * k_upT[h]^T            [4096 x 128 x 512] x16
  gemm_nt<bf16><<<dim3(1, 32, 16), 256, 0, stream>>>(Cl, kupT, Kb,
                                                     2048, 512, 128, 512,
                                                     0, 128 * 512, (long long)4096 * 128);
  // VT[h] = v_upT[h] * C^T           [128 x 4096 x 512] x16
  gemm_nt<bf16><<<dim3(32, 1, 16), 256, 0, stream>>>(vupT, Cl, VTb,
                                                     512, 2048, 4096, 512,
                                                     128 * 512, 0, (long long)128 * 4096);
  // Wo convert (into XC region, now dead)
  cvt_f32_bf16<<<512, 256, 0, stream>>>(Wo, Wob, 2048 * 2048 / 4);
  // chunked attention + combine (tables are compile-time constants)
  attn_kernel<<<dim3(ATTN_BLOCKS, 1, 1), 256, 0, stream>>>(Qb, Kb, VTb, Ob, mld, parts);
  attn_combine<<<dim3(COMB_BLOCKS, 1, 1), 256, 0, stream>>>(mld, parts, Ob);
  // out = O * Wo^T                   [4096 x 2048 x 2048], fp32 output
  gemm_nt<float><<<dim3(16, 32, 1), 256, 0, stream>>>(Ob, Wob, out,
                                                      2048, 2048, 2048, 2048, 0, 0, 0);
}

// Round 7
// 402.099 us; speedup vs baseline: 1.2517x; 1.0550x over previous
//
#include <hip/hip_runtime.h>
#include <math.h>

// MLA + ALiBi causal attention. fp32 in/out, bf16 MFMA internal compute.
// R12 (resubmit #2; prior bench failed on container acquisition, no data).
// GEMM BK 32->64 (m97 structure exact: 128^2 tile, BK=64, 2-barrier,
// global_load_lds w16 -> 874-912 TF verified vs our ~390 TF at BK=32).
// E2E accounting: attn 88us + converts ~25us + ~310us of gemm_nt -> GEMM
// is the elephant. Parameter change within the proven template; accumulation
// order per output unchanged (bit-identical results). Attn kernel untouched
// (R11: 88us; occupancy rounds exhausted -- 40KB faster-occupancy/slower,
// 64KB same-occupancy/faster; remaining attn cost is latency structure).
typedef __bf16 bf16;
typedef __bf16 bf16x8 __attribute__((ext_vector_type(8)));
typedef __bf16 bf16x4 __attribute__((ext_vector_type(4)));
typedef float f32x4 __attribute__((ext_vector_type(4)));

#define AS1 __attribute__((address_space(1)))
#define AS3 __attribute__((address_space(3)))

// Exact static decomposition (L=2048, 128-row q tiles, 64-key kv tiles,
// chunk = 8 kv tiles, ALiBi window WH[h]): per b: 172 direct + 224 chunks,
// 84 groups. Totals: 344 direct + 448 partial = 792 blocks; 168 groups.
#define ATTN_BLOCKS 792
#define COMB_BLOCKS 168

struct ATables {
  int tbl[ATTN_BLOCKS * 2];   // {meta, partIdx(-1=direct)}
  int grp[COMB_BLOCKS * 4];   // {meta, firstPart, nChunks, pad}
};

// meta = b | h<<1 | qt<<5 | cstart<<9 | clen<<16
constexpr ATables make_tables() {
  ATables T{};
  int WH[16] = {22,32,45,64,90,128,181,256,362,512,724,1024,1448,2048,2896,4096};
  int nc = 0, np = 0, ng = 0;
  for (int qt = 15; qt >= 0; --qt)
    for (int h = 15; h >= 0; --h)
      for (int b = 0; b < 2; ++b) {
        int q0 = qt * 128, nkv = 2 * qt + 2;
        int dlo = q0 - WH[h];
        int kv_lo = dlo > 0 ? (dlo >> 6) : 0;
        int span = nkv - kv_lo;
        int nch = (span + 7) >> 3;
        int base = b | (h << 1) | (qt << 5);
        if (nch == 1) {
          T.tbl[2 * nc] = base | (kv_lo << 9) | (span << 16);
          T.tbl[2 * nc + 1] = -1;
          ++nc;
        } else {
          T.grp[4 * ng] = base; T.grp[4 * ng + 1] = np; T.grp[4 * ng + 2] = nch;
          ++ng;
          for (int c = 0; c < nch; ++c) {
            int cs = kv_lo + c * 8;
            int cl = nkv - cs; if (cl > 8) cl = 8;
            T.tbl[2 * nc] = base | (cs << 9) | (cl << 16);
            T.tbl[2 * nc + 1] = np;
            ++nc; ++np;
          }
        }
      }
  return T;
}

__device__ const ATables g_tab = make_tables();

__device__ __forceinline__ void g2l16(const void* g, void* l) {
  // async global->LDS, 16B per lane; LDS dest is wave-uniform base + lane*16
  __builtin_amdgcn_global_load_lds((const AS1 void*)g, (AS3 void*)l, 16, 0, 0);
}

// ---------------------------------------------------------------------------
// fp32 -> bf16 elementwise convert (n4 = element count / 4)
// ---------------------------------------------------------------------------
__device__ __forceinline__ void cvt_seg(const float* __restrict__ in,
                                        bf16* __restrict__ out, int n4) {
  int i = blockIdx.x * 256 + threadIdx.x;
  const int stride = gridDim.x * 256;
  for (; i < n4; i += stride) {
    float4 v = ((const float4*)in)[i];
    bf16x4 o;
    o[0] = (bf16)v.x; o[1] = (bf16)v.y; o[2] = (bf16)v.z; o[3] = (bf16)v.w;
    ((bf16x4*)out)[i] = o;
  }
}

__global__ __launch_bounds__(256) void cvt_f32_bf16(
    const float* __restrict__ in, bf16* __restrict__ out, int n4) {
  cvt_seg(in, out, n4);
}

__global__ __launch_bounds__(256) void cvt3_f32_bf16(
    const float* __restrict__ s0, bf16* __restrict__ d0, int n0,
    const float* __restrict__ s1, bf16* __restrict__ d1, int n1,
    const float* __restrict__ s2, bf16* __restrict__ d2, int n2) {
  cvt_seg(s0, d0, n0);
  cvt_seg(s1, d1, n1);
  cvt_seg(s2, d2, n2);
}

// ---------------------------------------------------------------------------
// fused convert+transpose: fp32 [Z][R][D] -> bf16 [Z][D][R]. R%64==0, D%64==0.
// ---------------------------------------------------------------------------
__global__ __launch_bounds__(256) void transpose_cvt(
    const float* __restrict__ in, bf16* __restrict__ out, int R, int D)
{
  __shared__ bf16 tile[64][72];
  const long long base = (long long)blockIdx.z * R * D;
  const int r0 = blockIdx.y * 64, c0 = blockIdx.x * 64;
  const int t = threadIdx.x;
#pragma unroll
  for (int i = 0; i < 4; ++i) {
    int c = i * 256 + t;
    int rr = c >> 4, cc = (c & 15) << 2;
    float4 v = *(const float4*)&in[base + (long long)(r0 + rr) * D + c0 + cc];
    tile[rr][cc + 0] = (bf16)v.x;
    tile[rr][cc + 1] = (bf16)v.y;
    tile[rr][cc + 2] = (bf16)v.z;
    tile[rr][cc + 3] = (bf16)v.w;
  }
  __syncthreads();
#pragma unroll
  for (int i = 0; i < 2; ++i) {
    int c = i * 256 + t;
    int rr = c >> 3, cc = (c & 7) << 3;
    bf16x8 v;
#pragma unroll
    for (int j = 0; j < 8; ++j) v[j] = tile[cc + j][rr];
    *(bf16x8*)&out[base + (long long)(c0 + rr) * R + r0 + cc] = v;
  }
}

// ---------------------------------------------------------------------------
// NT GEMM: C[m,n] = sum_k A[m,k]*B[n,k]. 128x128 tile, BK=64, 4 waves.
// m97 structure: global_load_lds w16 staging, 2 barriers per K-step,
// 2 k-subtiles x 16 MFMA inner. K % 64 == 0 (2048/1536/512 all OK).
// ---------------------------------------------------------------------------
template <typename CT>
__global__ __launch_bounds__(256) void gemm_nt(
    const bf16* __restrict__ A, const bf16* __restrict__ B, CT* __restrict__ C,
    int lda, int ldb, int ldc, int K, long long sA, long long sB, long long sC)
{
  A += (long long)blockIdx.z * sA;
  B += (long long)blockIdx.z * sB;
  C += (long long)blockIdx.z * sC;

  __shared__ bf16 As[128][64];
  __shared__ bf16 Bs[128][64];

  const int t = threadIdx.x;
  const int lane = t & 63, wave = t >> 6;
  const int wm = (wave >> 1) * 64, wn = (wave & 1) * 64;
  const int m0 = blockIdx.y * 128, n0 = blockIdx.x * 128;
  const int r16 = lane & 15, q8 = (lane >> 4) * 8;

  f32x4 acc[4][4] = {};

  for (int k0 = 0; k0 < K; k0 += 64) {
    __syncthreads();
#pragma unroll
    for (int r = 0; r < 4; ++r) {
      int c = r * 256 + t;
      int row = c >> 3, col = (c & 7) << 3;
      g2l16(A + (long long)(m0 + row) * lda + (k0 + col), &As[row][col]);
      g2l16(B + (long long)(n0 + row) * ldb + (k0 + col), &Bs[row][col]);
    }
    __syncthreads();

#pragma unroll
    for (int ks = 0; ks < 2; ++ks) {
      bf16x8 af[4], bfr[4];
#pragma unroll
      for (int i = 0; i < 4; ++i)
        af[i]  = *(const bf16x8*)&As[wm + i * 16 + r16][ks * 32 + q8];
#pragma unroll
      for (int i = 0; i < 4; ++i)
        bfr[i] = *(const bf16x8*)&Bs[wn + i * 16 + r16][ks * 32 + q8];
#pragma unroll
      for (int mi = 0; mi < 4; ++mi)
#pragma unroll
        for (int ni = 0; ni < 4; ++ni)
          acc[mi][ni] = __builtin_amdgcn_mfma_f32_16x16x32_bf16(af[mi], bfr[ni], acc[mi][ni], 0, 0, 0);
    }
  }

  const int quad = lane >> 4;
#pragma unroll
  for (int mi = 0; mi < 4; ++mi)
#pragma unroll
    for (int ni = 0; ni < 4; ++ni)
#pragma unroll
      for (int r = 0; r < 4; ++r) {
        int mm = m0 + wm + mi * 16 + quad * 4 + r;
        int nn = n0 + wn + ni * 16 + r16;
        C[(long long)mm * ldc + nn] = (CT)acc[mi][ni][r];
      }
}

// ---------------------------------------------------------------------------
// Flash attention, chunked, 64-key tiles, REVERSED order (diagonal first).
// Block = table entry: 128 q rows of (b,h,qt) over KV tiles [cs,cs+cl),
// iterated cend-1 .. cs. K SINGLE-buffered, V double-buffered, Psf wave-
// private => LDS 64KB => 2 blocks/CU. Two barriers per tile:
//   A: drains vmcnt (K + V[cur] staged) / all waves left prev K section
//   QK^T (K consumed into regs)
//   B: all waves done reading Ksf -> safe to overwrite
//   stage K(next) + V(next) ; softmax ; PV (Vsf[cur], Psf)
// Softmax: exp2 domain, vote-gated fast path (no reduce/rescale; pass A
// growth scalar via separate expression tree). Slow path = full reduce.
// Causal mask on tiles >= nkv-2. LDS XOR-swizzled (conflict-free).
// ---------------------------------------------------------------------------
__global__ __launch_bounds__(256) void attn_kernel(
    const bf16* __restrict__ Q, const bf16* __restrict__ Kh,
    const bf16* __restrict__ VT, bf16* __restrict__ O,
    float* __restrict__ ml, bf16* __restrict__ parts)
{
  const int L = 2048, HD = 128, D = 2048;
  const int meta = g_tab.tbl[2 * blockIdx.x];
  const int part = g_tab.tbl[2 * blockIdx.x + 1];
  const int b = meta & 1, h = (meta >> 1) & 15, qt = (meta >> 5) & 15;
  const int cs = (meta >> 9) & 127, cl = (meta >> 16) & 15;
  const int q0 = qt * 128, nkv = 2 * qt + 2;
  const int cend = cs + cl;
  // mask any diagonal tile (>= nkv-2) present in this chunk:
  const int mraw = nkv - 2 > cs ? nkv - 2 : cs;
  const int mstart = mraw < cend ? mraw : cend;

  const int t = threadIdx.x, wave = t >> 6, lane = t & 63;
  const int col = lane & 15, quad = lane >> 4;
  const float LOG2E = 1.44269504f;
  const float slope2 = exp2f(-0.5f * (float)(h + 1)) * LOG2E;  // exp2-domain
  const float slope16 = slope2 * 16.0f;
  const float scale2 = 0.08838834764831845f * LOG2E;   // (1/sqrt(128))*log2e

  __shared__ bf16 Ksf[64 * 128];      // [key][d], 16 chunks/row, swz mask 15
  __shared__ bf16 Vsf[2][128 * 64];   // [d][key],  8 chunks/row, swz mask 7
  __shared__ bf16 Psf[128 * 64];      // [q][key], wave-private 32-row bands

  const long long qrow0 = (long long)(b * L + q0 + wave * 32);
  const long long kbase = (long long)(h * 4096 + b * L) * HD;
  const long long vbase = (long long)(h * HD) * 4096 + b * L;

  auto stage = [&](int vbuf, int itile) {
    const int kv0 = itile << 6;
#pragma unroll
    for (int i = 0; i < 4; ++i) {
      int P = i * 256 + t;   // physical 16B chunk index (contiguous per wave)
      {  // K: row = P>>4, phys chunk p = P&15, logical chunk = p ^ (row&15)
        int rr = P >> 4, cc = ((P & 15) ^ (rr & 15)) << 3;
        g2l16(Kh + kbase + (long long)(kv0 + rr) * HD + cc, &Ksf[P * 8]);
      }
      {  // V: row = P>>3, phys chunk p = P&7, logical chunk = p ^ (row&7)
        int rr = P >> 3, cc = ((P & 7) ^ (rr & 7)) << 3;
        g2l16(VT + vbase + (long long)rr * 4096 + kv0 + cc, &Vsf[vbuf][P * 8]);
      }
    }
  };

  bf16x8 qf[2][4];
#pragma unroll
  for (int mi = 0; mi < 2; ++mi)
#pragma unroll
    for (int ks = 0; ks < 4; ++ks)
      qf[mi][ks] = *(const bf16x8*)&Q[(qrow0 + mi * 16 + col) * D + h * HD + ks * 32 + quad * 8];

  f32x4 o_acc[2][8] = {};
  float m_i[2][4], l_i[2][4];   // l lane-partial (this lane's 4 cols)
#pragma unroll
  for (int mi = 0; mi < 2; ++mi)
#pragma unroll
    for (int r = 0; r < 4; ++r) { m_i[mi][r] = -1e30f; l_i[mi][r] = 0.f; }

  stage(0, cend - 1);

  for (int it = cend - 1; it >= cs; --it) {
    const int cur = (cend - 1 - it) & 1;
    const int kv0 = it << 6;
    const bool masked = (it >= mstart);   // wave-uniform

    __syncthreads();   // A: drains vmcnt -> Ksf + Vsf[cur] ready

    // S = Q K^T  (per wave: 2 m-tiles x 4 n-tiles, 4 k-steps over d=128)
    f32x4 s_acc[2][4] = {};
    __builtin_amdgcn_s_setprio(1);
#pragma unroll
    for (int ks = 0; ks < 4; ++ks) {
      bf16x8 kf[4];
#pragma unroll
      for (int ni = 0; ni < 4; ++ni)
        kf[ni] = *(const bf16x8*)&Ksf[(ni * 16 + col) * 128 +
                                      (((ks * 4 + quad) ^ col) << 3)];
#pragma unroll
      for (int mi = 0; mi < 2; ++mi)
#pragma unroll
        for (int ni = 0; ni < 4; ++ni)
          s_acc[mi][ni] = __builtin_amdgcn_mfma_f32_16x16x32_bf16(
              qf[mi][ks], kf[ni], s_acc[mi][ni], 0, 0, 0);
    }
    __builtin_amdgcn_s_setprio(0);

    __syncthreads();   // B: all waves done reading Ksf -> safe to restage
    if (it > cs) stage(cur ^ 1, it - 1);  // prefetch next (older) tile

    // pass A: single growth scalar per lane. Row max via max over ni of
    // fmaf(s, scale2, ni*slope16) minus sb -- a DIFFERENT expression tree
    // than pass B (no CSE -> nothing but `grow` stays live). Mask ignored:
    // overestimated rm only ever forces the always-correct slow path.
    float grow = -1e30f;
#pragma unroll
    for (int mi = 0; mi < 2; ++mi)
#pragma unroll
      for (int r = 0; r < 4; ++r) {
        const int rowq = wave * 32 + mi * 16 + quad * 4 + r;
        const int qg = q0 + rowq;
        const float sb = slope2 * (float)(qg - kv0 - col);   // dist at ni=0
        float t0 = fmaxf(
            fmaxf(fmaf(s_acc[mi][0][r], scale2, 0.0f * slope16),
                  fmaf(s_acc[mi][1][r], scale2, 1.0f * slope16)),
            fmaxf(fmaf(s_acc[mi][2][r], scale2, 2.0f * slope16),
                  fmaf(s_acc[mi][3][r], scale2, 3.0f * slope16)));
        grow = fmaxf(grow, (t0 - sb) - m_i[mi][r]);
      }

    if (!__any(grow > 20.0f)) {
      // fast path: reference m is safe (P <= 2^20); no reduce, no rescale,
      // no m-update. pv = exp2(fma(s, scale2, ni*slope16 - sb - mref)).
#pragma unroll
      for (int mi = 0; mi < 2; ++mi)
#pragma unroll
        for (int r = 0; r < 4; ++r) {
          const int rowq = wave * 32 + mi * 16 + quad * 4 + r;
          const int qg = q0 + rowq;
          const float c0 = -slope2 * (float)(qg - kv0 - col) - m_i[mi][r];
          float ps = 0.f;
#pragma unroll
          for (int ni = 0; ni < 4; ++ni) {
            float pv = exp2f(fmaf(s_acc[mi][ni][r], scale2,
                                  (float)ni * slope16 + c0));
            if (masked && (kv0 + ni * 16 + col > qg)) pv = 0.f;
            ps += pv;
            Psf[rowq * 64 + ((((ni * 2) + (col >> 3)) ^ (rowq & 7)) << 3) +
                (col & 7)] = (bf16)pv;
          }
          l_i[mi][r] += ps;
        }
    } else {
      // slow path (tile 0 / rare excursion): full reduce + rescale.
#pragma unroll
      for (int mi = 0; mi < 2; ++mi)
#pragma unroll
        for (int r = 0; r < 4; ++r) {
          const int rowq = wave * 32 + mi * 16 + quad * 4 + r;
          const int qg = q0 + rowq;
          const float sb = slope2 * (float)(qg - kv0 - col);
          float svv[4];
#pragma unroll
          for (int ni = 0; ni < 4; ++ni) {
            svv[ni] = fmaf(s_acc[mi][ni][r], scale2, (float)ni * slope16 - sb);
            if (masked && (kv0 + ni * 16 + col > qg)) svv[ni] = -1e30f;
          }
          float rm = fmaxf(fmaxf(svv[0], svv[1]), fmaxf(svv[2], svv[3]));
#pragma unroll
          for (int off = 1; off < 16; off <<= 1)
            rm = fmaxf(rm, __shfl_xor(rm, off, 64));
          const float mold = m_i[mi][r];
          float mnew = fmaxf(mold, rm);
          if (masked) mnew = fmaxf(mnew, -1e20f);   // all-masked-row floor
          const float alpha = exp2f(mold - mnew);
          float ps = 0.f;
#pragma unroll
          for (int ni = 0; ni < 4; ++ni) {
            float pv = exp2f(svv[ni] - mnew);
            ps += pv;
            Psf[rowq * 64 + ((((ni * 2) + (col >> 3)) ^ (rowq & 7)) << 3) +
                (col & 7)] = (bf16)pv;
          }
          l_i[mi][r] = fmaf(alpha, l_i[mi][r], ps);
          m_i[mi][r] = mnew;
#pragma unroll
          for (int di = 0; di < 8; ++di) o_acc[mi][di][r] *= alpha;
        }
    }

    // O += P V (no barrier needed: Psf band is wave-private; Vs double-buffered)
    __builtin_amdgcn_s_setprio(1);
#pragma unroll
    for (int kstep = 0; kstep < 2; ++kstep) {
      bf16x8 pf[2];
#pragma unroll
      for (int mi = 0; mi < 2; ++mi)
        pf[mi] = *(const bf16x8*)&Psf[(wave * 32 + mi * 16 + col) * 64 +
                                      (((kstep * 4 + quad) ^ (col & 7)) << 3)];
#pragma unroll
      for (int di = 0; di < 8; ++di) {
        bf16x8 vf = *(const bf16x8*)&Vsf[cur][(di * 16 + col) * 64 +
                                             (((kstep * 4 + quad) ^ (col & 7)) << 3)];
#pragma unroll
        for (int mi = 0; mi < 2; ++mi)
          o_acc[mi][di] = __builtin_amdgcn_mfma_f32_16x16x32_bf16(
              pf[mi], vf, o_acc[mi][di], 0, 0, 0);
      }
    }
    __builtin_amdgcn_s_setprio(0);
  }

  if (part < 0) {
    // direct: normalize (reduce lane-partial l over the 16-lane row group)
#pragma unroll
    for (int mi = 0; mi < 2; ++mi)
#pragma unroll
      for (int r = 0; r < 4; ++r) {
        float lt = l_i[mi][r];
#pragma unroll
        for (int off = 1; off < 16; off <<= 1)
          lt += __shfl_xor(lt, off, 64);
        float rl = 1.0f / lt;
        long long qg = qrow0 + mi * 16 + quad * 4 + r;
#pragma unroll
        for (int di = 0; di < 8; ++di)
          O[qg * D + h * HD + di * 16 + col] = (bf16)(o_acc[mi][di][r] * rl);
      }
  } else {
    // partial: store unnormalized O~ (bf16) + m,l (fp32 per row)
    bf16* pb = parts + (long long)part * 16384;
    float* mlp = ml + (long long)part * 256;
#pragma unroll
    for (int mi = 0; mi < 2; ++mi)
#pragma unroll
      for (int r = 0; r < 4; ++r) {
        float lt = l_i[mi][r];
#pragma unroll
        for (int off = 1; off < 16; off <<= 1)
          lt += __shfl_xor(lt, off, 64);
        int rowq = wave * 32 + mi * 16 + quad * 4 + r;
        if (col == 0) { mlp[rowq] = m_i[mi][r]; mlp[128 + rowq] = lt; }
#pragma unroll
        for (int di = 0; di < 8; ++di)
          pb[rowq * 128 + di * 16 + col] = (bf16)o_acc[mi][di][r];
      }
  }
}

// ---------------------------------------------------------------------------
// Combine partial chunks: O = sum_c e2^(m_c-M) O~_c / sum_c e2^(m_c-M) l_c.
// (m are exp2-domain references; weights use exp2f.) One block per group;
// thread t: row = t>>1, cols (t&1)*64..+63.
// ---------------------------------------------------------------------------
__global__ __launch_bounds__(256) void attn_combine(
    const float* __restrict__ ml, const bf16* __restrict__ parts,
    bf16* __restrict__ O)
{
  const int meta = g_tab.grp[4 * blockIdx.x];
  const int first = g_tab.grp[4 * blockIdx.x + 1];
  const int n = g_tab.grp[4 * blockIdx.x + 2];
  const int b = meta & 1, h = (meta >> 1) & 15, qt = (meta >> 5) & 15;
  const int t = threadIdx.x;
  const int row = t >> 1, cg = t & 1;

  float M = -1e30f;
  for (int c = 0; c < n; ++c) M = fmaxf(M, ml[(long long)(first + c) * 256 + row]);

  float acc[64];
#pragma unroll
  for (int j = 0; j < 64; ++j) acc[j] = 0.f;
  float den = 0.f;
  for (int c = 0; c < n; ++c) {
    const float* mlc = ml + (long long)(first + c) * 256;
    float w = exp2f(mlc[row] - M);
    den = fmaf(w, mlc[128 + row], den);
    const bf16* p = parts + (long long)(first + c) * 16384 + row * 128 + cg * 64;
#pragma unroll
    for (int j8 = 0; j8 < 8; ++j8) {
      bf16x8 v = ((const bf16x8*)p)[j8];
#pragma unroll
      for (int k = 0; k < 8; ++k) acc[j8 * 8 + k] = fmaf(w, (float)v[k], acc[j8 * 8 + k]);
    }
  }
  float rd = 1.0f / den;
  long long qg = (long long)b * 2048 + qt * 128 + row;
  bf16* o = O + qg * 2048 + h * 128 + cg * 64;
#pragma unroll
  for (int j8 = 0; j8 < 8; ++j8) {
    bf16x8 v;
#pragma unroll
    for (int k = 0; k < 8; ++k) v[k] = (bf16)(acc[j8 * 8 + k] * rd);
    ((bf16x8*)o)[j8] = v;
  }
}

// ---------------------------------------------------------------------------
extern "C" void kernel_launch(void* const* d_in, const int* in_sizes, int n_in,
                              void* d_out, int out_size, void* d_ws, size_t ws_size,
                              hipStream_t stream) {
  (void)in_sizes; (void)n_in; (void)out_size; (void)ws_size;
  const float* hs  = (const float*)d_in[0];  // [2,2048,2048]
  const float* Wqd = (const float*)d_in[1];  // [1536,2048]
  const float* Wqu = (const float*)d_in[2];  // [2048,1536]
  const float* Wkv = (const float*)d_in[3];  // [512,2048]
  const float* kup = (const float*)d_in[4];  // [16,512,128]
  const float* vup = (const float*)d_in[5];  // [16,512,128]
  const float* Wo  = (const float*)d_in[6];  // [2048,2048]
  float* out = (float*)d_out;                // [2,2048,2048] fp32

  char* ws = (char*)d_ws;
  bf16* hsb  = (bf16*)ws; ws += (size_t)4096 * 2048 * 2;   // [also Ob]
  bf16* Wdcb = (bf16*)ws; ws += (size_t)2048 * 2048 * 2;   // concat(Wqd,Wkv)
  bf16* Wqub = (bf16*)ws; ws += (size_t)2048 * 1536 * 2;
  bf16* kupT = (bf16*)ws; ws += (size_t)16 * 128 * 512 * 2;
  bf16* vupT = (bf16*)ws; ws += (size_t)16 * 128 * 512 * 2;
  bf16* XC   = (bf16*)ws; ws += (size_t)4096 * 2048 * 2;   // [Xq | Cl] [also Wob]
  bf16* Qb   = (bf16*)ws; ws += (size_t)4096 * 2048 * 2;
  bf16* Kb   = (bf16*)ws; ws += (size_t)16 * 4096 * 128 * 2;
  bf16* VTb  = (bf16*)ws; ws += (size_t)16 * 128 * 4096 * 2;
  bf16* Cl   = XC + 1536;   // latent = cols [1536,2048) of XC, ld 2048
  bf16* Ob   = hsb;         // attn out aliases hsb
  bf16* Wob  = XC;          // Wo bf16 aliases XC

  // attention split scratch aliases Wdcb.. (dead by attention time):
  // [ml 448*256 f32][parts 448*128*128 bf16] = 15.1 MB
  float* mld   = (float*)Wdcb;
  bf16*  parts = (bf16*)(mld + 448 * 256);

  // fp32 -> bf16 converts
  cvt_f32_bf16<<<1024, 256, 0, stream>>>(hs, hsb, 4096 * 2048 / 4);
  cvt3_f32_bf16<<<1024, 256, 0, stream>>>(
      Wqd, Wdcb, 1536 * 2048 / 4,
      Wkv, Wdcb + (size_t)1536 * 2048, 512 * 2048 / 4,
      Wqu, Wqub, 2048 * 1536 / 4);
  transpose_cvt<<<dim3(2, 8, 16), 256, 0, stream>>>(kup, kupT, 512, 128);
  transpose_cvt<<<dim3(2, 8, 16), 256, 0, stream>>>(vup, vupT, 512, 128);

  // XC = hs * [Wq_down|Wkv_down]^T   [4096 x 2048 x 2048]
  gemm_nt<bf16><<<dim3(16, 32, 1), 256, 0, stream>>>(hsb, Wdcb, XC,
                                                     2048, 2048, 2048, 2048, 0, 0, 0);
  // Q = Xq * Wq_up^T                 [4096 x 2048 x 1536]
  gemm_nt<bf16><<<dim3(16, 32, 1), 256, 0, stream>>>(XC, Wqub, Qb,
                                                     2048, 1536, 2048, 1536, 0, 0, 0);
  // K[h] = C * k_upT[h]^T            [4096 x 128 x 512] x16
  gemm_nt<bf16><<<dim3(1, 32, 16), 256, 0, stream>>>(Cl, kupT, Kb,
                                                     2048, 512, 128, 512,
                                                     0, 128 * 512, (long long)4096 * 128);
  // VT[h] = v_upT[h] * C^T           [128 x 4096 x 512] x16
  gemm_nt<bf16><<<dim3(32, 1, 16), 256, 0, stream>>>(vupT, Cl, VTb,
                                                     512, 2048, 4096, 512,
                                                     128 * 512, 0, (long long)128 * 4096);
  // Wo convert (into XC region, now dead)
  cvt_f32_bf16<<<512, 256, 0, stream>>>(Wo, Wob, 2048 * 2048 / 4);
  // chunked attention + combine (tables are compile-time constants)
  attn_kernel<<<dim3(ATTN_BLOCKS, 1, 1), 256, 0, stream>>>(Qb, Kb, VTb, Ob, mld, parts);
  attn_combine<<<dim3(COMB_BLOCKS, 1, 1), 256, 0, stream>>>(mld, parts, Ob);
  // out = O * Wo^T                   [4096 x 2048 x 2048], fp32 output
  gemm_nt<float><<<dim3(16, 32, 1), 256, 0, stream>>>(Ob, Wob, out,
                                                      2048, 2048, 2048, 2048, 0, 0, 0);
}

// Round 8
// 392.557 us; speedup vs baseline: 1.2821x; 1.0243x over previous
//
#include <hip/hip_runtime.h>
#include <math.h>

// MLA + ALiBi causal attention. fp32 in/out, bf16 MFMA internal compute.
// R13: merge Q/K/VT GEMMs (all independent consumers of XC) into ONE
// 1536-block dispatch. Evidence: R12's BK=64 gained only 22us because the
// three [4096x2048]-class GEMMs run 512 blocks = 2 blocks/CU each (m102:
// the m97 structure is blocks/CU-limited at this scale; 874 TF needs 4/CU).
// Merged grid = 1536 blocks -> ~3/CU sustained + backfill, no inter-launch
// gaps. Inner loop byte-identical to the verified BK=64 body; per-output
// accumulation order unchanged. XC/out GEMMs (serial deps) unchanged.
// Attn unchanged (R11: 88us).
typedef __bf16 bf16;
typedef __bf16 bf16x8 __attribute__((ext_vector_type(8)));
typedef __bf16 bf16x4 __attribute__((ext_vector_type(4)));
typedef float f32x4 __attribute__((ext_vector_type(4)));

#define AS1 __attribute__((address_space(1)))
#define AS3 __attribute__((address_space(3)))

// Exact static decomposition (L=2048, 128-row q tiles, 64-key kv tiles,
// chunk = 8 kv tiles, ALiBi window WH[h]): per b: 172 direct + 224 chunks,
// 84 groups. Totals: 344 direct + 448 partial = 792 blocks; 168 groups.
#define ATTN_BLOCKS 792
#define COMB_BLOCKS 168

struct ATables {
  int tbl[ATTN_BLOCKS * 2];   // {meta, partIdx(-1=direct)}
  int grp[COMB_BLOCKS * 4];   // {meta, firstPart, nChunks, pad}
};

// meta = b | h<<1 | qt<<5 | cstart<<9 | clen<<16
constexpr ATables make_tables() {
  ATables T{};
  int WH[16] = {22,32,45,64,90,128,181,256,362,512,724,1024,1448,2048,2896,4096};
  int nc = 0, np = 0, ng = 0;
  for (int qt = 15; qt >= 0; --qt)
    for (int h = 15; h >= 0; --h)
      for (int b = 0; b < 2; ++b) {
        int q0 = qt * 128, nkv = 2 * qt + 2;
        int dlo = q0 - WH[h];
        int kv_lo = dlo > 0 ? (dlo >> 6) : 0;
        int span = nkv - kv_lo;
        int nch = (span + 7) >> 3;
        int base = b | (h << 1) | (qt << 5);
        if (nch == 1) {
          T.tbl[2 * nc] = base | (kv_lo << 9) | (span << 16);
          T.tbl[2 * nc + 1] = -1;
          ++nc;
        } else {
          T.grp[4 * ng] = base; T.grp[4 * ng + 1] = np; T.grp[4 * ng + 2] = nch;
          ++ng;
          for (int c = 0; c < nch; ++c) {
            int cs = kv_lo + c * 8;
            int cl = nkv - cs; if (cl > 8) cl = 8;
            T.tbl[2 * nc] = base | (cs << 9) | (cl << 16);
            T.tbl[2 * nc + 1] = np;
            ++nc; ++np;
          }
        }
      }
  return T;
}

__device__ const ATables g_tab = make_tables();

__device__ __forceinline__ void g2l16(const void* g, void* l) {
  // async global->LDS, 16B per lane; LDS dest is wave-uniform base + lane*16
  __builtin_amdgcn_global_load_lds((const AS1 void*)g, (AS3 void*)l, 16, 0, 0);
}

// ---------------------------------------------------------------------------
// fp32 -> bf16 elementwise convert (n4 = element count / 4)
// ---------------------------------------------------------------------------
__device__ __forceinline__ void cvt_seg(const float* __restrict__ in,
                                        bf16* __restrict__ out, int n4) {
  int i = blockIdx.x * 256 + threadIdx.x;
  const int stride = gridDim.x * 256;
  for (; i < n4; i += stride) {
    float4 v = ((const float4*)in)[i];
    bf16x4 o;
    o[0] = (bf16)v.x; o[1] = (bf16)v.y; o[2] = (bf16)v.z; o[3] = (bf16)v.w;
    ((bf16x4*)out)[i] = o;
  }
}

__global__ __launch_bounds__(256) void cvt_f32_bf16(
    const float* __restrict__ in, bf16* __restrict__ out, int n4) {
  cvt_seg(in, out, n4);
}

__global__ __launch_bounds__(256) void cvt3_f32_bf16(
    const float* __restrict__ s0, bf16* __restrict__ d0, int n0,
    const float* __restrict__ s1, bf16* __restrict__ d1, int n1,
    const float* __restrict__ s2, bf16* __restrict__ d2, int n2) {
  cvt_seg(s0, d0, n0);
  cvt_seg(s1, d1, n1);
  cvt_seg(s2, d2, n2);
}

// ---------------------------------------------------------------------------
// fused convert+transpose: fp32 [Z][R][D] -> bf16 [Z][D][R]. R%64==0, D%64==0.
// ---------------------------------------------------------------------------
__global__ __launch_bounds__(256) void transpose_cvt(
    const float* __restrict__ in, bf16* __restrict__ out, int R, int D)
{
  __shared__ bf16 tile[64][72];
  const long long base = (long long)blockIdx.z * R * D;
  const int r0 = blockIdx.y * 64, c0 = blockIdx.x * 64;
  const int t = threadIdx.x;
#pragma unroll
  for (int i = 0; i < 4; ++i) {
    int c = i * 256 + t;
    int rr = c >> 4, cc = (c & 15) << 2;
    float4 v = *(const float4*)&in[base + (long long)(r0 + rr) * D + c0 + cc];
    tile[rr][cc + 0] = (bf16)v.x;
    tile[rr][cc + 1] = (bf16)v.y;
    tile[rr][cc + 2] = (bf16)v.z;
    tile[rr][cc + 3] = (bf16)v.w;
  }
  __syncthreads();
#pragma unroll
  for (int i = 0; i < 2; ++i) {
    int c = i * 256 + t;
    int rr = c >> 3, cc = (c & 7) << 3;
    bf16x8 v;
#pragma unroll
    for (int j = 0; j < 8; ++j) v[j] = tile[cc + j][rr];
    *(bf16x8*)&out[base + (long long)(c0 + rr) * R + r0 + cc] = v;
  }
}

// ---------------------------------------------------------------------------
// NT GEMM: C[m,n] = sum_k A[m,k]*B[n,k]. 128x128 tile, BK=64, 4 waves.
// m97 structure: global_load_lds w16 staging, 2 barriers per K-step,
// 2 k-subtiles x 16 MFMA inner. K % 64 == 0.
// ---------------------------------------------------------------------------
template <typename CT>
__global__ __launch_bounds__(256) void gemm_nt(
    const bf16* __restrict__ A, const bf16* __restrict__ B, CT* __restrict__ C,
    int lda, int ldb, int ldc, int K, long long sA, long long sB, long long sC)
{
  A += (long long)blockIdx.z * sA;
  B += (long long)blockIdx.z * sB;
  C += (long long)blockIdx.z * sC;

  __shared__ bf16 As[128][64];
  __shared__ bf16 Bs[128][64];

  const int t = threadIdx.x;
  const int lane = t & 63, wave = t >> 6;
  const int wm = (wave >> 1) * 64, wn = (wave & 1) * 64;
  const int m0 = blockIdx.y * 128, n0 = blockIdx.x * 128;
  const int r16 = lane & 15, q8 = (lane >> 4) * 8;

  f32x4 acc[4][4] = {};

  for (int k0 = 0; k0 < K; k0 += 64) {
    __syncthreads();
#pragma unroll
    for (int r = 0; r < 4; ++r) {
      int c = r * 256 + t;
      int row = c >> 3, col = (c & 7) << 3;
      g2l16(A + (long long)(m0 + row) * lda + (k0 + col), &As[row][col]);
      g2l16(B + (long long)(n0 + row) * ldb + (k0 + col), &Bs[row][col]);
    }
    __syncthreads();

#pragma unroll
    for (int ks = 0; ks < 2; ++ks) {
      bf16x8 af[4], bfr[4];
#pragma unroll
      for (int i = 0; i < 4; ++i)
        af[i]  = *(const bf16x8*)&As[wm + i * 16 + r16][ks * 32 + q8];
#pragma unroll
      for (int i = 0; i < 4; ++i)
        bfr[i] = *(const bf16x8*)&Bs[wn + i * 16 + r16][ks * 32 + q8];
#pragma unroll
      for (int mi = 0; mi < 4; ++mi)
#pragma unroll
        for (int ni = 0; ni < 4; ++ni)
          acc[mi][ni] = __builtin_amdgcn_mfma_f32_16x16x32_bf16(af[mi], bfr[ni], acc[mi][ni], 0, 0, 0);
    }
  }

  const int quad = lane >> 4;
#pragma unroll
  for (int mi = 0; mi < 4; ++mi)
#pragma unroll
    for (int ni = 0; ni < 4; ++ni)
#pragma unroll
      for (int r = 0; r < 4; ++r) {
        int mm = m0 + wm + mi * 16 + quad * 4 + r;
        int nn = n0 + wn + ni * 16 + r16;
        C[(long long)mm * ldc + nn] = (CT)acc[mi][ni][r];
      }
}

// ---------------------------------------------------------------------------
// Merged Q/K/VT projection GEMM: 1536 blocks in ONE dispatch (3 blocks/CU).
//   g in [0,512):    Q  = Xq * Wq_up^T   [4096 x 2048], K=1536
//   g in [512,1024): K[h] = Cl * kupT[h]^T [4096 x 128] x16, K=512
//   g in [1024,1536):VT[h] = vupT[h] * Cl^T [128 x 4096] x16, K=512
// Body identical to gemm_nt (BK=64).
// ---------------------------------------------------------------------------
__global__ __launch_bounds__(256) void gemm_qkv(
    const bf16* __restrict__ XCp, const bf16* __restrict__ Wqub,
    const bf16* __restrict__ kupT, const bf16* __restrict__ vupT,
    bf16* __restrict__ Qb, bf16* __restrict__ Kb, bf16* __restrict__ VTb)
{
  const bf16* Cl = XCp + 1536;
  const int g = blockIdx.x;
  const bf16 *A, *B;
  bf16* C;
  int lda, ldb, ldc, K, m0, n0;
  if (g < 512) {            // Q
    A = XCp; B = Wqub; C = Qb;
    lda = 2048; ldb = 1536; ldc = 2048; K = 1536;
    n0 = (g & 15) * 128; m0 = (g >> 4) * 128;
  } else if (g < 1024) {    // K[h]
    int i = g - 512, bz = i >> 5, by = i & 31;
    A = Cl; B = kupT + bz * 65536; C = Kb + (long long)bz * 524288;
    lda = 2048; ldb = 512; ldc = 128; K = 512;
    m0 = by * 128; n0 = 0;
  } else {                  // VT[h]
    int i = g - 1024, bz = i >> 5, bx = i & 31;
    A = vupT + bz * 65536; B = Cl; C = VTb + (long long)bz * 524288;
    lda = 512; ldb = 2048; ldc = 4096; K = 512;
    m0 = 0; n0 = bx * 128;
  }

  __shared__ bf16 As[128][64];
  __shared__ bf16 Bs[128][64];

  const int t = threadIdx.x;
  const int lane = t & 63, wave = t >> 6;
  const int wm = (wave >> 1) * 64, wn = (wave & 1) * 64;
  const int r16 = lane & 15, q8 = (lane >> 4) * 8;

  f32x4 acc[4][4] = {};

  for (int k0 = 0; k0 < K; k0 += 64) {
    __syncthreads();
#pragma unroll
    for (int r = 0; r < 4; ++r) {
      int c = r * 256 + t;
      int row = c >> 3, col = (c & 7) << 3;
      g2l16(A + (long long)(m0 + row) * lda + (k0 + col), &As[row][col]);
      g2l16(B + (long long)(n0 + row) * ldb + (k0 + col), &Bs[row][col]);
    }
    __syncthreads();

#pragma unroll
    for (int ks = 0; ks < 2; ++ks) {
      bf16x8 af[4], bfr[4];
#pragma unroll
      for (int i = 0; i < 4; ++i)
        af[i]  = *(const bf16x8*)&As[wm + i * 16 + r16][ks * 32 + q8];
#pragma unroll
      for (int i = 0; i < 4; ++i)
        bfr[i] = *(const bf16x8*)&Bs[wn + i * 16 + r16][ks * 32 + q8];
#pragma unroll
      for (int mi = 0; mi < 4; ++mi)
#pragma unroll
        for (int ni = 0; ni < 4; ++ni)
          acc[mi][ni] = __builtin_amdgcn_mfma_f32_16x16x32_bf16(af[mi], bfr[ni], acc[mi][ni], 0, 0, 0);
    }
  }

  const int quad = lane >> 4;
#pragma unroll
  for (int mi = 0; mi < 4; ++mi)
#pragma unroll
    for (int ni = 0; ni < 4; ++ni)
#pragma unroll
      for (int r = 0; r < 4; ++r) {
        int mm = m0 + wm + mi * 16 + quad * 4 + r;
        int nn = n0 + wn + ni * 16 + r16;
        C[(long long)mm * ldc + nn] = (bf16)acc[mi][ni][r];
      }
}

// ---------------------------------------------------------------------------
// Flash attention, chunked, 64-key tiles, REVERSED order (diagonal first).
// Block = table entry: 128 q rows of (b,h,qt) over KV tiles [cs,cs+cl),
// iterated cend-1 .. cs. K SINGLE-buffered, V double-buffered, Psf wave-
// private => LDS 64KB. Two barriers per tile:
//   A: drains vmcnt (K + V[cur] staged) / all waves left prev K section
//   QK^T (K consumed into regs)
//   B: all waves done reading Ksf -> safe to overwrite
//   stage K(next) + V(next) ; softmax ; PV (Vsf[cur], Psf)
// Softmax: exp2 domain, vote-gated fast path (no reduce/rescale; pass A
// growth scalar via separate expression tree). Slow path = full reduce.
// Causal mask on tiles >= nkv-2. LDS XOR-swizzled (conflict-free).
// ---------------------------------------------------------------------------
__global__ __launch_bounds__(256) void attn_kernel(
    const bf16* __restrict__ Q, const bf16* __restrict__ Kh,
    const bf16* __restrict__ VT, bf16* __restrict__ O,
    float* __restrict__ ml, bf16* __restrict__ parts)
{
  const int L = 2048, HD = 128, D = 2048;
  const int meta = g_tab.tbl[2 * blockIdx.x];
  const int part = g_tab.tbl[2 * blockIdx.x + 1];
  const int b = meta & 1, h = (meta >> 1) & 15, qt = (meta >> 5) & 15;
  const int cs = (meta >> 9) & 127, cl = (meta >> 16) & 15;
  const int q0 = qt * 128, nkv = 2 * qt + 2;
  const int cend = cs + cl;
  // mask any diagonal tile (>= nkv-2) present in this chunk:
  const int mraw = nkv - 2 > cs ? nkv - 2 : cs;
  const int mstart = mraw < cend ? mraw : cend;

  const int t = threadIdx.x, wave = t >> 6, lane = t & 63;
  const int col = lane & 15, quad = lane >> 4;
  const float LOG2E = 1.44269504f;
  const float slope2 = exp2f(-0.5f * (float)(h + 1)) * LOG2E;  // exp2-domain
  const float slope16 = slope2 * 16.0f;
  const float scale2 = 0.08838834764831845f * LOG2E;   // (1/sqrt(128))*log2e

  __shared__ bf16 Ksf[64 * 128];      // [key][d], 16 chunks/row, swz mask 15
  __shared__ bf16 Vsf[2][128 * 64];   // [d][key],  8 chunks/row, swz mask 7
  __shared__ bf16 Psf[128 * 64];      // [q][key], wave-private 32-row bands

  const long long qrow0 = (long long)(b * L + q0 + wave * 32);
  const long long kbase = (long long)(h * 4096 + b * L) * HD;
  const long long vbase = (long long)(h * HD) * 4096 + b * L;

  auto stage = [&](int vbuf, int itile) {
    const int kv0 = itile << 6;
#pragma unroll
    for (int i = 0; i < 4; ++i) {
      int P = i * 256 + t;   // physical 16B chunk index (contiguous per wave)
      {  // K: row = P>>4, phys chunk p = P&15, logical chunk = p ^ (row&15)
        int rr = P >> 4, cc = ((P & 15) ^ (rr & 15)) << 3;
        g2l16(Kh + kbase + (long long)(kv0 + rr) * HD + cc, &Ksf[P * 8]);
      }
      {  // V: row = P>>3, phys chunk p = P&7, logical chunk = p ^ (row&7)
        int rr = P >> 3, cc = ((P & 7) ^ (rr & 7)) << 3;
        g2l16(VT + vbase + (long long)rr * 4096 + kv0 + cc, &Vsf[vbuf][P * 8]);
      }
    }
  };

  bf16x8 qf[2][4];
#pragma unroll
  for (int mi = 0; mi < 2; ++mi)
#pragma unroll
    for (int ks = 0; ks < 4; ++ks)
      qf[mi][ks] = *(const bf16x8*)&Q[(qrow0 + mi * 16 + col) * D + h * HD + ks * 32 + quad * 8];

  f32x4 o_acc[2][8] = {};
  float m_i[2][4], l_i[2][4];   // l lane-partial (this lane's 4 cols)
#pragma unroll
  for (int mi = 0; mi < 2; ++mi)
#pragma unroll
    for (int r = 0; r < 4; ++r) { m_i[mi][r] = -1e30f; l_i[mi][r] = 0.f; }

  stage(0, cend - 1);

  for (int it = cend - 1; it >= cs; --it) {
    const int cur = (cend - 1 - it) & 1;
    const int kv0 = it << 6;
    const bool masked = (it >= mstart);   // wave-uniform

    __syncthreads();   // A: drains vmcnt -> Ksf + Vsf[cur] ready

    // S = Q K^T  (per wave: 2 m-tiles x 4 n-tiles, 4 k-steps over d=128)
    f32x4 s_acc[2][4] = {};
    __builtin_amdgcn_s_setprio(1);
#pragma unroll
    for (int ks = 0; ks < 4; ++ks) {
      bf16x8 kf[4];
#pragma unroll
      for (int ni = 0; ni < 4; ++ni)
        kf[ni] = *(const bf16x8*)&Ksf[(ni * 16 + col) * 128 +
                                      (((ks * 4 + quad) ^ col) << 3)];
#pragma unroll
      for (int mi = 0; mi < 2; ++mi)
#pragma unroll
        for (int ni = 0; ni < 4; ++ni)
          s_acc[mi][ni] = __builtin_amdgcn_mfma_f32_16x16x32_bf16(
              qf[mi][ks], kf[ni], s_acc[mi][ni], 0, 0, 0);
    }
    __builtin_amdgcn_s_setprio(0);

    __syncthreads();   // B: all waves done reading Ksf -> safe to restage
    if (it > cs) stage(cur ^ 1, it - 1);  // prefetch next (older) tile

    // pass A: single growth scalar per lane. Row max via max over ni of
    // fmaf(s, scale2, ni*slope16) minus sb -- a DIFFERENT expression tree
    // than pass B (no CSE -> nothing but `grow` stays live). Mask ignored:
    // overestimated rm only ever forces the always-correct slow path.
    float grow = -1e30f;
#pragma unroll
    for (int mi = 0; mi < 2; ++mi)
#pragma unroll
      for (int r = 0; r < 4; ++r) {
        const int rowq = wave * 32 + mi * 16 + quad * 4 + r;
        const int qg = q0 + rowq;
        const float sb = slope2 * (float)(qg - kv0 - col);   // dist at ni=0
        float t0 = fmaxf(
            fmaxf(fmaf(s_acc[mi][0][r], scale2, 0.0f * slope16),
                  fmaf(s_acc[mi][1][r], scale2, 1.0f * slope16)),
            fmaxf(fmaf(s_acc[mi][2][r], scale2, 2.0f * slope16),
                  fmaf(s_acc[mi][3][r], scale2, 3.0f * slope16)));
        grow = fmaxf(grow, (t0 - sb) - m_i[mi][r]);
      }

    if (!__any(grow > 20.0f)) {
      // fast path: reference m is safe (P <= 2^20); no reduce, no rescale,
      // no m-update. pv = exp2(fma(s, scale2, ni*slope16 - sb - mref)).
#pragma unroll
      for (int mi = 0; mi < 2; ++mi)
#pragma unroll
        for (int r = 0; r < 4; ++r) {
          const int rowq = wave * 32 + mi * 16 + quad * 4 + r;
          const int qg = q0 + rowq;
          const float c0 = -slope2 * (float)(qg - kv0 - col) - m_i[mi][r];
          float ps = 0.f;
#pragma unroll
          for (int ni = 0; ni < 4; ++ni) {
            float pv = exp2f(fmaf(s_acc[mi][ni][r], scale2,
                                  (float)ni * slope16 + c0));
            if (masked && (kv0 + ni * 16 + col > qg)) pv = 0.f;
            ps += pv;
            Psf[rowq * 64 + ((((ni * 2) + (col >> 3)) ^ (rowq & 7)) << 3) +
                (col & 7)] = (bf16)pv;
          }
          l_i[mi][r] += ps;
        }
    } else {
      // slow path (tile 0 / rare excursion): full reduce + rescale.
#pragma unroll
      for (int mi = 0; mi < 2; ++mi)
#pragma unroll
        for (int r = 0; r < 4; ++r) {
          const int rowq = wave * 32 + mi * 16 + quad * 4 + r;
          const int qg = q0 + rowq;
          const float sb = slope2 * (float)(qg - kv0 - col);
          float svv[4];
#pragma unroll
          for (int ni = 0; ni < 4; ++ni) {
            svv[ni] = fmaf(s_acc[mi][ni][r], scale2, (float)ni * slope16 - sb);
            if (masked && (kv0 + ni * 16 + col > qg)) svv[ni] = -1e30f;
          }
          float rm = fmaxf(fmaxf(svv[0], svv[1]), fmaxf(svv[2], svv[3]));
#pragma unroll
          for (int off = 1; off < 16; off <<= 1)
            rm = fmaxf(rm, __shfl_xor(rm, off, 64));
          const float mold = m_i[mi][r];
          float mnew = fmaxf(mold, rm);
          if (masked) mnew = fmaxf(mnew, -1e20f);   // all-masked-row floor
          const float alpha = exp2f(mold - mnew);
          float ps = 0.f;
#pragma unroll
          for (int ni = 0; ni < 4; ++ni) {
            float pv = exp2f(svv[ni] - mnew);
            ps += pv;
            Psf[rowq * 64 + ((((ni * 2) + (col >> 3)) ^ (rowq & 7)) << 3) +
                (col & 7)] = (bf16)pv;
          }
          l_i[mi][r] = fmaf(alpha, l_i[mi][r], ps);
          m_i[mi][r] = mnew;
#pragma unroll
          for (int di = 0; di < 8; ++di) o_acc[mi][di][r] *= alpha;
        }
    }

    // O += P V (no barrier needed: Psf band is wave-private; Vs double-buffered)
    __builtin_amdgcn_s_setprio(1);
#pragma unroll
    for (int kstep = 0; kstep < 2; ++kstep) {
      bf16x8 pf[2];
#pragma unroll
      for (int mi = 0; mi < 2; ++mi)
        pf[mi] = *(const bf16x8*)&Psf[(wave * 32 + mi * 16 + col) * 64 +
                                      (((kstep * 4 + quad) ^ (col & 7)) << 3)];
#pragma unroll
      for (int di = 0; di < 8; ++di) {
        bf16x8 vf = *(const bf16x8*)&Vsf[cur][(di * 16 + col) * 64 +
                                             (((kstep * 4 + quad) ^ (col & 7)) << 3)];
#pragma unroll
        for (int mi = 0; mi < 2; ++mi)
          o_acc[mi][di] = __builtin_amdgcn_mfma_f32_16x16x32_bf16(
              pf[mi], vf, o_acc[mi][di], 0, 0, 0);
      }
    }
    __builtin_amdgcn_s_setprio(0);
  }

  if (part < 0) {
    // direct: normalize (reduce lane-partial l over the 16-lane row group)
#pragma unroll
    for (int mi = 0; mi < 2; ++mi)
#pragma unroll
      for (int r = 0; r < 4; ++r) {
        float lt = l_i[mi][r];
#pragma unroll
        for (int off = 1; off < 16; off <<= 1)
          lt += __shfl_xor(lt, off, 64);
        float rl = 1.0f / lt;
        long long qg = qrow0 + mi * 16 + quad * 4 + r;
#pragma unroll
        for (int di = 0; di < 8; ++di)
          O[qg * D + h * HD + di * 16 + col] = (bf16)(o_acc[mi][di][r] * rl);
      }
  } else {
    // partial: store unnormalized O~ (bf16) + m,l (fp32 per row)
    bf16* pb = parts + (long long)part * 16384;
    float* mlp = ml + (long long)part * 256;
#pragma unroll
    for (int mi = 0; mi < 2; ++mi)
#pragma unroll
      for (int r = 0; r < 4; ++r) {
        float lt = l_i[mi][r];
#pragma unroll
        for (int off = 1; off < 16; off <<= 1)
          lt += __shfl_xor(lt, off, 64);
        int rowq = wave * 32 + mi * 16 + quad * 4 + r;
        if (col == 0) { mlp[rowq] = m_i[mi][r]; mlp[128 + rowq] = lt; }
#pragma unroll
        for (int di = 0; di < 8; ++di)
          pb[rowq * 128 + di * 16 + col] = (bf16)o_acc[mi][di][r];
      }
  }
}

// ---------------------------------------------------------------------------
// Combine partial chunks: O = sum_c e2^(m_c-M) O~_c / sum_c e2^(m_c-M) l_c.
// (m are exp2-domain references; weights use exp2f.) One block per group;
// thread t: row = t>>1, cols (t&1)*64..+63.
// ---------------------------------------------------------------------------
__global__ __launch_bounds__(256) void attn_combine(
    const float* __restrict__ ml, const bf16* __restrict__ parts,
    bf16* __restrict__ O)
{
  const int meta = g_tab.grp[4 * blockIdx.x];
  const int first = g_tab.grp[4 * blockIdx.x + 1];
  const int n = g_tab.grp[4 * blockIdx.x + 2];
  const int b = meta & 1, h = (meta >> 1) & 15, qt = (meta >> 5) & 15;
  const int t = threadIdx.x;
  const int row = t >> 1, cg = t & 1;

  float M = -1e30f;
  for (int c = 0; c < n; ++c) M = fmaxf(M, ml[(long long)(first + c) * 256 + row]);

  float acc[64];
#pragma unroll
  for (int j = 0; j < 64; ++j) acc[j] = 0.f;
  float den = 0.f;
  for (int c = 0; c < n; ++c) {
    const float* mlc = ml + (long long)(first + c) * 256;
    float w = exp2f(mlc[row] - M);
    den = fmaf(w, mlc[128 + row], den);
    const bf16* p = parts + (long long)(first + c) * 16384 + row * 128 + cg * 64;
#pragma unroll
    for (int j8 = 0; j8 < 8; ++j8) {
      bf16x8 v = ((const bf16x8*)p)[j8];
#pragma unroll
      for (int k = 0; k < 8; ++k) acc[j8 * 8 + k] = fmaf(w, (float)v[k], acc[j8 * 8 + k]);
    }
  }
  float rd = 1.0f / den;
  long long qg = (long long)b * 2048 + qt * 128 + row;
  bf16* o = O + qg * 2048 + h * 128 + cg * 64;
#pragma unroll
  for (int j8 = 0; j8 < 8; ++j8) {
    bf16x8 v;
#pragma unroll
    for (int k = 0; k < 8; ++k) v[k] = (bf16)(acc[j8 * 8 + k] * rd);
    ((bf16x8*)o)[j8] = v;
  }
}

// ---------------------------------------------------------------------------
extern "C" void kernel_launch(void* const* d_in, const int* in_sizes, int n_in,
                              void* d_out, int out_size, void* d_ws, size_t ws_size,
                              hipStream_t stream) {
  (void)in_sizes; (void)n_in; (void)out_size; (void)ws_size;
  const float* hs  = (const float*)d_in[0];  // [2,2048,2048]
  const float* Wqd = (const float*)d_in[1];  // [1536,2048]
  const float* Wqu = (const float*)d_in[2];  // [2048,1536]
  const float* Wkv = (const float*)d_in[3];  // [512,2048]
  const float* kup = (const float*)d_in[4];  // [16,512,128]
  const float* vup = (const float*)d_in[5];  // [16,512,128]
  const float* Wo  = (const float*)d_in[6];  // [2048,2048]
  float* out = (float*)d_out;                // [2,2048,2048] fp32

  char* ws = (char*)d_ws;
  bf16* hsb  = (bf16*)ws; ws += (size_t)4096 * 2048 * 2;   // [also Ob]
  bf16* Wdcb = (bf16*)ws; ws += (size_t)2048 * 2048 * 2;   // concat(Wqd,Wkv)
  bf16* Wqub = (bf16*)ws; ws += (size_t)2048 * 1536 * 2;
  bf16* kupT = (bf16*)ws; ws += (size_t)16 * 128 * 512 * 2;
  bf16* vupT = (bf16*)ws; ws += (size_t)16 * 128 * 512 * 2;
  bf16* XC   = (bf16*)ws; ws += (size_t)4096 * 2048 * 2;   // [Xq | Cl] [also Wob]
  bf16* Qb   = (bf16*)ws; ws += (size_t)4096 * 2048 * 2;
  bf16* Kb   = (bf16*)ws; ws += (size_t)16 * 4096 * 128 * 2;
  bf16* VTb  = (bf16*)ws; ws += (size_t)16 * 128 * 4096 * 2;
  bf16* Cl   = XC + 1536;   // latent = cols [1536,2048) of XC, ld 2048
  bf16* Ob   = hsb;         // attn out aliases hsb
  bf16* Wob  = XC;          // Wo bf16 aliases XC

  // attention split scratch aliases Wdcb.. (dead by attention time):
  // [ml 448*256 f32][parts 448*128*128 bf16] = 15.1 MB
  float* mld   = (float*)Wdcb;
  bf16*  parts = (bf16*)(mld + 448 * 256);

  // fp32 -> bf16 converts
  cvt_f32_bf16<<<1024, 256, 0, stream>>>(hs, hsb, 4096 * 2048 / 4);
  cvt3_f32_bf16<<<1024, 256, 0, stream>>>(
      Wqd, Wdcb, 1536 * 2048 / 4,
      Wkv, Wdcb + (size_t)1536 * 2048, 512 * 2048 / 4,
      Wqu, Wqub, 2048 * 1536 / 4);
  transpose_cvt<<<dim3(2, 8, 16), 256, 0, stream>>>(kup, kupT, 512, 128);
  transpose_cvt<<<dim3(2, 8, 16), 256, 0, stream>>>(vup, vupT, 512, 128);

  // XC = hs * [Wq_down|Wkv_down]^T   [4096 x 2048 x 2048]
  gemm_nt<bf16><<<dim3(16, 32, 1), 256, 0, stream>>>(hsb, Wdcb, XC,
                                                     2048, 2048, 2048, 2048, 0, 0, 0);
  // Q, K[h], VT[h] projections: ONE 1536-block dispatch (3 blocks/CU)
  gemm_qkv<<<dim3(1536, 1, 1), 256, 0, stream>>>(XC, Wqub, kupT, vupT,
                                                 Qb, Kb, VTb);
  // Wo convert (into XC region, dead after gemm_qkv)
  cvt_f32_bf16<<<512, 256, 0, stream>>>(Wo, Wob, 2048 * 2048 / 4);
  // chunked attention + combine (tables are compile-time constants)
  attn_kernel<<<dim3(ATTN_BLOCKS, 1, 1), 256, 0, stream>>>(Qb, Kb, VTb, Ob, mld, parts);
  attn_combine<<<dim3(COMB_BLOCKS, 1, 1), 256, 0, stream>>>(mld, parts, Ob);
  // out = O * Wo^T                   [4096 x 2048 x 2048], fp32 output
  gemm_nt<float><<<dim3(16, 32, 1), 256, 0, stream>>>(Ob, Wob, out,
                                                      2048, 2048, 2048, 2048, 0, 0, 0);
}

// Round 9
// 390.559 us; speedup vs baseline: 1.2887x; 1.0051x over previous
//
#include <hip/hip_runtime.h>
#include <math.h>

// MLA + ALiBi causal attention. fp32 in/out, bf16 MFMA internal compute.
// R14: GEMM 2-phase double-buffer (T3 minimum recipe, m228d: 622 TF @128^2
// refcheck'd vs our ~420). R13's body was single-buffered with TWO barriers
// per K-step (stage drain fully serialized with compute). Now: As/Bs[2]
// (64KB LDS, 2 blocks/CU), prologue stage, ONE barrier per K-step, prefetch
// issued before compute -- staging overlaps MFMA. Same pattern as attn's
// V-dbuf (verified). Per-output accumulation order unchanged. Attn/combine/
// converts byte-identical to R13 (passed, 392.5us; attn 89us).
typedef __bf16 bf16;
typedef __bf16 bf16x8 __attribute__((ext_vector_type(8)));
typedef __bf16 bf16x4 __attribute__((ext_vector_type(4)));
typedef float f32x4 __attribute__((ext_vector_type(4)));

#define AS1 __attribute__((address_space(1)))
#define AS3 __attribute__((address_space(3)))

// Exact static decomposition (L=2048, 128-row q tiles, 64-key kv tiles,
// chunk = 8 kv tiles, ALiBi window WH[h]): per b: 172 direct + 224 chunks,
// 84 groups. Totals: 344 direct + 448 partial = 792 blocks; 168 groups.
#define ATTN_BLOCKS 792
#define COMB_BLOCKS 168

struct ATables {
  int tbl[ATTN_BLOCKS * 2];   // {meta, partIdx(-1=direct)}
  int grp[COMB_BLOCKS * 4];   // {meta, firstPart, nChunks, pad}
};

// meta = b | h<<1 | qt<<5 | cstart<<9 | clen<<16
constexpr ATables make_tables() {
  ATables T{};
  int WH[16] = {22,32,45,64,90,128,181,256,362,512,724,1024,1448,2048,2896,4096};
  int nc = 0, np = 0, ng = 0;
  for (int qt = 15; qt >= 0; --qt)
    for (int h = 15; h >= 0; --h)
      for (int b = 0; b < 2; ++b) {
        int q0 = qt * 128, nkv = 2 * qt + 2;
        int dlo = q0 - WH[h];
        int kv_lo = dlo > 0 ? (dlo >> 6) : 0;
        int span = nkv - kv_lo;
        int nch = (span + 7) >> 3;
        int base = b | (h << 1) | (qt << 5);
        if (nch == 1) {
          T.tbl[2 * nc] = base | (kv_lo << 9) | (span << 16);
          T.tbl[2 * nc + 1] = -1;
          ++nc;
        } else {
          T.grp[4 * ng] = base; T.grp[4 * ng + 1] = np; T.grp[4 * ng + 2] = nch;
          ++ng;
          for (int c = 0; c < nch; ++c) {
            int cs = kv_lo + c * 8;
            int cl = nkv - cs; if (cl > 8) cl = 8;
            T.tbl[2 * nc] = base | (cs << 9) | (cl << 16);
            T.tbl[2 * nc + 1] = np;
            ++nc; ++np;
          }
        }
      }
  return T;
}

__device__ const ATables g_tab = make_tables();

__device__ __forceinline__ void g2l16(const void* g, void* l) {
  // async global->LDS, 16B per lane; LDS dest is wave-uniform base + lane*16
  __builtin_amdgcn_global_load_lds((const AS1 void*)g, (AS3 void*)l, 16, 0, 0);
}

// ---------------------------------------------------------------------------
// fp32 -> bf16 elementwise convert (n4 = element count / 4)
// ---------------------------------------------------------------------------
__device__ __forceinline__ void cvt_seg(const float* __restrict__ in,
                                        bf16* __restrict__ out, int n4) {
  int i = blockIdx.x * 256 + threadIdx.x;
  const int stride = gridDim.x * 256;
  for (; i < n4; i += stride) {
    float4 v = ((const float4*)in)[i];
    bf16x4 o;
    o[0] = (bf16)v.x; o[1] = (bf16)v.y; o[2] = (bf16)v.z; o[3] = (bf16)v.w;
    ((bf16x4*)out)[i] = o;
  }
}

__global__ __launch_bounds__(256) void cvt_f32_bf16(
    const float* __restrict__ in, bf16* __restrict__ out, int n4) {
  cvt_seg(in, out, n4);
}

__global__ __launch_bounds__(256) void cvt3_f32_bf16(
    const float* __restrict__ s0, bf16* __restrict__ d0, int n0,
    const float* __restrict__ s1, bf16* __restrict__ d1, int n1,
    const float* __restrict__ s2, bf16* __restrict__ d2, int n2) {
  cvt_seg(s0, d0, n0);
  cvt_seg(s1, d1, n1);
  cvt_seg(s2, d2, n2);
}

// ---------------------------------------------------------------------------
// fused convert+transpose: fp32 [Z][R][D] -> bf16 [Z][D][R]. R%64==0, D%64==0.
// ---------------------------------------------------------------------------
__global__ __launch_bounds__(256) void transpose_cvt(
    const float* __restrict__ in, bf16* __restrict__ out, int R, int D)
{
  __shared__ bf16 tile[64][72];
  const long long base = (long long)blockIdx.z * R * D;
  const int r0 = blockIdx.y * 64, c0 = blockIdx.x * 64;
  const int t = threadIdx.x;
#pragma unroll
  for (int i = 0; i < 4; ++i) {
    int c = i * 256 + t;
    int rr = c >> 4, cc = (c & 15) << 2;
    float4 v = *(const float4*)&in[base + (long long)(r0 + rr) * D + c0 + cc];
    tile[rr][cc + 0] = (bf16)v.x;
    tile[rr][cc + 1] = (bf16)v.y;
    tile[rr][cc + 2] = (bf16)v.z;
    tile[rr][cc + 3] = (bf16)v.w;
  }
  __syncthreads();
#pragma unroll
  for (int i = 0; i < 2; ++i) {
    int c = i * 256 + t;
    int rr = c >> 3, cc = (c & 7) << 3;
    bf16x8 v;
#pragma unroll
    for (int j = 0; j < 8; ++j) v[j] = tile[cc + j][rr];
    *(bf16x8*)&out[base + (long long)(c0 + rr) * R + r0 + cc] = v;
  }
}

// ---------------------------------------------------------------------------
// NT GEMM: C[m,n] = sum_k A[m,k]*B[n,k]. 128x128 tile, BK=64, 4 waves.
// 2-phase double-buffered (T3 minimum): prologue stage buf0; per K-step
// ONE barrier, then issue stage(next) into buf^1, then ds_read+MFMA on cur.
// Barrier at loop top drains the prefetch vmcnt AND proves all waves done
// reading the buffer about to be overwritten.
// ---------------------------------------------------------------------------
template <typename CT>
__global__ __launch_bounds__(256) void gemm_nt(
    const bf16* __restrict__ A, const bf16* __restrict__ B, CT* __restrict__ C,
    int lda, int ldb, int ldc, int K, long long sA, long long sB, long long sC)
{
  A += (long long)blockIdx.z * sA;
  B += (long long)blockIdx.z * sB;
  C += (long long)blockIdx.z * sC;

  __shared__ bf16 As[2][128][64];
  __shared__ bf16 Bs[2][128][64];

  const int t = threadIdx.x;
  const int lane = t & 63, wave = t >> 6;
  const int wm = (wave >> 1) * 64, wn = (wave & 1) * 64;
  const int m0 = blockIdx.y * 128, n0 = blockIdx.x * 128;
  const int r16 = lane & 15, q8 = (lane >> 4) * 8;

  auto stage = [&](int buf, int k0) {
#pragma unroll
    for (int r = 0; r < 4; ++r) {
      int c = r * 256 + t;
      int row = c >> 3, col = (c & 7) << 3;
      g2l16(A + (long long)(m0 + row) * lda + (k0 + col), &As[buf][row][col]);
      g2l16(B + (long long)(n0 + row) * ldb + (k0 + col), &Bs[buf][row][col]);
    }
  };

  f32x4 acc[4][4] = {};

  stage(0, 0);
  int cur = 0;
  for (int k0 = 0; k0 < K; k0 += 64, cur ^= 1) {
    __syncthreads();                       // buf[cur] staged; prev reads done
    if (k0 + 64 < K) stage(cur ^ 1, k0 + 64);   // prefetch next K-step

#pragma unroll
    for (int ks = 0; ks < 2; ++ks) {
      bf16x8 af[4], bfr[4];
#pragma unroll
      for (int i = 0; i < 4; ++i)
        af[i]  = *(const bf16x8*)&As[cur][wm + i * 16 + r16][ks * 32 + q8];
#pragma unroll
      for (int i = 0; i < 4; ++i)
        bfr[i] = *(const bf16x8*)&Bs[cur][wn + i * 16 + r16][ks * 32 + q8];
#pragma unroll
      for (int mi = 0; mi < 4; ++mi)
#pragma unroll
        for (int ni = 0; ni < 4; ++ni)
          acc[mi][ni] = __builtin_amdgcn_mfma_f32_16x16x32_bf16(af[mi], bfr[ni], acc[mi][ni], 0, 0, 0);
    }
  }

  const int quad = lane >> 4;
#pragma unroll
  for (int mi = 0; mi < 4; ++mi)
#pragma unroll
    for (int ni = 0; ni < 4; ++ni)
#pragma unroll
      for (int r = 0; r < 4; ++r) {
        int mm = m0 + wm + mi * 16 + quad * 4 + r;
        int nn = n0 + wn + ni * 16 + r16;
        C[(long long)mm * ldc + nn] = (CT)acc[mi][ni][r];
      }
}

// ---------------------------------------------------------------------------
// Merged Q/K/VT projection GEMM: 1536 blocks in ONE dispatch.
//   g in [0,512):    Q  = Xq * Wq_up^T   [4096 x 2048], K=1536
//   g in [512,1024): K[h] = Cl * kupT[h]^T [4096 x 128] x16, K=512
//   g in [1024,1536):VT[h] = vupT[h] * Cl^T [128 x 4096] x16, K=512
// Same 2-phase double-buffered body.
// ---------------------------------------------------------------------------
__global__ __launch_bounds__(256) void gemm_qkv(
    const bf16* __restrict__ XCp, const bf16* __restrict__ Wqub,
    const bf16* __restrict__ kupT, const bf16* __restrict__ vupT,
    bf16* __restrict__ Qb, bf16* __restrict__ Kb, bf16* __restrict__ VTb)
{
  const bf16* Cl = XCp + 1536;
  const int g = blockIdx.x;
  const bf16 *A, *B;
  bf16* C;
  int lda, ldb, ldc, K, m0, n0;
  if (g < 512) {            // Q
    A = XCp; B = Wqub; C = Qb;
    lda = 2048; ldb = 1536; ldc = 2048; K = 1536;
    n0 = (g & 15) * 128; m0 = (g >> 4) * 128;
  } else if (g < 1024) {    // K[h]
    int i = g - 512, bz = i >> 5, by = i & 31;
    A = Cl; B = kupT + bz * 65536; C = Kb + (long long)bz * 524288;
    lda = 2048; ldb = 512; ldc = 128; K = 512;
    m0 = by * 128; n0 = 0;
  } else {                  // VT[h]
    int i = g - 1024, bz = i >> 5, bx = i & 31;
    A = vupT + bz * 65536; B = Cl; C = VTb + (long long)bz * 524288;
    lda = 512; ldb = 2048; ldc = 4096; K = 512;
    m0 = 0; n0 = bx * 128;
  }

  __shared__ bf16 As[2][128][64];
  __shared__ bf16 Bs[2][128][64];

  const int t = threadIdx.x;
  const int lane = t & 63, wave = t >> 6;
  const int wm = (wave >> 1) * 64, wn = (wave & 1) * 64;
  const int r16 = lane & 15, q8 = (lane >> 4) * 8;

  auto stage = [&](int buf, int k0) {
#pragma unroll
    for (int r = 0; r < 4; ++r) {
      int c = r * 256 + t;
      int row = c >> 3, col = (c & 7) << 3;
      g2l16(A + (long long)(m0 + row) * lda + (k0 + col), &As[buf][row][col]);
      g2l16(B + (long long)(n0 + row) * ldb + (k0 + col), &Bs[buf][row][col]);
    }
  };

  f32x4 acc[4][4] = {};

  stage(0, 0);
  int cur = 0;
  for (int k0 = 0; k0 < K; k0 += 64, cur ^= 1) {
    __syncthreads();
    if (k0 + 64 < K) stage(cur ^ 1, k0 + 64);

#pragma unroll
    for (int ks = 0; ks < 2; ++ks) {
      bf16x8 af[4], bfr[4];
#pragma unroll
      for (int i = 0; i < 4; ++i)
        af[i]  = *(const bf16x8*)&As[cur][wm + i * 16 + r16][ks * 32 + q8];
#pragma unroll
      for (int i = 0; i < 4; ++i)
        bfr[i] = *(const bf16x8*)&Bs[cur][wn + i * 16 + r16][ks * 32 + q8];
#pragma unroll
      for (int mi = 0; mi < 4; ++mi)
#pragma unroll
        for (int ni = 0; ni < 4; ++ni)
          acc[mi][ni] = __builtin_amdgcn_mfma_f32_16x16x32_bf16(af[mi], bfr[ni], acc[mi][ni], 0, 0, 0);
    }
  }

  const int quad = lane >> 4;
#pragma unroll
  for (int mi = 0; mi < 4; ++mi)
#pragma unroll
    for (int ni = 0; ni < 4; ++ni)
#pragma unroll
      for (int r = 0; r < 4; ++r) {
        int mm = m0 + wm + mi * 16 + quad * 4 + r;
        int nn = n0 + wn + ni * 16 + r16;
        C[(long long)mm * ldc + nn] = (bf16)acc[mi][ni][r];
      }
}

// ---------------------------------------------------------------------------
// Flash attention, chunked, 64-key tiles, REVERSED order (diagonal first).
// Block = table entry: 128 q rows of (b,h,qt) over KV tiles [cs,cs+cl),
// iterated cend-1 .. cs. K SINGLE-buffered, V double-buffered, Psf wave-
// private => LDS 64KB. Two barriers per tile:
//   A: drains vmcnt (K + V[cur] staged) / all waves left prev K section
//   QK^T (K consumed into regs)
//   B: all waves done reading Ksf -> safe to overwrite
//   stage K(next) + V(next) ; softmax ; PV (Vsf[cur], Psf)
// Softmax: exp2 domain, vote-gated fast path (no reduce/rescale; pass A
// growth scalar via separate expression tree). Slow path = full reduce.
// Causal mask on tiles >= nkv-2. LDS XOR-swizzled (conflict-free).
// ---------------------------------------------------------------------------
__global__ __launch_bounds__(256) void attn_kernel(
    const bf16* __restrict__ Q, const bf16* __restrict__ Kh,
    const bf16* __restrict__ VT, bf16* __restrict__ O,
    float* __restrict__ ml, bf16* __restrict__ parts)
{
  const int L = 2048, HD = 128, D = 2048;
  const int meta = g_tab.tbl[2 * blockIdx.x];
  const int part = g_tab.tbl[2 * blockIdx.x + 1];
  const int b = meta & 1, h = (meta >> 1) & 15, qt = (meta >> 5) & 15;
  const int cs = (meta >> 9) & 127, cl = (meta >> 16) & 15;
  const int q0 = qt * 128, nkv = 2 * qt + 2;
  const int cend = cs + cl;
  // mask any diagonal tile (>= nkv-2) present in this chunk:
  const int mraw = nkv - 2 > cs ? nkv - 2 : cs;
  const int mstart = mraw < cend ? mraw : cend;

  const int t = threadIdx.x, wave = t >> 6, lane = t & 63;
  const int col = lane & 15, quad = lane >> 4;
  const float LOG2E = 1.44269504f;
  const float slope2 = exp2f(-0.5f * (float)(h + 1)) * LOG2E;  // exp2-domain
  const float slope16 = slope2 * 16.0f;
  const float scale2 = 0.08838834764831845f * LOG2E;   // (1/sqrt(128))*log2e

  __shared__ bf16 Ksf[64 * 128];      // [key][d], 16 chunks/row, swz mask 15
  __shared__ bf16 Vsf[2][128 * 64];   // [d][key],  8 chunks/row, swz mask 7
  __shared__ bf16 Psf[128 * 64];      // [q][key], wave-private 32-row bands

  const long long qrow0 = (long long)(b * L + q0 + wave * 32);
  const long long kbase = (long long)(h * 4096 + b * L) * HD;
  const long long vbase = (long long)(h * HD) * 4096 + b * L;

  auto stage = [&](int vbuf, int itile) {
    const int kv0 = itile << 6;
#pragma unroll
    for (int i = 0; i < 4; ++i) {
      int P = i * 256 + t;   // physical 16B chunk index (contiguous per wave)
      {  // K: row = P>>4, phys chunk p = P&15, logical chunk = p ^ (row&15)
        int rr = P >> 4, cc = ((P & 15) ^ (rr & 15)) << 3;
        g2l16(Kh + kbase + (long long)(kv0 + rr) * HD + cc, &Ksf[P * 8]);
      }
      {  // V: row = P>>3, phys chunk p = P&7, logical chunk = p ^ (row&7)
        int rr = P >> 3, cc = ((P & 7) ^ (rr & 7)) << 3;
        g2l16(VT + vbase + (long long)rr * 4096 + kv0 + cc, &Vsf[vbuf][P * 8]);
      }
    }
  };

  bf16x8 qf[2][4];
#pragma unroll
  for (int mi = 0; mi < 2; ++mi)
#pragma unroll
    for (int ks = 0; ks < 4; ++ks)
      qf[mi][ks] = *(const bf16x8*)&Q[(qrow0 + mi * 16 + col) * D + h * HD + ks * 32 + quad * 8];

  f32x4 o_acc[2][8] = {};
  float m_i[2][4], l_i[2][4];   // l lane-partial (this lane's 4 cols)
#pragma unroll
  for (int mi = 0; mi < 2; ++mi)
#pragma unroll
    for (int r = 0; r < 4; ++r) { m_i[mi][r] = -1e30f; l_i[mi][r] = 0.f; }

  stage(0, cend - 1);

  for (int it = cend - 1; it >= cs; --it) {
    const int cur = (cend - 1 - it) & 1;
    const int kv0 = it << 6;
    const bool masked = (it >= mstart);   // wave-uniform

    __syncthreads();   // A: drains vmcnt -> Ksf + Vsf[cur] ready

    // S = Q K^T  (per wave: 2 m-tiles x 4 n-tiles, 4 k-steps over d=128)
    f32x4 s_acc[2][4] = {};
    __builtin_amdgcn_s_setprio(1);
#pragma unroll
    for (int ks = 0; ks < 4; ++ks) {
      bf16x8 kf[4];
#pragma unroll
      for (int ni = 0; ni < 4; ++ni)
        kf[ni] = *(const bf16x8*)&Ksf[(ni * 16 + col) * 128 +
                                      (((ks * 4 + quad) ^ col) << 3)];
#pragma unroll
      for (int mi = 0; mi < 2; ++mi)
#pragma unroll
        for (int ni = 0; ni < 4; ++ni)
          s_acc[mi][ni] = __builtin_amdgcn_mfma_f32_16x16x32_bf16(
              qf[mi][ks], kf[ni], s_acc[mi][ni], 0, 0, 0);
    }
    __builtin_amdgcn_s_setprio(0);

    __syncthreads();   // B: all waves done reading Ksf -> safe to restage
    if (it > cs) stage(cur ^ 1, it - 1);  // prefetch next (older) tile

    // pass A: single growth scalar per lane. Row max via max over ni of
    // fmaf(s, scale2, ni*slope16) minus sb -- a DIFFERENT expression tree
    // than pass B (no CSE -> nothing but `grow` stays live). Mask ignored:
    // overestimated rm only ever forces the always-correct slow path.
    float grow = -1e30f;
#pragma unroll
    for (int mi = 0; mi < 2; ++mi)
#pragma unroll
      for (int r = 0; r < 4; ++r) {
        const int rowq = wave * 32 + mi * 16 + quad * 4 + r;
        const int qg = q0 + rowq;
        const float sb = slope2 * (float)(qg - kv0 - col);   // dist at ni=0
        float t0 = fmaxf(
            fmaxf(fmaf(s_acc[mi][0][r], scale2, 0.0f * slope16),
                  fmaf(s_acc[mi][1][r], scale2, 1.0f * slope16)),
            fmaxf(fmaf(s_acc[mi][2][r], scale2, 2.0f * slope16),
                  fmaf(s_acc[mi][3][r], scale2, 3.0f * slope16)));
        grow = fmaxf(grow, (t0 - sb) - m_i[mi][r]);
      }

    if (!__any(grow > 20.0f)) {
      // fast path: reference m is safe (P <= 2^20); no reduce, no rescale,
      // no m-update. pv = exp2(fma(s, scale2, ni*slope16 - sb - mref)).
#pragma unroll
      for (int mi = 0; mi < 2; ++mi)
#pragma unroll
        for (int r = 0; r < 4; ++r) {
          const int rowq = wave * 32 + mi * 16 + quad * 4 + r;
          const int qg = q0 + rowq;
          const float c0 = -slope2 * (float)(qg - kv0 - col) - m_i[mi][r];
          float ps = 0.f;
#pragma unroll
          for (int ni = 0; ni < 4; ++ni) {
            float pv = exp2f(fmaf(s_acc[mi][ni][r], scale2,
                                  (float)ni * slope16 + c0));
            if (masked && (kv0 + ni * 16 + col > qg)) pv = 0.f;
            ps += pv;
            Psf[rowq * 64 + ((((ni * 2) + (col >> 3)) ^ (rowq & 7)) << 3) +
                (col & 7)] = (bf16)pv;
          }
          l_i[mi][r] += ps;
        }
    } else {
      // slow path (tile 0 / rare excursion): full reduce + rescale.
#pragma unroll
      for (int mi = 0; mi < 2; ++mi)
#pragma unroll
        for (int r = 0; r < 4; ++r) {
          const int rowq = wave * 32 + mi * 16 + quad * 4 + r;
          const int qg = q0 + rowq;
          const float sb = slope2 * (float)(qg - kv0 - col);
          float svv[4];
#pragma unroll
          for (int ni = 0; ni < 4; ++ni) {
            svv[ni] = fmaf(s_acc[mi][ni][r], scale2, (float)ni * slope16 - sb);
            if (masked && (kv0 + ni * 16 + col > qg)) svv[ni] = -1e30f;
          }
          float rm = fmaxf(fmaxf(svv[0], svv[1]), fmaxf(svv[2], svv[3]));
#pragma unroll
          for (int off = 1; off < 16; off <<= 1)
            rm = fmaxf(rm, __shfl_xor(rm, off, 64));
          const float mold = m_i[mi][r];
          float mnew = fmaxf(mold, rm);
          if (masked) mnew = fmaxf(mnew, -1e20f);   // all-masked-row floor
          const float alpha = exp2f(mold - mnew);
          float ps = 0.f;
#pragma unroll
          for (int ni = 0; ni < 4; ++ni) {
            float pv = exp2f(svv[ni] - mnew);
            ps += pv;
            Psf[rowq * 64 + ((((ni * 2) + (col >> 3)) ^ (rowq & 7)) << 3) +
                (col & 7)] = (bf16)pv;
          }
          l_i[mi][r] = fmaf(alpha, l_i[mi][r], ps);
          m_i[mi][r] = mnew;
#pragma unroll
          for (int di = 0; di < 8; ++di) o_acc[mi][di][r] *= alpha;
        }
    }

    // O += P V (no barrier needed: Psf band is wave-private; Vs double-buffered)
    __builtin_amdgcn_s_setprio(1);
#pragma unroll
    for (int kstep = 0; kstep < 2; ++kstep) {
      bf16x8 pf[2];
#pragma unroll
      for (int mi = 0; mi < 2; ++mi)
        pf[mi] = *(const bf16x8*)&Psf[(wave * 32 + mi * 16 + col) * 64 +
                                      (((kstep * 4 + quad) ^ (col & 7)) << 3)];
#pragma unroll
      for (int di = 0; di < 8; ++di) {
        bf16x8 vf = *(const bf16x8*)&Vsf[cur][(di * 16 + col) * 64 +
                                             (((kstep * 4 + quad) ^ (col & 7)) << 3)];
#pragma unroll
        for (int mi = 0; mi < 2; ++mi)
          o_acc[mi][di] = __builtin_amdgcn_mfma_f32_16x16x32_bf16(
              pf[mi], vf, o_acc[mi][di], 0, 0, 0);
      }
    }
    __builtin_amdgcn_s_setprio(0);
  }

  if (part < 0) {
    // direct: normalize (reduce lane-partial l over the 16-lane row group)
#pragma unroll
    for (int mi = 0; mi < 2; ++mi)
#pragma unroll
      for (int r = 0; r < 4; ++r) {
        float lt = l_i[mi][r];
#pragma unroll
        for (int off = 1; off < 16; off <<= 1)
          lt += __shfl_xor(lt, off, 64);
        float rl = 1.0f / lt;
        long long qg = qrow0 + mi * 16 + quad * 4 + r;
#pragma unroll
        for (int di = 0; di < 8; ++di)
          O[qg * D + h * HD + di * 16 + col] = (bf16)(o_acc[mi][di][r] * rl);
      }
  } else {
    // partial: store unnormalized O~ (bf16) + m,l (fp32 per row)
    bf16* pb = parts + (long long)part * 16384;
    float* mlp = ml + (long long)part * 256;
#pragma unroll
    for (int mi = 0; mi < 2; ++mi)
#pragma unroll
      for (int r = 0; r < 4; ++r) {
        float lt = l_i[mi][r];
#pragma unroll
        for (int off = 1; off < 16; off <<= 1)
          lt += __shfl_xor(lt, off, 64);
        int rowq = wave * 32 + mi * 16 + quad * 4 + r;
        if (col == 0) { mlp[rowq] = m_i[mi][r]; mlp[128 + rowq] = lt; }
#pragma unroll
        for (int di = 0; di < 8; ++di)
          pb[rowq * 128 + di * 16 + col] = (bf16)o_acc[mi][di][r];
      }
  }
}

// ---------------------------------------------------------------------------
// Combine partial chunks: O = sum_c e2^(m_c-M) O~_c / sum_c e2^(m_c-M) l_c.
// (m are exp2-domain references; weights use exp2f.) One block per group;
// thread t: row = t>>1, cols (t&1)*64..+63.
// ---------------------------------------------------------------------------
__global__ __launch_bounds__(256) void attn_combine(
    const float* __restrict__ ml, const bf16* __restrict__ parts,
    bf16* __restrict__ O)
{
  const int meta = g_tab.grp[4 * blockIdx.x];
  const int first = g_tab.grp[4 * blockIdx.x + 1];
  const int n = g_tab.grp[4 * blockIdx.x + 2];
  const int b = meta & 1, h = (meta >> 1) & 15, qt = (meta >> 5) & 15;
  const int t = threadIdx.x;
  const int row = t >> 1, cg = t & 1;

  float M = -1e30f;
  for (int c = 0; c < n; ++c) M = fmaxf(M, ml[(long long)(first + c) * 256 + row]);

  float acc[64];
#pragma unroll
  for (int j = 0; j < 64; ++j) acc[j] = 0.f;
  float den = 0.f;
  for (int c = 0; c < n; ++c) {
    const float* mlc = ml + (long long)(first + c) * 256;
    float w = exp2f(mlc[row] - M);
    den = fmaf(w, mlc[128 + row], den);
    const bf16* p = parts + (long long)(first + c) * 16384 + row * 128 + cg * 64;
#pragma unroll
    for (int j8 = 0; j8 < 8; ++j8) {
      bf16x8 v = ((const bf16x8*)p)[j8];
#pragma unroll
      for (int k = 0; k < 8; ++k) acc[j8 * 8 + k] = fmaf(w, (float)v[k], acc[j8 * 8 + k]);
    }
  }
  float rd = 1.0f / den;
  long long qg = (long long)b * 2048 + qt * 128 + row;
  bf16* o = O + qg * 2048 + h * 128 + cg * 64;
#pragma unroll
  for (int j8 = 0; j8 < 8; ++j8) {
    bf16x8 v;
#pragma unroll
    for (int k = 0; k < 8; ++k) v[k] = (bf16)(acc[j8 * 8 + k] * rd);
    ((bf16x8*)o)[j8] = v;
  }
}

// ---------------------------------------------------------------------------
extern "C" void kernel_launch(void* const* d_in, const int* in_sizes, int n_in,
                              void* d_out, int out_size, void* d_ws, size_t ws_size,
                              hipStream_t stream) {
  (void)in_sizes; (void)n_in; (void)out_size; (void)ws_size;
  const float* hs  = (const float*)d_in[0];  // [2,2048,2048]
  const float* Wqd = (const float*)d_in[1];  // [1536,2048]
  const float* Wqu = (const float*)d_in[2];  // [2048,1536]
  const float* Wkv = (const float*)d_in[3];  // [512,2048]
  const float* kup = (const float*)d_in[4];  // [16,512,128]
  const float* vup = (const float*)d_in[5];  // [16,512,128]
  const float* Wo  = (const float*)d_in[6];  // [2048,2048]
  float* out = (float*)d_out;                // [2,2048,2048] fp32

  char* ws = (char*)d_ws;
  bf16* hsb  = (bf16*)ws; ws += (size_t)4096 * 2048 * 2;   // [also Ob]
  bf16* Wdcb = (bf16*)ws; ws += (size_t)2048 * 2048 * 2;   // concat(Wqd,Wkv)
  bf16* Wqub = (bf16*)ws; ws += (size_t)2048 * 1536 * 2;
  bf16* kupT = (bf16*)ws; ws += (size_t)16 * 128 * 512 * 2;
  bf16* vupT = (bf16*)ws; ws += (size_t)16 * 128 * 512 * 2;
  bf16* XC   = (bf16*)ws; ws += (size_t)4096 * 2048 * 2;   // [Xq | Cl] [also Wob]
  bf16* Qb   = (bf16*)ws; ws += (size_t)4096 * 2048 * 2;
  bf16* Kb   = (bf16*)ws; ws += (size_t)16 * 4096 * 128 * 2;
  bf16* VTb  = (bf16*)ws; ws += (size_t)16 * 128 * 4096 * 2;
  bf16* Cl   = XC + 1536;   // latent = cols [1536,2048) of XC, ld 2048
  bf16* Ob   = hsb;         // attn out aliases hsb
  bf16* Wob  = XC;          // Wo bf16 aliases XC

  // attention split scratch aliases Wdcb.. (dead by attention time):
  // [ml 448*256 f32][parts 448*128*128 bf16] = 15.1 MB
  float* mld   = (float*)Wdcb;
  bf16*  parts = (bf16*)(mld + 448 * 256);

  // fp32 -> bf16 converts
  cvt_f32_bf16<<<1024, 256, 0, stream>>>(hs, hsb, 4096 * 2048 / 4);
  cvt3_f32_bf16<<<1024, 256, 0, stream>>>(
      Wqd, Wdcb, 1536 * 2048 / 4,
      Wkv, Wdcb + (size_t)1536 * 2048, 512 * 2048 / 4,
      Wqu, Wqub, 2048 * 1536 / 4);
  transpose_cvt<<<dim3(2, 8, 16), 256, 0, stream>>>(kup, kupT, 512, 128);
  transpose_cvt<<<dim3(2, 8, 16), 256, 0, stream>>>(vup, vupT, 512, 128);

  // XC = hs * [Wq_down|Wkv_down]^T   [4096 x 2048 x 2048]
  gemm_nt<bf16><<<dim3(16, 32, 1), 256, 0, stream>>>(hsb, Wdcb, XC,
                                                     2048, 2048, 2048, 2048, 0, 0, 0);
  // Q, K[h], VT[h] projections: ONE 1536-block dispatch
  gemm_qkv<<<dim3(1536, 1, 1), 256, 0, stream>>>(XC, Wqub, kupT, vupT,
                                                 Qb, Kb, VTb);
  // Wo convert (into XC region, dead after gemm_qkv)
  cvt_f32_bf16<<<512, 256, 0, stream>>>(Wo, Wob, 2048 * 2048 / 4);
  // chunked attention + combine (tables are compile-time constants)
  attn_kernel<<<dim3(ATTN_BLOCKS, 1, 1), 256, 0, stream>>>(Qb, Kb, VTb, Ob, mld, parts);
  attn_combine<<<dim3(COMB_BLOCKS, 1, 1), 256, 0, stream>>>(mld, parts, Ob);
  // out = O * Wo^T                   [4096 x 2048 x 2048], fp32 output
  gemm_nt<float><<<dim3(16, 32, 1), 256, 0, stream>>>(Ob, Wob, out,
                                                      2048, 2048, 2048, 2048, 0, 0, 0);
}

// Round 10
// 387.339 us; speedup vs baseline: 1.2994x; 1.0083x over previous
//
#include <hip/hip_runtime.h>
#include <math.h>

// MLA + ALiBi causal attention. fp32 in/out, bf16 MFMA internal compute.
// R15: GEMM = dbuf pipeline at BK=32 (32KB LDS) + __launch_bounds__(256,3).
// R14 post-mortem: dbuf@64KB halved LDS-allowed blocks/CU (2 vs 3-5 at
// 32KB) -- overlap gain cancelled by residency loss (m99/m100 repeat).
// m97's 912 TF regime = 32KB + VGPR<=168 -> 12 waves/CU. This config keeps
// the 1-barrier-per-K-step pipeline AND the residency: qkv (1536 blocks)
// can reach 3 blocks/CU; XC/out grid-capped at 2. Bounds pin 3 waves/SIMD
// (body ~135 VGPR, no spill expected -- watch WRITE_SIZE). Same k-order
// per output -> bit-identical. Attn/combine/converts byte-identical to R14.
typedef __bf16 bf16;
typedef __bf16 bf16x8 __attribute__((ext_vector_type(8)));
typedef __bf16 bf16x4 __attribute__((ext_vector_type(4)));
typedef float f32x4 __attribute__((ext_vector_type(4)));

#define AS1 __attribute__((address_space(1)))
#define AS3 __attribute__((address_space(3)))

// Exact static decomposition (L=2048, 128-row q tiles, 64-key kv tiles,
// chunk = 8 kv tiles, ALiBi window WH[h]): per b: 172 direct + 224 chunks,
// 84 groups. Totals: 344 direct + 448 partial = 792 blocks; 168 groups.
#define ATTN_BLOCKS 792
#define COMB_BLOCKS 168

struct ATables {
  int tbl[ATTN_BLOCKS * 2];   // {meta, partIdx(-1=direct)}
  int grp[COMB_BLOCKS * 4];   // {meta, firstPart, nChunks, pad}
};

// meta = b | h<<1 | qt<<5 | cstart<<9 | clen<<16
constexpr ATables make_tables() {
  ATables T{};
  int WH[16] = {22,32,45,64,90,128,181,256,362,512,724,1024,1448,2048,2896,4096};
  int nc = 0, np = 0, ng = 0;
  for (int qt = 15; qt >= 0; --qt)
    for (int h = 15; h >= 0; --h)
      for (int b = 0; b < 2; ++b) {
        int q0 = qt * 128, nkv = 2 * qt + 2;
        int dlo = q0 - WH[h];
        int kv_lo = dlo > 0 ? (dlo >> 6) : 0;
        int span = nkv - kv_lo;
        int nch = (span + 7) >> 3;
        int base = b | (h << 1) | (qt << 5);
        if (nch == 1) {
          T.tbl[2 * nc] = base | (kv_lo << 9) | (span << 16);
          T.tbl[2 * nc + 1] = -1;
          ++nc;
        } else {
          T.grp[4 * ng] = base; T.grp[4 * ng + 1] = np; T.grp[4 * ng + 2] = nch;
          ++ng;
          for (int c = 0; c < nch; ++c) {
            int cs = kv_lo + c * 8;
            int cl = nkv - cs; if (cl > 8) cl = 8;
            T.tbl[2 * nc] = base | (cs << 9) | (cl << 16);
            T.tbl[2 * nc + 1] = np;
            ++nc; ++np;
          }
        }
      }
  return T;
}

__device__ const ATables g_tab = make_tables();

__device__ __forceinline__ void g2l16(const void* g, void* l) {
  // async global->LDS, 16B per lane; LDS dest is wave-uniform base + lane*16
  __builtin_amdgcn_global_load_lds((const AS1 void*)g, (AS3 void*)l, 16, 0, 0);
}

// ---------------------------------------------------------------------------
// fp32 -> bf16 elementwise convert (n4 = element count / 4)
// ---------------------------------------------------------------------------
__device__ __forceinline__ void cvt_seg(const float* __restrict__ in,
                                        bf16* __restrict__ out, int n4) {
  int i = blockIdx.x * 256 + threadIdx.x;
  const int stride = gridDim.x * 256;
  for (; i < n4; i += stride) {
    float4 v = ((const float4*)in)[i];
    bf16x4 o;
    o[0] = (bf16)v.x; o[1] = (bf16)v.y; o[2] = (bf16)v.z; o[3] = (bf16)v.w;
    ((bf16x4*)out)[i] = o;
  }
}

__global__ __launch_bounds__(256) void cvt_f32_bf16(
    const float* __restrict__ in, bf16* __restrict__ out, int n4) {
  cvt_seg(in, out, n4);
}

__global__ __launch_bounds__(256) void cvt3_f32_bf16(
    const float* __restrict__ s0, bf16* __restrict__ d0, int n0,
    const float* __restrict__ s1, bf16* __restrict__ d1, int n1,
    const float* __restrict__ s2, bf16* __restrict__ d2, int n2) {
  cvt_seg(s0, d0, n0);
  cvt_seg(s1, d1, n1);
  cvt_seg(s2, d2, n2);
}

// ---------------------------------------------------------------------------
// fused convert+transpose: fp32 [Z][R][D] -> bf16 [Z][D][R]. R%64==0, D%64==0.
// ---------------------------------------------------------------------------
__global__ __launch_bounds__(256) void transpose_cvt(
    const float* __restrict__ in, bf16* __restrict__ out, int R, int D)
{
  __shared__ bf16 tile[64][72];
  const long long base = (long long)blockIdx.z * R * D;
  const int r0 = blockIdx.y * 64, c0 = blockIdx.x * 64;
  const int t = threadIdx.x;
#pragma unroll
  for (int i = 0; i < 4; ++i) {
    int c = i * 256 + t;
    int rr = c >> 4, cc = (c & 15) << 2;
    float4 v = *(const float4*)&in[base + (long long)(r0 + rr) * D + c0 + cc];
    tile[rr][cc + 0] = (bf16)v.x;
    tile[rr][cc + 1] = (bf16)v.y;
    tile[rr][cc + 2] = (bf16)v.z;
    tile[rr][cc + 3] = (bf16)v.w;
  }
  __syncthreads();
#pragma unroll
  for (int i = 0; i < 2; ++i) {
    int c = i * 256 + t;
    int rr = c >> 3, cc = (c & 7) << 3;
    bf16x8 v;
#pragma unroll
    for (int j = 0; j < 8; ++j) v[j] = tile[cc + j][rr];
    *(bf16x8*)&out[base + (long long)(c0 + rr) * R + r0 + cc] = v;
  }
}

// ---------------------------------------------------------------------------
// NT GEMM: C[m,n] = sum_k A[m,k]*B[n,k]. 128x128 tile, BK=32, 4 waves.
// 2-phase double-buffered at 32KB LDS: prologue stage buf0; per K-step ONE
// barrier, then issue stage(next) into buf^1, then ds_read+MFMA on cur.
// __launch_bounds__(256,3) pins 3 waves/SIMD (12 waves/CU) -- the m97/m103
// residency regime -- while keeping the 1-barrier pipeline.
// ---------------------------------------------------------------------------
template <typename CT>
__global__ __launch_bounds__(256, 3) void gemm_nt(
    const bf16* __restrict__ A, const bf16* __restrict__ B, CT* __restrict__ C,
    int lda, int ldb, int ldc, int K, long long sA, long long sB, long long sC)
{
  A += (long long)blockIdx.z * sA;
  B += (long long)blockIdx.z * sB;
  C += (long long)blockIdx.z * sC;

  __shared__ bf16 As[2][128][32];
  __shared__ bf16 Bs[2][128][32];

  const int t = threadIdx.x;
  const int lane = t & 63, wave = t >> 6;
  const int wm = (wave >> 1) * 64, wn = (wave & 1) * 64;
  const int m0 = blockIdx.y * 128, n0 = blockIdx.x * 128;
  const int r16 = lane & 15, q8 = (lane >> 4) * 8;

  auto stage = [&](int buf, int k0) {
#pragma unroll
    for (int r = 0; r < 2; ++r) {
      int c = r * 256 + t;
      int row = c >> 2, col = (c & 3) << 3;
      g2l16(A + (long long)(m0 + row) * lda + (k0 + col), &As[buf][row][col]);
      g2l16(B + (long long)(n0 + row) * ldb + (k0 + col), &Bs[buf][row][col]);
    }
  };

  f32x4 acc[4][4] = {};

  stage(0, 0);
  int cur = 0;
  for (int k0 = 0; k0 < K; k0 += 32, cur ^= 1) {
    __syncthreads();                       // buf[cur] staged; prev reads done
    if (k0 + 32 < K) stage(cur ^ 1, k0 + 32);   // prefetch next K-step

    bf16x8 af[4], bfr[4];
#pragma unroll
    for (int i = 0; i < 4; ++i)
      af[i]  = *(const bf16x8*)&As[cur][wm + i * 16 + r16][q8];
#pragma unroll
    for (int i = 0; i < 4; ++i)
      bfr[i] = *(const bf16x8*)&Bs[cur][wn + i * 16 + r16][q8];
#pragma unroll
    for (int mi = 0; mi < 4; ++mi)
#pragma unroll
      for (int ni = 0; ni < 4; ++ni)
        acc[mi][ni] = __builtin_amdgcn_mfma_f32_16x16x32_bf16(af[mi], bfr[ni], acc[mi][ni], 0, 0, 0);
  }

  const int quad = lane >> 4;
#pragma unroll
  for (int mi = 0; mi < 4; ++mi)
#pragma unroll
    for (int ni = 0; ni < 4; ++ni)
#pragma unroll
      for (int r = 0; r < 4; ++r) {
        int mm = m0 + wm + mi * 16 + quad * 4 + r;
        int nn = n0 + wn + ni * 16 + r16;
        C[(long long)mm * ldc + nn] = (CT)acc[mi][ni][r];
      }
}

// ---------------------------------------------------------------------------
// Merged Q/K/VT projection GEMM: 1536 blocks in ONE dispatch.
//   g in [0,512):    Q  = Xq * Wq_up^T   [4096 x 2048], K=1536
//   g in [512,1024): K[h] = Cl * kupT[h]^T [4096 x 128] x16, K=512
//   g in [1024,1536):VT[h] = vupT[h] * Cl^T [128 x 4096] x16, K=512
// Same 2-phase dbuf BK=32 body; 32KB LDS + bounds(256,3) -> 3 blocks/CU.
// ---------------------------------------------------------------------------
__global__ __launch_bounds__(256, 3) void gemm_qkv(
    const bf16* __restrict__ XCp, const bf16* __restrict__ Wqub,
    const bf16* __restrict__ kupT, const bf16* __restrict__ vupT,
    bf16* __restrict__ Qb, bf16* __restrict__ Kb, bf16* __restrict__ VTb)
{
  const bf16* Cl = XCp + 1536;
  const int g = blockIdx.x;
  const bf16 *A, *B;
  bf16* C;
  int lda, ldb, ldc, K, m0, n0;
  if (g < 512) {            // Q
    A = XCp; B = Wqub; C = Qb;
    lda = 2048; ldb = 1536; ldc = 2048; K = 1536;
    n0 = (g & 15) * 128; m0 = (g >> 4) * 128;
  } else if (g < 1024) {    // K[h]
    int i = g - 512, bz = i >> 5, by = i & 31;
    A = Cl; B = kupT + bz * 65536; C = Kb + (long long)bz * 524288;
    lda = 2048; ldb = 512; ldc = 128; K = 512;
    m0 = by * 128; n0 = 0;
  } else {                  // VT[h]
    int i = g - 1024, bz = i >> 5, bx = i & 31;
    A = vupT + bz * 65536; B = Cl; C = VTb + (long long)bz * 524288;
    lda = 512; ldb = 2048; ldc = 4096; K = 512;
    m0 = 0; n0 = bx * 128;
  }

  __shared__ bf16 As[2][128][32];
  __shared__ bf16 Bs[2][128][32];

  const int t = threadIdx.x;
  const int lane = t & 63, wave = t >> 6;
  const int wm = (wave >> 1) * 64, wn = (wave & 1) * 64;
  const int r16 = lane & 15, q8 = (lane >> 4) * 8;

  auto stage = [&](int buf, int k0) {
#pragma unroll
    for (int r = 0; r < 2; ++r) {
      int c = r * 256 + t;
      int row = c >> 2, col = (c & 3) << 3;
      g2l16(A + (long long)(m0 + row) * lda + (k0 + col), &As[buf][row][col]);
      g2l16(B + (long long)(n0 + row) * ldb + (k0 + col), &Bs[buf][row][col]);
    }
  };

  f32x4 acc[4][4] = {};

  stage(0, 0);
  int cur = 0;
  for (int k0 = 0; k0 < K; k0 += 32, cur ^= 1) {
    __syncthreads();
    if (k0 + 32 < K) stage(cur ^ 1, k0 + 32);

    bf16x8 af[4], bfr[4];
#pragma unroll
    for (int i = 0; i < 4; ++i)
      af[i]  = *(const bf16x8*)&As[cur][wm + i * 16 + r16][q8];
#pragma unroll
    for (int i = 0; i < 4; ++i)
      bfr[i] = *(const bf16x8*)&Bs[cur][wn + i * 16 + r16][q8];
#pragma unroll
    for (int mi = 0; mi < 4; ++mi)
#pragma unroll
      for (int ni = 0; ni < 4; ++ni)
        acc[mi][ni] = __builtin_amdgcn_mfma_f32_16x16x32_bf16(af[mi], bfr[ni], acc[mi][ni], 0, 0, 0);
  }

  const int quad = lane >> 4;
#pragma unroll
  for (int mi = 0; mi < 4; ++mi)
#pragma unroll
    for (int ni = 0; ni < 4; ++ni)
#pragma unroll
      for (int r = 0; r < 4; ++r) {
        int mm = m0 + wm + mi * 16 + quad * 4 + r;
        int nn = n0 + wn + ni * 16 + r16;
        C[(long long)mm * ldc + nn] = (bf16)acc[mi][ni][r];
      }
}

// ---------------------------------------------------------------------------
// Flash attention, chunked, 64-key tiles, REVERSED order (diagonal first).
// Block = table entry: 128 q rows of (b,h,qt) over KV tiles [cs,cs+cl),
// iterated cend-1 .. cs. K SINGLE-buffered, V double-buffered, Psf wave-
// private => LDS 64KB. Two barriers per tile:
//   A: drains vmcnt (K + V[cur] staged) / all waves left prev K section
//   QK^T (K consumed into regs)
//   B: all waves done reading Ksf -> safe to overwrite
//   stage K(next) + V(next) ; softmax ; PV (Vsf[cur], Psf)
// Softmax: exp2 domain, vote-gated fast path (no reduce/rescale; pass A
// growth scalar via separate expression tree). Slow path = full reduce.
// Causal mask on tiles >= nkv-2. LDS XOR-swizzled (conflict-free).
// ---------------------------------------------------------------------------
__global__ __launch_bounds__(256) void attn_kernel(
    const bf16* __restrict__ Q, const bf16* __restrict__ Kh,
    const bf16* __restrict__ VT, bf16* __restrict__ O,
    float* __restrict__ ml, bf16* __restrict__ parts)
{
  const int L = 2048, HD = 128, D = 2048;
  const int meta = g_tab.tbl[2 * blockIdx.x];
  const int part = g_tab.tbl[2 * blockIdx.x + 1];
  const int b = meta & 1, h = (meta >> 1) & 15, qt = (meta >> 5) & 15;
  const int cs = (meta >> 9) & 127, cl = (meta >> 16) & 15;
  const int q0 = qt * 128, nkv = 2 * qt + 2;
  const int cend = cs + cl;
  // mask any diagonal tile (>= nkv-2) present in this chunk:
  const int mraw = nkv - 2 > cs ? nkv - 2 : cs;
  const int mstart = mraw < cend ? mraw : cend;

  const int t = threadIdx.x, wave = t >> 6, lane = t & 63;
  const int col = lane & 15, quad = lane >> 4;
  const float LOG2E = 1.44269504f;
  const float slope2 = exp2f(-0.5f * (float)(h + 1)) * LOG2E;  // exp2-domain
  const float slope16 = slope2 * 16.0f;
  const float scale2 = 0.08838834764831845f * LOG2E;   // (1/sqrt(128))*log2e

  __shared__ bf16 Ksf[64 * 128];      // [key][d], 16 chunks/row, swz mask 15
  __shared__ bf16 Vsf[2][128 * 64];   // [d][key],  8 chunks/row, swz mask 7
  __shared__ bf16 Psf[128 * 64];      // [q][key], wave-private 32-row bands

  const long long qrow0 = (long long)(b * L + q0 + wave * 32);
  const long long kbase = (long long)(h * 4096 + b * L) * HD;
  const long long vbase = (long long)(h * HD) * 4096 + b * L;

  auto stage = [&](int vbuf, int itile) {
    const int kv0 = itile << 6;
#pragma unroll
    for (int i = 0; i < 4; ++i) {
      int P = i * 256 + t;   // physical 16B chunk index (contiguous per wave)
      {  // K: row = P>>4, phys chunk p = P&15, logical chunk = p ^ (row&15)
        int rr = P >> 4, cc = ((P & 15) ^ (rr & 15)) << 3;
        g2l16(Kh + kbase + (long long)(kv0 + rr) * HD + cc, &Ksf[P * 8]);
      }
      {  // V: row = P>>3, phys chunk p = P&7, logical chunk = p ^ (row&7)
        int rr = P >> 3, cc = ((P & 7) ^ (rr & 7)) << 3;
        g2l16(VT + vbase + (long long)rr * 4096 + kv0 + cc, &Vsf[vbuf][P * 8]);
      }
    }
  };

  bf16x8 qf[2][4];
#pragma unroll
  for (int mi = 0; mi < 2; ++mi)
#pragma unroll
    for (int ks = 0; ks < 4; ++ks)
      qf[mi][ks] = *(const bf16x8*)&Q[(qrow0 + mi * 16 + col) * D + h * HD + ks * 32 + quad * 8];

  f32x4 o_acc[2][8] = {};
  float m_i[2][4], l_i[2][4];   // l lane-partial (this lane's 4 cols)
#pragma unroll
  for (int mi = 0; mi < 2; ++mi)
#pragma unroll
    for (int r = 0; r < 4; ++r) { m_i[mi][r] = -1e30f; l_i[mi][r] = 0.f; }

  stage(0, cend - 1);

  for (int it = cend - 1; it >= cs; --it) {
    const int cur = (cend - 1 - it) & 1;
    const int kv0 = it << 6;
    const bool masked = (it >= mstart);   // wave-uniform

    __syncthreads();   // A: drains vmcnt -> Ksf + Vsf[cur] ready

    // S = Q K^T  (per wave: 2 m-tiles x 4 n-tiles, 4 k-steps over d=128)
    f32x4 s_acc[2][4] = {};
    __builtin_amdgcn_s_setprio(1);
#pragma unroll
    for (int ks = 0; ks < 4; ++ks) {
      bf16x8 kf[4];
#pragma unroll
      for (int ni = 0; ni < 4; ++ni)
        kf[ni] = *(const bf16x8*)&Ksf[(ni * 16 + col) * 128 +
                                      (((ks * 4 + quad) ^ col) << 3)];
#pragma unroll
      for (int mi = 0; mi < 2; ++mi)
#pragma unroll
        for (int ni = 0; ni < 4; ++ni)
          s_acc[mi][ni] = __builtin_amdgcn_mfma_f32_16x16x32_bf16(
              qf[mi][ks], kf[ni], s_acc[mi][ni], 0, 0, 0);
    }
    __builtin_amdgcn_s_setprio(0);

    __syncthreads();   // B: all waves done reading Ksf -> safe to restage
    if (it > cs) stage(cur ^ 1, it - 1);  // prefetch next (older) tile

    // pass A: single growth scalar per lane. Row max via max over ni of
    // fmaf(s, scale2, ni*slope16) minus sb -- a DIFFERENT expression tree
    // than pass B (no CSE -> nothing but `grow` stays live). Mask ignored:
    // overestimated rm only ever forces the always-correct slow path.
    float grow = -1e30f;
#pragma unroll
    for (int mi = 0; mi < 2; ++mi)
#pragma unroll
      for (int r = 0; r < 4; ++r) {
        const int rowq = wave * 32 + mi * 16 + quad * 4 + r;
        const int qg = q0 + rowq;
        const float sb = slope2 * (float)(qg - kv0 - col);   // dist at ni=0
        float t0 = fmaxf(
            fmaxf(fmaf(s_acc[mi][0][r], scale2, 0.0f * slope16),
                  fmaf(s_acc[mi][1][r], scale2, 1.0f * slope16)),
            fmaxf(fmaf(s_acc[mi][2][r], scale2, 2.0f * slope16),
                  fmaf(s_acc[mi][3][r], scale2, 3.0f * slope16)));
        grow = fmaxf(grow, (t0 - sb) - m_i[mi][r]);
      }

    if (!__any(grow > 20.0f)) {
      // fast path: reference m is safe (P <= 2^20); no reduce, no rescale,
      // no m-update. pv = exp2(fma(s, scale2, ni*slope16 - sb - mref)).
#pragma unroll
      for (int mi = 0; mi < 2; ++mi)
#pragma unroll
        for (int r = 0; r < 4; ++r) {
          const int rowq = wave * 32 + mi * 16 + quad * 4 + r;
          const int qg = q0 + rowq;
          const float c0 = -slope2 * (float)(qg - kv0 - col) - m_i[mi][r];
          float ps = 0.f;
#pragma unroll
          for (int ni = 0; ni < 4; ++ni) {
            float pv = exp2f(fmaf(s_acc[mi][ni][r], scale2,
                                  (float)ni * slope16 + c0));
            if (masked && (kv0 + ni * 16 + col > qg)) pv = 0.f;
            ps += pv;
            Psf[rowq * 64 + ((((ni * 2) + (col >> 3)) ^ (rowq & 7)) << 3) +
                (col & 7)] = (bf16)pv;
          }
          l_i[mi][r] += ps;
        }
    } else {
      // slow path (tile 0 / rare excursion): full reduce + rescale.
#pragma unroll
      for (int mi = 0; mi < 2; ++mi)
#pragma unroll
        for (int r = 0; r < 4; ++r) {
          const int rowq = wave * 32 + mi * 16 + quad * 4 + r;
          const int qg = q0 + rowq;
          const float sb = slope2 * (float)(qg - kv0 - col);
          float svv[4];
#pragma unroll
          for (int ni = 0; ni < 4; ++ni) {
            svv[ni] = fmaf(s_acc[mi][ni][r], scale2, (float)ni * slope16 - sb);
            if (masked && (kv0 + ni * 16 + col > qg)) svv[ni] = -1e30f;
          }
          float rm = fmaxf(fmaxf(svv[0], svv[1]), fmaxf(svv[2], svv[3]));
#pragma unroll
          for (int off = 1; off < 16; off <<= 1)
            rm = fmaxf(rm, __shfl_xor(rm, off, 64));
          const float mold = m_i[mi][r];
          float mnew = fmaxf(mold, rm);
          if (masked) mnew = fmaxf(mnew, -1e20f);   // all-masked-row floor
          const float alpha = exp2f(mold - mnew);
          float ps = 0.f;
#pragma unroll
          for (int ni = 0; ni < 4; ++ni) {
            float pv = exp2f(svv[ni] - mnew);
            ps += pv;
            Psf[rowq * 64 + ((((ni * 2) + (col >> 3)) ^ (rowq & 7)) << 3) +
                (col & 7)] = (bf16)pv;
          }
          l_i[mi][r] = fmaf(alpha, l_i[mi][r], ps);
          m_i[mi][r] = mnew;
#pragma unroll
          for (int di = 0; di < 8; ++di) o_acc[mi][di][r] *= alpha;
        }
    }

    // O += P V (no barrier needed: Psf band is wave-private; Vs double-buffered)
    __builtin_amdgcn_s_setprio(1);
#pragma unroll
    for (int kstep = 0; kstep < 2; ++kstep) {
      bf16x8 pf[2];
#pragma unroll
      for (int mi = 0; mi < 2; ++mi)
        pf[mi] = *(const bf16x8*)&Psf[(wave * 32 + mi * 16 + col) * 64 +
                                      (((kstep * 4 + quad) ^ (col & 7)) << 3)];
#pragma unroll
      for (int di = 0; di < 8; ++di) {
        bf16x8 vf = *(const bf16x8*)&Vsf[cur][(di * 16 + col) * 64 +
                                             (((kstep * 4 + quad) ^ (col & 7)) << 3)];
#pragma unroll
        for (int mi = 0; mi < 2; ++mi)
          o_acc[mi][di] = __builtin_amdgcn_mfma_f32_16x16x32_bf16(
              pf[mi], vf, o_acc[mi][di], 0, 0, 0);
      }
    }
    __builtin_amdgcn_s_setprio(0);
  }

  if (part < 0) {
    // direct: normalize (reduce lane-partial l over the 16-lane row group)
#pragma unroll
    for (int mi = 0; mi < 2; ++mi)
#pragma unroll
      for (int r = 0; r < 4; ++r) {
        float lt = l_i[mi][r];
#pragma unroll
        for (int off = 1; off < 16; off <<= 1)
          lt += __shfl_xor(lt, off, 64);
        float rl = 1.0f / lt;
        long long qg = qrow0 + mi * 16 + quad * 4 + r;
#pragma unroll
        for (int di = 0; di < 8; ++di)
          O[qg * D + h * HD + di * 16 + col] = (bf16)(o_acc[mi][di][r] * rl);
      }
  } else {
    // partial: store unnormalized O~ (bf16) + m,l (fp32 per row)
    bf16* pb = parts + (long long)part * 16384;
    float* mlp = ml + (long long)part * 256;
#pragma unroll
    for (int mi = 0; mi < 2; ++mi)
#pragma unroll
      for (int r = 0; r < 4; ++r) {
        float lt = l_i[mi][r];
#pragma unroll
        for (int off = 1; off < 16; off <<= 1)
          lt += __shfl_xor(lt, off, 64);
        int rowq = wave * 32 + mi * 16 + quad * 4 + r;
        if (col == 0) { mlp[rowq] = m_i[mi][r]; mlp[128 + rowq] = lt; }
#pragma unroll
        for (int di = 0; di < 8; ++di)
          pb[rowq * 128 + di * 16 + col] = (bf16)o_acc[mi][di][r];
      }
  }
}

// ---------------------------------------------------------------------------
// Combine partial chunks: O = sum_c e2^(m_c-M) O~_c / sum_c e2^(m_c-M) l_c.
// (m are exp2-domain references; weights use exp2f.) One block per group;
// thread t: row = t>>1, cols (t&1)*64..+63.
// ---------------------------------------------------------------------------
__global__ __launch_bounds__(256) void attn_combine(
    const float* __restrict__ ml, const bf16* __restrict__ parts,
    bf16* __restrict__ O)
{
  const int meta = g_tab.grp[4 * blockIdx.x];
  const int first = g_tab.grp[4 * blockIdx.x + 1];
  const int n = g_tab.grp[4 * blockIdx.x + 2];
  const int b = meta & 1, h = (meta >> 1) & 15, qt = (meta >> 5) & 15;
  const int t = threadIdx.x;
  const int row = t >> 1, cg = t & 1;

  float M = -1e30f;
  for (int c = 0; c < n; ++c) M = fmaxf(M, ml[(long long)(first + c) * 256 + row]);

  float acc[64];
#pragma unroll
  for (int j = 0; j < 64; ++j) acc[j] = 0.f;
  float den = 0.f;
  for (int c = 0; c < n; ++c) {
    const float* mlc = ml + (long long)(first + c) * 256;
    float w = exp2f(mlc[row] - M);
    den = fmaf(w, mlc[128 + row], den);
    const bf16* p = parts + (long long)(first + c) * 16384 + row * 128 + cg * 64;
#pragma unroll
    for (int j8 = 0; j8 < 8; ++j8) {
      bf16x8 v = ((const bf16x8*)p)[j8];
#pragma unroll
      for (int k = 0; k < 8; ++k) acc[j8 * 8 + k] = fmaf(w, (float)v[k], acc[j8 * 8 + k]);
    }
  }
  float rd = 1.0f / den;
  long long qg = (long long)b * 2048 + qt * 128 + row;
  bf16* o = O + qg * 2048 + h * 128 + cg * 64;
#pragma unroll
  for (int j8 = 0; j8 < 8; ++j8) {
    bf16x8 v;
#pragma unroll
    for (int k = 0; k < 8; ++k) v[k] = (bf16)(acc[j8 * 8 + k] * rd);
    ((bf16x8*)o)[j8] = v;
  }
}

// ---------------------------------------------------------------------------
extern "C" void kernel_launch(void* const* d_in, const int* in_sizes, int n_in,
                              void* d_out, int out_size, void* d_ws, size_t ws_size,
                              hipStream_t stream) {
  (void)in_sizes; (void)n_in; (void)out_size; (void)ws_size;
  const float* hs  = (const float*)d_in[0];  // [2,2048,2048]
  const float* Wqd = (const float*)d_in[1];  // [1536,2048]
  const float* Wqu = (const float*)d_in[2];  // [2048,1536]
  const float* Wkv = (const float*)d_in[3];  // [512,2048]
  const float* kup = (const float*)d_in[4];  // [16,512,128]
  const float* vup = (const float*)d_in[5];  // [16,512,128]
  const float* Wo  = (const float*)d_in[6];  // [2048,2048]
  float* out = (float*)d_out;                // [2,2048,2048] fp32

  char* ws = (char*)d_ws;
  bf16* hsb  = (bf16*)ws; ws += (size_t)4096 * 2048 * 2;   // [also Ob]
  bf16* Wdcb = (bf16*)ws; ws += (size_t)2048 * 2048 * 2;   // concat(Wqd,Wkv)
  bf16* Wqub = (bf16*)ws; ws += (size_t)2048 * 1536 * 2;
  bf16* kupT = (bf16*)ws; ws += (size_t)16 * 128 * 512 * 2;
  bf16* vupT = (bf16*)ws; ws += (size_t)16 * 128 * 512 * 2;
  bf16* XC   = (bf16*)ws; ws += (size_t)4096 * 2048 * 2;   // [Xq | Cl] [also Wob]
  bf16* Qb   = (bf16*)ws; ws += (size_t)4096 * 2048 * 2;
  bf16* Kb   = (bf16*)ws; ws += (size_t)16 * 4096 * 128 * 2;
  bf16* VTb  = (bf16*)ws; ws += (size_t)16 * 128 * 4096 * 2;
  bf16* Cl   = XC + 1536;   // latent = cols [1536,2048) of XC, ld 2048
  bf16* Ob   = hsb;         // attn out aliases hsb
  bf16* Wob  = XC;          // Wo bf16 aliases XC

  // attention split scratch aliases Wdcb.. (dead by attention time):
  // [ml 448*256 f32][parts 448*128*128 bf16] = 15.1 MB
  float* mld   = (float*)Wdcb;
  bf16*  parts = (bf16*)(mld + 448 * 256);

  // fp32 -> bf16 converts
  cvt_f32_bf16<<<1024, 256, 0, stream>>>(hs, hsb, 4096 * 2048 / 4);
  cvt3_f32_bf16<<<1024, 256, 0, stream>>>(
      Wqd, Wdcb, 1536 * 2048 / 4,
      Wkv, Wdcb + (size_t)1536 * 2048, 512 * 2048 / 4,
      Wqu, Wqub, 2048 * 1536 / 4);
  transpose_cvt<<<dim3(2, 8, 16), 256, 0, stream>>>(kup, kupT, 512, 128);
  transpose_cvt<<<dim3(2, 8, 16), 256, 0, stream>>>(vup, vupT, 512, 128);

  // XC = hs * [Wq_down|Wkv_down]^T   [4096 x 2048 x 2048]
  gemm_nt<bf16><<<dim3(16, 32, 1), 256, 0, stream>>>(hsb, Wdcb, XC,
                                                     2048, 2048, 2048, 2048, 0, 0, 0);
  // Q, K[h], VT[h] projections: ONE 1536-block dispatch
  gemm_qkv<<<dim3(1536, 1, 1), 256, 0, stream>>>(XC, Wqub, kupT, vupT,
                                                 Qb, Kb, VTb);
  // Wo convert (into XC region, dead after gemm_qkv)
  cvt_f32_bf16<<<512, 256, 0, stream>>>(Wo, Wob, 2048 * 2048 / 4);
  // chunked attention + combine (tables are compile-time constants)
  attn_kernel<<<dim3(ATTN_BLOCKS, 1, 1), 256, 0, stream>>>(Qb, Kb, VTb, Ob, mld, parts);
  attn_combine<<<dim3(COMB_BLOCKS, 1, 1), 256, 0, stream>>>(mld, parts, Ob);
  // out = O * Wo^T                   [4096 x 2048 x 2048], fp32 output
  gemm_nt<float><<<dim3(16, 32, 1), 256, 0, stream>>>(Ob, Wob, out,
                                                      2048, 2048, 2048, 2048, 0, 0, 0);
}